// Round 1
// baseline (4869.191 us; speedup 1.0000x reference)
//
#include <hip/hip_runtime.h>

#define NNODES 50000
#define EORIG  1600000
#define ETOT   (EORIG + NNODES)
#define NEG 0.2f

__device__ __forceinline__ float lrelu(float v) { return v > 0.f ? v : NEG * v; }

// ---------------------------------------------------------------------------
// Fused dual linear: xl = x@Wl + bl, xr = x@Wr + br.  x:[N,K], W:[K,M].
// Block = 256 threads; covers 2M columns; each thread accumulates 8 rows.
// ---------------------------------------------------------------------------
template<int K, int M>
__global__ __launch_bounds__(256) void lin_kernel(
    const float* __restrict__ x,
    const float* __restrict__ Wl, const float* __restrict__ bl,
    const float* __restrict__ Wr, const float* __restrict__ br,
    float* __restrict__ xl, float* __restrict__ xr, int N)
{
    constexpr int COLS = 2 * M;
    constexpr int RPI  = 256 / COLS;   // row-groups processed in parallel
    constexpr int BR   = 8 * RPI;      // rows per block
    __shared__ float xs[BR * K];

    const int r0 = blockIdx.x * BR;

    // cooperative load of BR rows of x into LDS (float4)
    constexpr int TOT4 = BR * K / 4;
    const float4* x4 = reinterpret_cast<const float4*>(x);
    float4* xs4 = reinterpret_cast<float4*>(xs);
    for (int i = threadIdx.x; i < TOT4; i += 256) {
        int row = r0 + i / (K / 4);
        float4 v = make_float4(0.f, 0.f, 0.f, 0.f);
        if (row < N) v = x4[(size_t)row * (K / 4) + (i % (K / 4))];
        xs4[i] = v;
    }
    __syncthreads();

    const int c = threadIdx.x % COLS;
    const int g = threadIdx.x / COLS;
    const float* Wp = (c < M) ? (Wl + c) : (Wr + (c - M));

    float acc[8] = {0.f,0.f,0.f,0.f,0.f,0.f,0.f,0.f};
    const float4* xsr = reinterpret_cast<const float4*>(xs) + (g * 8) * (K / 4);

    for (int k4 = 0; k4 < K / 4; ++k4) {
        float w0 = Wp[(k4 * 4 + 0) * M];
        float w1 = Wp[(k4 * 4 + 1) * M];
        float w2 = Wp[(k4 * 4 + 2) * M];
        float w3 = Wp[(k4 * 4 + 3) * M];
        #pragma unroll
        for (int r = 0; r < 8; ++r) {
            float4 xv = xsr[r * (K / 4) + k4];
            acc[r] += xv.x * w0 + xv.y * w1 + xv.z * w2 + xv.w * w3;
        }
    }

    const float b = (c < M) ? bl[c] : br[c - M];
    float* dstp = (c < M) ? xl : xr;
    const int cc = (c < M) ? c : c - M;
    #pragma unroll
    for (int r = 0; r < 8; ++r) {
        int row = r0 + g * 8 + r;
        if (row < N) dstp[(size_t)row * M + cc] = acc[r] + b;
    }
}

// ---------------------------------------------------------------------------
// Edge pass 1: p[e,h] = exp( sum_c att[h,c]*leaky(xl[s,h,c]+xr[d,h,c]) )
//              denom[d,h] += p  (atomic)
// One thread per (edge, head). Self-loops implicit for e >= EORIG.
// ---------------------------------------------------------------------------
template<int H, int C>
__global__ __launch_bounds__(256) void edge_logits_kernel(
    const float* __restrict__ xl, const float* __restrict__ xr,
    const float* __restrict__ att,
    const int* __restrict__ src, const int* __restrict__ dst,
    float* __restrict__ p, float* __restrict__ denom)
{
    long long t = (long long)blockIdx.x * 256 + threadIdx.x;
    if (t >= (long long)ETOT * H) return;
    int e = (int)(t / H), h = (int)(t % H);
    int s, d;
    if (e < EORIG) { s = src[e]; d = dst[e]; }
    else           { s = e - EORIG; d = s; }

    const float4* a4 = reinterpret_cast<const float4*>(xl) + ((size_t)s * H + h) * (C / 4);
    const float4* b4 = reinterpret_cast<const float4*>(xr) + ((size_t)d * H + h) * (C / 4);
    const float4* t4 = reinterpret_cast<const float4*>(att) + h * (C / 4);

    float acc = 0.f;
    #pragma unroll
    for (int i = 0; i < C / 4; ++i) {
        float4 va = a4[i], vb = b4[i], vt = t4[i];
        acc += lrelu(va.x + vb.x) * vt.x + lrelu(va.y + vb.y) * vt.y
             + lrelu(va.z + vb.z) * vt.z + lrelu(va.w + vb.w) * vt.w;
    }
    float pe = expf(acc);   // softmax shift-invariance: no max subtraction needed
    p[t] = pe;
    atomicAdd(denom + (size_t)d * H + h, pe);
}

// ---------------------------------------------------------------------------
// Edge pass 2: out[d,h,:] += (p[e,h]/denom[d,h]) * xl[s,h,:]  (atomic)
// One thread per (edge, float4-chunk).
// ---------------------------------------------------------------------------
template<int H, int C>
__global__ __launch_bounds__(256) void edge_agg_kernel(
    const float* __restrict__ xl, const float* __restrict__ p,
    const float* __restrict__ denom,
    const int* __restrict__ src, const int* __restrict__ dst,
    float* __restrict__ out)
{
    constexpr int CH4 = H * C / 4;
    long long t = (long long)blockIdx.x * 256 + threadIdx.x;
    if (t >= (long long)ETOT * CH4) return;
    int e = (int)(t / CH4), q = (int)(t % CH4);
    int s, d;
    if (e < EORIG) { s = src[e]; d = dst[e]; }
    else           { s = e - EORIG; d = s; }

    const int h = q / (C / 4);
    float alpha = p[(size_t)e * H + h] / denom[(size_t)d * H + h];
    float4 v = reinterpret_cast<const float4*>(xl)[(size_t)s * CH4 + q];
    float* o = out + (size_t)d * (H * C) + q * 4;
    atomicAdd(o + 0, alpha * v.x);
    atomicAdd(o + 1, alpha * v.y);
    atomicAdd(o + 2, alpha * v.z);
    atomicAdd(o + 3, alpha * v.w);
}

__global__ __launch_bounds__(256) void relu_bias_kernel(
    float* __restrict__ a, const float* __restrict__ b, int n, int F)
{
    int i = blockIdx.x * 256 + threadIdx.x;
    if (i < n) a[i] = fmaxf(a[i] + b[i % F], 0.f);
}

__global__ __launch_bounds__(256) void bias_kernel(
    float* __restrict__ a, const float* __restrict__ b, int n, int F)
{
    int i = blockIdx.x * 256 + threadIdx.x;
    if (i < n) a[i] = a[i] + b[i % F];
}

extern "C" void kernel_launch(void* const* d_in, const int* in_sizes, int n_in,
                              void* d_out, int out_size, void* d_ws, size_t ws_size,
                              hipStream_t stream) {
    const float* x    = (const float*)d_in[0];
    const int*   ei   = (const int*)d_in[1];
    const float* Wl1  = (const float*)d_in[2];
    const float* bl1  = (const float*)d_in[3];
    const float* Wr1  = (const float*)d_in[4];
    const float* br1  = (const float*)d_in[5];
    const float* att1 = (const float*)d_in[6];
    const float* b1   = (const float*)d_in[7];
    const float* Wlmu = (const float*)d_in[8];
    const float* blmu = (const float*)d_in[9];
    const float* Wrmu = (const float*)d_in[10];
    const float* brmu = (const float*)d_in[11];
    const float* atmu = (const float*)d_in[12];
    const float* bmu  = (const float*)d_in[13];
    const float* Wllv = (const float*)d_in[14];
    const float* bllv = (const float*)d_in[15];
    const float* Wrlv = (const float*)d_in[16];
    const float* brlv = (const float*)d_in[17];
    const float* atlv = (const float*)d_in[18];
    const float* blv  = (const float*)d_in[19];

    float* out = (float*)d_out;
    float* ws  = (float*)d_ws;

    float* xl1  = ws;                    // 6,400,000
    float* xr1  = ws + 6400000;          // 6,400,000
    float* agg1 = ws + 12800000;         // 6,400,000 (becomes h after relu)
    float* p1   = ws + 19200000;         // 6,600,000
    float* den1 = ws + 25800000;         // 200,000

    // layer-2 aliases (lifetimes verified: xr1 dead after layer-1 logits,
    // p1/den1 dead after layer-1 aggregation)
    float* xlmu = xr1;
    float* xrmu = xr1 + 1600000;
    float* xllv = xr1 + 3200000;
    float* xrlv = xr1 + 4800000;
    float* pmu  = p1;
    float* plv  = p1 + ETOT;
    float* denmu = den1;
    float* denlv = den1 + NNODES;

    const int* srcp = ei;
    const int* dstp = ei + EORIG;

    hipMemsetAsync(den1, 0, 200000 * sizeof(float), stream);
    hipMemsetAsync(agg1, 0, 6400000 * sizeof(float), stream);
    hipMemsetAsync(out,  0, (size_t)out_size * sizeof(float), stream);

    // ---- layer 1 ----
    lin_kernel<128,128><<<(NNODES + 7) / 8, 256, 0, stream>>>(
        x, Wl1, bl1, Wr1, br1, xl1, xr1, NNODES);

    {
        long long nt = (long long)ETOT * 4;
        int nb = (int)((nt + 255) / 256);
        edge_logits_kernel<4,32><<<nb, 256, 0, stream>>>(
            xl1, xr1, att1, srcp, dstp, p1, den1);
    }
    {
        long long nt = (long long)ETOT * 32;
        int nb = (int)((nt + 255) / 256);
        edge_agg_kernel<4,32><<<nb, 256, 0, stream>>>(
            xl1, p1, den1, srcp, dstp, agg1);
    }
    relu_bias_kernel<<<(6400000 + 255) / 256, 256, 0, stream>>>(agg1, b1, 6400000, 128);

    // ---- layer 2 transforms (input = agg1 == h) ----
    lin_kernel<128,32><<<(NNODES + 31) / 32, 256, 0, stream>>>(
        agg1, Wlmu, blmu, Wrmu, brmu, xlmu, xrmu, NNODES);
    lin_kernel<128,32><<<(NNODES + 31) / 32, 256, 0, stream>>>(
        agg1, Wllv, bllv, Wrlv, brlv, xllv, xrlv, NNODES);

    hipMemsetAsync(denmu, 0, 100000 * sizeof(float), stream);

    {
        int nb = (ETOT + 255) / 256;
        edge_logits_kernel<1,32><<<nb, 256, 0, stream>>>(
            xlmu, xrmu, atmu, srcp, dstp, pmu, denmu);
        edge_logits_kernel<1,32><<<nb, 256, 0, stream>>>(
            xllv, xrlv, atlv, srcp, dstp, plv, denlv);
    }
    {
        long long nt = (long long)ETOT * 8;
        int nb = (int)((nt + 255) / 256);
        edge_agg_kernel<1,32><<<nb, 256, 0, stream>>>(
            xlmu, pmu, denmu, srcp, dstp, out);
        edge_agg_kernel<1,32><<<nb, 256, 0, stream>>>(
            xllv, plv, denlv, srcp, dstp, out + 1600000);
    }
    bias_kernel<<<(1600000 + 255) / 256, 256, 0, stream>>>(out,           bmu, 1600000, 32);
    bias_kernel<<<(1600000 + 255) / 256, 256, 0, stream>>>(out + 1600000, blv, 1600000, 32);
}

// Round 2
// 835.362 us; speedup vs baseline: 5.8288x; 5.8288x over previous
//
#include <hip/hip_runtime.h>

#define NNODES 50000
#define EORIG  1600000
#define ETOT   (EORIG + NNODES)
#define NEG 0.2f

__device__ __forceinline__ float lrelu(float v) { return v > 0.f ? v : NEG * v; }

// ---------------------------------------------------------------------------
// Fused dual linear: xl = x@Wl + bl, xr = x@Wr + br.  x:[N,K], W:[K,M].
// ---------------------------------------------------------------------------
template<int K, int M>
__global__ __launch_bounds__(256) void lin_kernel(
    const float* __restrict__ x,
    const float* __restrict__ Wl, const float* __restrict__ bl,
    const float* __restrict__ Wr, const float* __restrict__ br,
    float* __restrict__ xl, float* __restrict__ xr, int N)
{
    constexpr int COLS = 2 * M;
    constexpr int RPI  = 256 / COLS;
    constexpr int BR   = 8 * RPI;
    __shared__ float xs[BR * K];

    const int r0 = blockIdx.x * BR;

    constexpr int TOT4 = BR * K / 4;
    const float4* x4 = reinterpret_cast<const float4*>(x);
    float4* xs4 = reinterpret_cast<float4*>(xs);
    for (int i = threadIdx.x; i < TOT4; i += 256) {
        int row = r0 + i / (K / 4);
        float4 v = make_float4(0.f, 0.f, 0.f, 0.f);
        if (row < N) v = x4[(size_t)row * (K / 4) + (i % (K / 4))];
        xs4[i] = v;
    }
    __syncthreads();

    const int c = threadIdx.x % COLS;
    const int g = threadIdx.x / COLS;
    const float* Wp = (c < M) ? (Wl + c) : (Wr + (c - M));

    float acc[8] = {0.f,0.f,0.f,0.f,0.f,0.f,0.f,0.f};
    const float4* xsr = reinterpret_cast<const float4*>(xs) + (g * 8) * (K / 4);

    for (int k4 = 0; k4 < K / 4; ++k4) {
        float w0 = Wp[(k4 * 4 + 0) * M];
        float w1 = Wp[(k4 * 4 + 1) * M];
        float w2 = Wp[(k4 * 4 + 2) * M];
        float w3 = Wp[(k4 * 4 + 3) * M];
        #pragma unroll
        for (int r = 0; r < 8; ++r) {
            float4 xv = xsr[r * (K / 4) + k4];
            acc[r] += xv.x * w0 + xv.y * w1 + xv.z * w2 + xv.w * w3;
        }
    }

    const float b = (c < M) ? bl[c] : br[c - M];
    float* dstp = (c < M) ? xl : xr;
    const int cc = (c < M) ? c : c - M;
    #pragma unroll
    for (int r = 0; r < 8; ++r) {
        int row = r0 + g * 8 + r;
        if (row < N) dstp[(size_t)row * M + cc] = acc[r] + b;
    }
}

// ---------------------------------------------------------------------------
// CSR build: histogram -> exclusive scan -> scatter (src ids, bucket by dst)
// ---------------------------------------------------------------------------
__global__ __launch_bounds__(256) void hist_kernel(
    const int* __restrict__ dst, int* __restrict__ deg)
{
    int e = blockIdx.x * 256 + threadIdx.x;
    if (e >= ETOT) return;
    int d = (e < EORIG) ? dst[e] : e - EORIG;
    atomicAdd(deg + d, 1);
}

__global__ __launch_bounds__(256) void scan1_kernel(
    const int* __restrict__ deg, int* __restrict__ offs, int* __restrict__ partials)
{
    __shared__ int tmp[256];
    int t = threadIdx.x;
    int i = blockIdx.x * 256 + t;
    int v = (i < NNODES) ? deg[i] : 0;
    tmp[t] = v;
    __syncthreads();
    for (int off = 1; off < 256; off <<= 1) {
        int a = (t >= off) ? tmp[t - off] : 0;
        __syncthreads();
        tmp[t] += a;
        __syncthreads();
    }
    if (i < NNODES) offs[i] = tmp[t] - v;   // exclusive within block
    if (t == 255) partials[blockIdx.x] = tmp[255];
}

__global__ __launch_bounds__(256) void scan2_kernel(int* __restrict__ partials, int nb)
{
    __shared__ int tmp[256];
    int t = threadIdx.x;
    int v = (t < nb) ? partials[t] : 0;
    tmp[t] = v;
    __syncthreads();
    for (int off = 1; off < 256; off <<= 1) {
        int a = (t >= off) ? tmp[t - off] : 0;
        __syncthreads();
        tmp[t] += a;
        __syncthreads();
    }
    if (t < nb) partials[t] = tmp[t] - v;   // exclusive
}

__global__ __launch_bounds__(256) void scan3_kernel(
    int* __restrict__ offs, const int* __restrict__ partials)
{
    int i = blockIdx.x * 256 + threadIdx.x;
    if (i < NNODES) offs[i] += partials[blockIdx.x];
    if (i == 0) offs[NNODES] = ETOT;
}

__global__ __launch_bounds__(256) void scatter_kernel(
    const int* __restrict__ src, const int* __restrict__ dst,
    const int* __restrict__ offs, int* __restrict__ deg /* destroyed */,
    int* __restrict__ csr)
{
    int e = blockIdx.x * 256 + threadIdx.x;
    if (e >= ETOT) return;
    int s, d;
    if (e < EORIG) { s = src[e]; d = dst[e]; }
    else           { s = e - EORIG; d = s; }
    int old = atomicSub(deg + d, 1);
    csr[offs[d] + old - 1] = s;
}

// ---------------------------------------------------------------------------
// Layer-1 fused gather: per (node, head-pair) wave. Single pass computes
// logits, exp, numerator and denominator; epilogue adds bias + relu.
// ---------------------------------------------------------------------------
__global__ __launch_bounds__(256) void gat_gather1(
    const float* __restrict__ xl, const float* __restrict__ xr,
    const float* __restrict__ att, const float* __restrict__ bias,
    const int* __restrict__ offs, const int* __restrict__ csr,
    float* __restrict__ outp)
{
    int w = (blockIdx.x * 256 + threadIdx.x) >> 6;
    if (w >= NNODES * 2) return;
    int lane = threadIdx.x & 63;
    int d = w >> 1;
    int col = ((w & 1) << 6) + lane;     // hpair*64 + lane -> contiguous 64 cols
    float xrc = xr[(size_t)d * 128 + col];
    float ac  = att[col];
    int beg = offs[d], end = offs[d + 1];
    float den = 0.f, acc = 0.f;
    for (int slot = beg; slot < end; ++slot) {
        int s = csr[slot];
        float xlc = xl[(size_t)s * 128 + col];
        float t = lrelu(xlc + xrc) * ac;
        #pragma unroll
        for (int m = 16; m >= 1; m >>= 1) t += __shfl_xor(t, m, 64);  // 32-lane (per-head) reduce
        float p = __expf(t);
        den += p;
        acc += p * xlc;
    }
    outp[(size_t)d * 128 + col] = fmaxf(acc / den + bias[col], 0.f);
}

// ---------------------------------------------------------------------------
// Layer-2 fused gather: one wave per node; lanes 0-31 = mu head, 32-63 = lv.
// ---------------------------------------------------------------------------
__global__ __launch_bounds__(256) void gat_gather2(
    const float* __restrict__ xlmu, const float* __restrict__ xrmu,
    const float* __restrict__ atmu, const float* __restrict__ bmu,
    const float* __restrict__ xllv, const float* __restrict__ xrlv,
    const float* __restrict__ atlv, const float* __restrict__ blv,
    const int* __restrict__ offs, const int* __restrict__ csr,
    float* __restrict__ out)
{
    int w = (blockIdx.x * 256 + threadIdx.x) >> 6;
    if (w >= NNODES) return;
    int lane = threadIdx.x & 63;
    int half = lane >> 5;
    int c = lane & 31;
    int d = w;
    const float* xlp = half ? xllv : xlmu;
    float xrc = (half ? xrlv : xrmu)[(size_t)d * 32 + c];
    float ac  = (half ? atlv : atmu)[c];
    int beg = offs[d], end = offs[d + 1];
    float den = 0.f, acc = 0.f;
    for (int slot = beg; slot < end; ++slot) {
        int s = csr[slot];
        float xlc = xlp[(size_t)s * 32 + c];
        float t = lrelu(xlc + xrc) * ac;
        #pragma unroll
        for (int m = 16; m >= 1; m >>= 1) t += __shfl_xor(t, m, 64);
        float p = __expf(t);
        den += p;
        acc += p * xlc;
    }
    float* op = out + (half ? 1600000 : 0);
    op[(size_t)d * 32 + c] = acc / den + (half ? blv : bmu)[c];
}

extern "C" void kernel_launch(void* const* d_in, const int* in_sizes, int n_in,
                              void* d_out, int out_size, void* d_ws, size_t ws_size,
                              hipStream_t stream) {
    const float* x    = (const float*)d_in[0];
    const int*   ei   = (const int*)d_in[1];
    const float* Wl1  = (const float*)d_in[2];
    const float* bl1  = (const float*)d_in[3];
    const float* Wr1  = (const float*)d_in[4];
    const float* br1  = (const float*)d_in[5];
    const float* att1 = (const float*)d_in[6];
    const float* b1   = (const float*)d_in[7];
    const float* Wlmu = (const float*)d_in[8];
    const float* blmu = (const float*)d_in[9];
    const float* Wrmu = (const float*)d_in[10];
    const float* brmu = (const float*)d_in[11];
    const float* atmu = (const float*)d_in[12];
    const float* bmu  = (const float*)d_in[13];
    const float* Wllv = (const float*)d_in[14];
    const float* bllv = (const float*)d_in[15];
    const float* Wrlv = (const float*)d_in[16];
    const float* brlv = (const float*)d_in[17];
    const float* atlv = (const float*)d_in[18];
    const float* blv  = (const float*)d_in[19];

    float* out = (float*)d_out;
    float* ws  = (float*)d_ws;

    float* xl1 = ws;                 // 6.4M floats
    float* xr1 = ws + 6400000;       // 6.4M
    float* h   = ws + 12800000;      // 6.4M

    // layer-2 transforms alias xl1/xr1 (dead after layer-1 gather)
    float* xlmu = ws;
    float* xrmu = ws + 1600000;
    float* xllv = ws + 3200000;
    float* xrlv = ws + 4800000;

    int* ip       = (int*)(ws + 19200000);
    int* deg      = ip;               // 50,000
    int* offs     = ip + 50000;       // 50,001
    int* partials = ip + 100001;      // 256
    int* csr      = ip + 100257;      // 1,650,000

    const int* srcp = ei;
    const int* dstp = ei + EORIG;

    const int NB1 = (NNODES + 255) / 256;   // 196

    // ---- CSR build (runs concurrently-safe, stream-serialized) ----
    hipMemsetAsync(deg, 0, NNODES * sizeof(int), stream);
    hist_kernel<<<(ETOT + 255) / 256, 256, 0, stream>>>(dstp, deg);
    scan1_kernel<<<NB1, 256, 0, stream>>>(deg, offs, partials);
    scan2_kernel<<<1, 256, 0, stream>>>(partials, NB1);
    scan3_kernel<<<NB1, 256, 0, stream>>>(offs, partials);
    scatter_kernel<<<(ETOT + 255) / 256, 256, 0, stream>>>(srcp, dstp, offs, deg, csr);

    // ---- layer 1 ----
    lin_kernel<128,128><<<(NNODES + 7) / 8, 256, 0, stream>>>(
        x, Wl1, bl1, Wr1, br1, xl1, xr1, NNODES);

    gat_gather1<<<(NNODES * 2 * 64 + 255) / 256, 256, 0, stream>>>(
        xl1, xr1, att1, b1, offs, csr, h);

    // ---- layer 2 ----
    lin_kernel<128,32><<<(NNODES + 31) / 32, 256, 0, stream>>>(
        h, Wlmu, blmu, Wrmu, brmu, xlmu, xrmu, NNODES);
    lin_kernel<128,32><<<(NNODES + 31) / 32, 256, 0, stream>>>(
        h, Wllv, bllv, Wrlv, brlv, xllv, xrlv, NNODES);

    gat_gather2<<<(NNODES * 64 + 255) / 256, 256, 0, stream>>>(
        xlmu, xrmu, atmu, bmu, xllv, xrlv, atlv, blv, offs, csr, out);
}

// Round 3
// 597.488 us; speedup vs baseline: 8.1494x; 1.3981x over previous
//
#include <hip/hip_runtime.h>

#define NNODES 50000
#define EORIG  1600000
#define ETOT   (EORIG + NNODES)
#define NEG 0.2f

__device__ __forceinline__ float lrelu(float v) { return v > 0.f ? v : NEG * v; }

// ---------------------------------------------------------------------------
// Fused dual linear: xl = x@Wl + bl, xr = x@Wr + br.  x:[N,K], W:[K,M].
// ---------------------------------------------------------------------------
template<int K, int M>
__global__ __launch_bounds__(256) void lin_kernel(
    const float* __restrict__ x,
    const float* __restrict__ Wl, const float* __restrict__ bl,
    const float* __restrict__ Wr, const float* __restrict__ br,
    float* __restrict__ xl, float* __restrict__ xr, int N)
{
    constexpr int COLS = 2 * M;
    constexpr int RPI  = 256 / COLS;
    constexpr int BR   = 8 * RPI;
    __shared__ float xs[BR * K];

    const int r0 = blockIdx.x * BR;

    constexpr int TOT4 = BR * K / 4;
    const float4* x4 = reinterpret_cast<const float4*>(x);
    float4* xs4 = reinterpret_cast<float4*>(xs);
    for (int i = threadIdx.x; i < TOT4; i += 256) {
        int row = r0 + i / (K / 4);
        float4 v = make_float4(0.f, 0.f, 0.f, 0.f);
        if (row < N) v = x4[(size_t)row * (K / 4) + (i % (K / 4))];
        xs4[i] = v;
    }
    __syncthreads();

    const int c = threadIdx.x % COLS;
    const int g = threadIdx.x / COLS;
    const float* Wp = (c < M) ? (Wl + c) : (Wr + (c - M));

    float acc[8] = {0.f,0.f,0.f,0.f,0.f,0.f,0.f,0.f};
    const float4* xsr = reinterpret_cast<const float4*>(xs) + (g * 8) * (K / 4);

    for (int k4 = 0; k4 < K / 4; ++k4) {
        float w0 = Wp[(k4 * 4 + 0) * M];
        float w1 = Wp[(k4 * 4 + 1) * M];
        float w2 = Wp[(k4 * 4 + 2) * M];
        float w3 = Wp[(k4 * 4 + 3) * M];
        #pragma unroll
        for (int r = 0; r < 8; ++r) {
            float4 xv = xsr[r * (K / 4) + k4];
            acc[r] += xv.x * w0 + xv.y * w1 + xv.z * w2 + xv.w * w3;
        }
    }

    const float b = (c < M) ? bl[c] : br[c - M];
    float* dstp = (c < M) ? xl : xr;
    const int cc = (c < M) ? c : c - M;
    #pragma unroll
    for (int r = 0; r < 8; ++r) {
        int row = r0 + g * 8 + r;
        if (row < N) dstp[(size_t)row * M + cc] = acc[r] + b;
    }
}

// ---------------------------------------------------------------------------
// CSR build: histogram -> exclusive scan -> scatter (src ids, bucket by dst)
// ---------------------------------------------------------------------------
__global__ __launch_bounds__(256) void hist_kernel(
    const int* __restrict__ dst, int* __restrict__ deg)
{
    int e = blockIdx.x * 256 + threadIdx.x;
    if (e >= ETOT) return;
    int d = (e < EORIG) ? dst[e] : e - EORIG;
    atomicAdd(deg + d, 1);
}

__global__ __launch_bounds__(256) void scan1_kernel(
    const int* __restrict__ deg, int* __restrict__ offs, int* __restrict__ partials)
{
    __shared__ int tmp[256];
    int t = threadIdx.x;
    int i = blockIdx.x * 256 + t;
    int v = (i < NNODES) ? deg[i] : 0;
    tmp[t] = v;
    __syncthreads();
    for (int off = 1; off < 256; off <<= 1) {
        int a = (t >= off) ? tmp[t - off] : 0;
        __syncthreads();
        tmp[t] += a;
        __syncthreads();
    }
    if (i < NNODES) offs[i] = tmp[t] - v;
    if (t == 255) partials[blockIdx.x] = tmp[255];
}

__global__ __launch_bounds__(256) void scan2_kernel(int* __restrict__ partials, int nb)
{
    __shared__ int tmp[256];
    int t = threadIdx.x;
    int v = (t < nb) ? partials[t] : 0;
    tmp[t] = v;
    __syncthreads();
    for (int off = 1; off < 256; off <<= 1) {
        int a = (t >= off) ? tmp[t - off] : 0;
        __syncthreads();
        tmp[t] += a;
        __syncthreads();
    }
    if (t < nb) partials[t] = tmp[t] - v;
}

__global__ __launch_bounds__(256) void scan3_kernel(
    int* __restrict__ offs, const int* __restrict__ partials)
{
    int i = blockIdx.x * 256 + threadIdx.x;
    if (i < NNODES) offs[i] += partials[blockIdx.x];
    if (i == 0) offs[NNODES] = ETOT;
}

__global__ __launch_bounds__(256) void scatter_kernel(
    const int* __restrict__ src, const int* __restrict__ dst,
    const int* __restrict__ offs, int* __restrict__ deg /* destroyed */,
    int* __restrict__ csr)
{
    int e = blockIdx.x * 256 + threadIdx.x;
    if (e >= ETOT) return;
    int s, d;
    if (e < EORIG) { s = src[e]; d = dst[e]; }
    else           { s = e - EORIG; d = s; }
    int old = atomicSub(deg + d, 1);
    csr[offs[d] + old - 1] = s;
}

// ---------------------------------------------------------------------------
// Layer-1 fused gather, 8-edge batched for memory-level parallelism.
// One wave per (node, head-pair); 64 contiguous cols per wave.
// ---------------------------------------------------------------------------
__global__ __launch_bounds__(256) void gat_gather1(
    const float* __restrict__ xl, const float* __restrict__ xr,
    const float* __restrict__ att, const float* __restrict__ bias,
    const int* __restrict__ offs, const int* __restrict__ csr,
    float* __restrict__ outp)
{
    int w = (blockIdx.x * 256 + threadIdx.x) >> 6;
    if (w >= NNODES * 2) return;
    int lane = threadIdx.x & 63;
    int d = w >> 1;
    int col = ((w & 1) << 6) + lane;
    float xrc = xr[(size_t)d * 128 + col];
    float ac  = att[col];
    float bc  = bias[col];
    int beg = offs[d], end = offs[d + 1];   // deg >= 1 (self-loop)
    float den = 0.f, acc = 0.f;

    for (int base = beg; base < end; base += 8) {
        int   si[8];
        float xv[8], tv[8];
        #pragma unroll
        for (int k = 0; k < 8; ++k) {
            int sl = base + k;
            si[k] = csr[sl < end ? sl : end - 1];
        }
        #pragma unroll
        for (int k = 0; k < 8; ++k)
            xv[k] = xl[(size_t)si[k] * 128 + col];
        #pragma unroll
        for (int k = 0; k < 8; ++k)
            tv[k] = lrelu(xv[k] + xrc) * ac;
        #pragma unroll
        for (int m = 16; m >= 1; m >>= 1) {
            #pragma unroll
            for (int k = 0; k < 8; ++k)
                tv[k] += __shfl_xor(tv[k], m, 64);
        }
        #pragma unroll
        for (int k = 0; k < 8; ++k) {
            float p = (base + k < end) ? __expf(tv[k]) : 0.f;
            den += p;
            acc += p * xv[k];
        }
    }
    outp[(size_t)d * 128 + col] = fmaxf(acc / den + bc, 0.f);
}

// ---------------------------------------------------------------------------
// Layer-2 fused gather, 8-edge batched. One wave per node;
// lanes 0-31 = mu head, lanes 32-63 = logvar head.
// ---------------------------------------------------------------------------
__global__ __launch_bounds__(256) void gat_gather2(
    const float* __restrict__ xlmu, const float* __restrict__ xrmu,
    const float* __restrict__ atmu, const float* __restrict__ bmu,
    const float* __restrict__ xllv, const float* __restrict__ xrlv,
    const float* __restrict__ atlv, const float* __restrict__ blv,
    const int* __restrict__ offs, const int* __restrict__ csr,
    float* __restrict__ out)
{
    int w = (blockIdx.x * 256 + threadIdx.x) >> 6;
    if (w >= NNODES) return;
    int lane = threadIdx.x & 63;
    int half = lane >> 5;
    int c = lane & 31;
    int d = w;
    const float* xlp = half ? xllv : xlmu;
    float xrc = (half ? xrlv : xrmu)[(size_t)d * 32 + c];
    float ac  = (half ? atlv : atmu)[c];
    float bc  = (half ? blv : bmu)[c];
    int beg = offs[d], end = offs[d + 1];
    float den = 0.f, acc = 0.f;

    for (int base = beg; base < end; base += 8) {
        int   si[8];
        float xv[8], tv[8];
        #pragma unroll
        for (int k = 0; k < 8; ++k) {
            int sl = base + k;
            si[k] = csr[sl < end ? sl : end - 1];
        }
        #pragma unroll
        for (int k = 0; k < 8; ++k)
            xv[k] = xlp[(size_t)si[k] * 32 + c];
        #pragma unroll
        for (int k = 0; k < 8; ++k)
            tv[k] = lrelu(xv[k] + xrc) * ac;
        #pragma unroll
        for (int m = 16; m >= 1; m >>= 1) {
            #pragma unroll
            for (int k = 0; k < 8; ++k)
                tv[k] += __shfl_xor(tv[k], m, 64);
        }
        #pragma unroll
        for (int k = 0; k < 8; ++k) {
            float p = (base + k < end) ? __expf(tv[k]) : 0.f;
            den += p;
            acc += p * xv[k];
        }
    }
    float* op = out + (half ? 1600000 : 0);
    op[(size_t)d * 32 + c] = acc / den + bc;
}

extern "C" void kernel_launch(void* const* d_in, const int* in_sizes, int n_in,
                              void* d_out, int out_size, void* d_ws, size_t ws_size,
                              hipStream_t stream) {
    const float* x    = (const float*)d_in[0];
    const int*   ei   = (const int*)d_in[1];
    const float* Wl1  = (const float*)d_in[2];
    const float* bl1  = (const float*)d_in[3];
    const float* Wr1  = (const float*)d_in[4];
    const float* br1  = (const float*)d_in[5];
    const float* att1 = (const float*)d_in[6];
    const float* b1   = (const float*)d_in[7];
    const float* Wlmu = (const float*)d_in[8];
    const float* blmu = (const float*)d_in[9];
    const float* Wrmu = (const float*)d_in[10];
    const float* brmu = (const float*)d_in[11];
    const float* atmu = (const float*)d_in[12];
    const float* bmu  = (const float*)d_in[13];
    const float* Wllv = (const float*)d_in[14];
    const float* bllv = (const float*)d_in[15];
    const float* Wrlv = (const float*)d_in[16];
    const float* brlv = (const float*)d_in[17];
    const float* atlv = (const float*)d_in[18];
    const float* blv  = (const float*)d_in[19];

    float* out = (float*)d_out;
    float* ws  = (float*)d_ws;

    float* xl1 = ws;                 // 6.4M floats
    float* xr1 = ws + 6400000;       // 6.4M
    float* h   = ws + 12800000;      // 6.4M

    // layer-2 transforms alias xl1/xr1 (dead after layer-1 gather)
    float* xlmu = ws;
    float* xrmu = ws + 1600000;
    float* xllv = ws + 3200000;
    float* xrlv = ws + 4800000;

    int* ip       = (int*)(ws + 19200000);
    int* deg      = ip;               // 50,000
    int* offs     = ip + 50000;       // 50,001
    int* partials = ip + 100001;      // 256
    int* csr      = ip + 100257;      // 1,650,000

    const int* srcp = ei;
    const int* dstp = ei + EORIG;

    const int NB1 = (NNODES + 255) / 256;   // 196

    // ---- CSR build ----
    hipMemsetAsync(deg, 0, NNODES * sizeof(int), stream);
    hist_kernel<<<(ETOT + 255) / 256, 256, 0, stream>>>(dstp, deg);
    scan1_kernel<<<NB1, 256, 0, stream>>>(deg, offs, partials);
    scan2_kernel<<<1, 256, 0, stream>>>(partials, NB1);
    scan3_kernel<<<NB1, 256, 0, stream>>>(offs, partials);
    scatter_kernel<<<(ETOT + 255) / 256, 256, 0, stream>>>(srcp, dstp, offs, deg, csr);

    // ---- layer 1 ----
    lin_kernel<128,128><<<(NNODES + 7) / 8, 256, 0, stream>>>(
        x, Wl1, bl1, Wr1, br1, xl1, xr1, NNODES);

    gat_gather1<<<(NNODES * 2 * 64 + 255) / 256, 256, 0, stream>>>(
        xl1, xr1, att1, b1, offs, csr, h);

    // ---- layer 2 ----
    lin_kernel<128,32><<<(NNODES + 31) / 32, 256, 0, stream>>>(
        h, Wlmu, blmu, Wrmu, brmu, xlmu, xrmu, NNODES);
    lin_kernel<128,32><<<(NNODES + 31) / 32, 256, 0, stream>>>(
        h, Wllv, bllv, Wrlv, brlv, xllv, xrlv, NNODES);

    gat_gather2<<<(NNODES * 64 + 255) / 256, 256, 0, stream>>>(
        xlmu, xrmu, atmu, bmu, xllv, xrlv, atlv, blv, offs, csr, out);
}

// Round 4
// 466.191 us; speedup vs baseline: 10.4446x; 1.2816x over previous
//
#include <hip/hip_runtime.h>

#define NNODES 50000
#define EORIG  1600000
#define ETOT   (EORIG + NNODES)
#define NEG 0.2f

__device__ __forceinline__ float lrelu(float v) { return v > 0.f ? v : NEG * v; }

// ---------------------------------------------------------------------------
// Fused dual linear: xl = x@Wl + bl, xr = x@Wr + br.  x:[N,K], W:[K,M].
// ---------------------------------------------------------------------------
template<int K, int M>
__global__ __launch_bounds__(256) void lin_kernel(
    const float* __restrict__ x,
    const float* __restrict__ Wl, const float* __restrict__ bl,
    const float* __restrict__ Wr, const float* __restrict__ br,
    float* __restrict__ xl, float* __restrict__ xr, int N)
{
    constexpr int COLS = 2 * M;
    constexpr int RPI  = 256 / COLS;
    constexpr int BR   = 8 * RPI;
    __shared__ float xs[BR * K];

    const int r0 = blockIdx.x * BR;

    constexpr int TOT4 = BR * K / 4;
    const float4* x4 = reinterpret_cast<const float4*>(x);
    float4* xs4 = reinterpret_cast<float4*>(xs);
    for (int i = threadIdx.x; i < TOT4; i += 256) {
        int row = r0 + i / (K / 4);
        float4 v = make_float4(0.f, 0.f, 0.f, 0.f);
        if (row < N) v = x4[(size_t)row * (K / 4) + (i % (K / 4))];
        xs4[i] = v;
    }
    __syncthreads();

    const int c = threadIdx.x % COLS;
    const int g = threadIdx.x / COLS;
    const float* Wp = (c < M) ? (Wl + c) : (Wr + (c - M));

    float acc[8] = {0.f,0.f,0.f,0.f,0.f,0.f,0.f,0.f};
    const float4* xsr = reinterpret_cast<const float4*>(xs) + (g * 8) * (K / 4);

    for (int k4 = 0; k4 < K / 4; ++k4) {
        float w0 = Wp[(k4 * 4 + 0) * M];
        float w1 = Wp[(k4 * 4 + 1) * M];
        float w2 = Wp[(k4 * 4 + 2) * M];
        float w3 = Wp[(k4 * 4 + 3) * M];
        #pragma unroll
        for (int r = 0; r < 8; ++r) {
            float4 xv = xsr[r * (K / 4) + k4];
            acc[r] += xv.x * w0 + xv.y * w1 + xv.z * w2 + xv.w * w3;
        }
    }

    const float b = (c < M) ? bl[c] : br[c - M];
    float* dstp = (c < M) ? xl : xr;
    const int cc = (c < M) ? c : c - M;
    #pragma unroll
    for (int r = 0; r < 8; ++r) {
        int row = r0 + g * 8 + r;
        if (row < N) dstp[(size_t)row * M + cc] = acc[r] + b;
    }
}

// ---------------------------------------------------------------------------
// CSR build: histogram -> exclusive scan -> scatter (src ids, bucket by dst)
// ---------------------------------------------------------------------------
__global__ __launch_bounds__(256) void hist_kernel(
    const int* __restrict__ dst, int* __restrict__ deg)
{
    int e = blockIdx.x * 256 + threadIdx.x;
    if (e >= ETOT) return;
    int d = (e < EORIG) ? dst[e] : e - EORIG;
    atomicAdd(deg + d, 1);
}

__global__ __launch_bounds__(256) void scan1_kernel(
    const int* __restrict__ deg, int* __restrict__ offs, int* __restrict__ partials)
{
    __shared__ int tmp[256];
    int t = threadIdx.x;
    int i = blockIdx.x * 256 + t;
    int v = (i < NNODES) ? deg[i] : 0;
    tmp[t] = v;
    __syncthreads();
    for (int off = 1; off < 256; off <<= 1) {
        int a = (t >= off) ? tmp[t - off] : 0;
        __syncthreads();
        tmp[t] += a;
        __syncthreads();
    }
    if (i < NNODES) offs[i] = tmp[t] - v;
    if (t == 255) partials[blockIdx.x] = tmp[255];
}

__global__ __launch_bounds__(256) void scan2_kernel(int* __restrict__ partials, int nb)
{
    __shared__ int tmp[256];
    int t = threadIdx.x;
    int v = (t < nb) ? partials[t] : 0;
    tmp[t] = v;
    __syncthreads();
    for (int off = 1; off < 256; off <<= 1) {
        int a = (t >= off) ? tmp[t - off] : 0;
        __syncthreads();
        tmp[t] += a;
        __syncthreads();
    }
    if (t < nb) partials[t] = tmp[t] - v;
}

__global__ __launch_bounds__(256) void scan3_kernel(
    int* __restrict__ offs, const int* __restrict__ partials)
{
    int i = blockIdx.x * 256 + threadIdx.x;
    if (i < NNODES) offs[i] += partials[blockIdx.x];
    if (i == 0) offs[NNODES] = ETOT;
}

__global__ __launch_bounds__(256) void scatter_kernel(
    const int* __restrict__ src, const int* __restrict__ dst,
    const int* __restrict__ offs, int* __restrict__ deg /* destroyed */,
    int* __restrict__ csr)
{
    int e = blockIdx.x * 256 + threadIdx.x;
    if (e >= ETOT) return;
    int s, d;
    if (e < EORIG) { s = src[e]; d = dst[e]; }
    else           { s = e - EORIG; d = s; }
    int old = atomicSub(deg + d, 1);
    csr[offs[d] + old - 1] = s;
}

// ---------------------------------------------------------------------------
// Layer-1 fused gather. ONE wave per node; float4 per lane.
// Lane = half*32 + q:  half in {0,1} = edge sub-slot, q = col-chunk (cols 4q..4q+3).
// Each load instr fetches two full 128-ch rows (2 edges). Head = q>>3; per-
// (edge,head) logit reduce = 3 shfl steps over the 8-lane q-group. Halves'
// partial den/acc combined once at the end via xor-32.
// ---------------------------------------------------------------------------
__global__ __launch_bounds__(256) void gat_gather1(
    const float* __restrict__ xl, const float* __restrict__ xr,
    const float* __restrict__ att, const float* __restrict__ bias,
    const int* __restrict__ offs, const int* __restrict__ csr,
    float* __restrict__ outp)
{
    int d = (blockIdx.x * 256 + threadIdx.x) >> 6;   // node
    if (d >= NNODES) return;
    int lane = threadIdx.x & 63;
    int half = lane >> 5;
    int q    = lane & 31;

    const float4* xl4 = reinterpret_cast<const float4*>(xl);
    float4 xrc = reinterpret_cast<const float4*>(xr)[(size_t)d * 32 + q];
    float4 ac  = reinterpret_cast<const float4*>(att)[q];
    float4 bc  = reinterpret_cast<const float4*>(bias)[q];

    int beg = offs[d], end = offs[d + 1];   // deg >= 1 (self-loop)
    float den = 0.f;
    float4 acc = make_float4(0.f, 0.f, 0.f, 0.f);

    for (int base = beg; base < end; base += 8) {
        int   si[4];
        bool  val[4];
        float4 xv[4];
        #pragma unroll
        for (int k = 0; k < 4; ++k) {
            int sl = base + 2 * k + half;
            val[k] = sl < end;
            si[k]  = csr[val[k] ? sl : end - 1];
        }
        #pragma unroll
        for (int k = 0; k < 4; ++k)
            xv[k] = xl4[(size_t)si[k] * 32 + q];
        #pragma unroll
        for (int k = 0; k < 4; ++k) {
            float t = lrelu(xv[k].x + xrc.x) * ac.x
                    + lrelu(xv[k].y + xrc.y) * ac.y
                    + lrelu(xv[k].z + xrc.z) * ac.z
                    + lrelu(xv[k].w + xrc.w) * ac.w;
            t += __shfl_xor(t, 1, 64);
            t += __shfl_xor(t, 2, 64);
            t += __shfl_xor(t, 4, 64);
            float p = val[k] ? __expf(t) : 0.f;
            den += p;
            acc.x += p * xv[k].x;
            acc.y += p * xv[k].y;
            acc.z += p * xv[k].z;
            acc.w += p * xv[k].w;
        }
    }

    den   += __shfl_xor(den,   32, 64);
    acc.x += __shfl_xor(acc.x, 32, 64);
    acc.y += __shfl_xor(acc.y, 32, 64);
    acc.z += __shfl_xor(acc.z, 32, 64);
    acc.w += __shfl_xor(acc.w, 32, 64);

    if (half == 0) {
        float r = 1.f / den;
        float4 o;
        o.x = fmaxf(acc.x * r + bc.x, 0.f);
        o.y = fmaxf(acc.y * r + bc.y, 0.f);
        o.z = fmaxf(acc.z * r + bc.z, 0.f);
        o.w = fmaxf(acc.w * r + bc.w, 0.f);
        reinterpret_cast<float4*>(outp)[(size_t)d * 32 + q] = o;
    }
}

// ---------------------------------------------------------------------------
// Layer-2 fused gather. ONE wave per node; float4 per lane.
// Lane = g*16 + h*8 + q:  g = edge sub-slot 0..3, h in {mu,lv}, q = col-chunk.
// Per-(edge,head) reduce = 3 shfl steps over 8-lane q-group; g-groups
// combined at the end via xor-16 then xor-32.
// ---------------------------------------------------------------------------
__global__ __launch_bounds__(256) void gat_gather2(
    const float* __restrict__ xlmu, const float* __restrict__ xrmu,
    const float* __restrict__ atmu, const float* __restrict__ bmu,
    const float* __restrict__ xllv, const float* __restrict__ xrlv,
    const float* __restrict__ atlv, const float* __restrict__ blv,
    const int* __restrict__ offs, const int* __restrict__ csr,
    float* __restrict__ out)
{
    int d = (blockIdx.x * 256 + threadIdx.x) >> 6;
    if (d >= NNODES) return;
    int lane = threadIdx.x & 63;
    int g = lane >> 4;
    int h = (lane >> 3) & 1;
    int q = lane & 7;

    const float4* xlp = reinterpret_cast<const float4*>(h ? xllv : xlmu);
    float4 xrc = reinterpret_cast<const float4*>(h ? xrlv : xrmu)[(size_t)d * 8 + q];
    float4 ac  = reinterpret_cast<const float4*>(h ? atlv : atmu)[q];
    float4 bc  = reinterpret_cast<const float4*>(h ? blv  : bmu )[q];

    int beg = offs[d], end = offs[d + 1];
    float den = 0.f;
    float4 acc = make_float4(0.f, 0.f, 0.f, 0.f);

    for (int base = beg; base < end; base += 8) {
        int   si[2];
        bool  val[2];
        float4 xv[2];
        #pragma unroll
        for (int k = 0; k < 2; ++k) {
            int sl = base + 4 * k + g;
            val[k] = sl < end;
            si[k]  = csr[val[k] ? sl : end - 1];
        }
        #pragma unroll
        for (int k = 0; k < 2; ++k)
            xv[k] = xlp[(size_t)si[k] * 8 + q];
        #pragma unroll
        for (int k = 0; k < 2; ++k) {
            float t = lrelu(xv[k].x + xrc.x) * ac.x
                    + lrelu(xv[k].y + xrc.y) * ac.y
                    + lrelu(xv[k].z + xrc.z) * ac.z
                    + lrelu(xv[k].w + xrc.w) * ac.w;
            t += __shfl_xor(t, 1, 64);
            t += __shfl_xor(t, 2, 64);
            t += __shfl_xor(t, 4, 64);
            float p = val[k] ? __expf(t) : 0.f;
            den += p;
            acc.x += p * xv[k].x;
            acc.y += p * xv[k].y;
            acc.z += p * xv[k].z;
            acc.w += p * xv[k].w;
        }
    }

    den   += __shfl_xor(den,   16, 64);
    den   += __shfl_xor(den,   32, 64);
    acc.x += __shfl_xor(acc.x, 16, 64); acc.x += __shfl_xor(acc.x, 32, 64);
    acc.y += __shfl_xor(acc.y, 16, 64); acc.y += __shfl_xor(acc.y, 32, 64);
    acc.z += __shfl_xor(acc.z, 16, 64); acc.z += __shfl_xor(acc.z, 32, 64);
    acc.w += __shfl_xor(acc.w, 16, 64); acc.w += __shfl_xor(acc.w, 32, 64);

    if (g == 0) {
        float r = 1.f / den;
        float4 o;
        o.x = acc.x * r + bc.x;
        o.y = acc.y * r + bc.y;
        o.z = acc.z * r + bc.z;
        o.w = acc.w * r + bc.w;
        float* op = out + (h ? 1600000 : 0);
        reinterpret_cast<float4*>(op)[(size_t)d * 8 + q] = o;
    }
}

extern "C" void kernel_launch(void* const* d_in, const int* in_sizes, int n_in,
                              void* d_out, int out_size, void* d_ws, size_t ws_size,
                              hipStream_t stream) {
    const float* x    = (const float*)d_in[0];
    const int*   ei   = (const int*)d_in[1];
    const float* Wl1  = (const float*)d_in[2];
    const float* bl1  = (const float*)d_in[3];
    const float* Wr1  = (const float*)d_in[4];
    const float* br1  = (const float*)d_in[5];
    const float* att1 = (const float*)d_in[6];
    const float* b1   = (const float*)d_in[7];
    const float* Wlmu = (const float*)d_in[8];
    const float* blmu = (const float*)d_in[9];
    const float* Wrmu = (const float*)d_in[10];
    const float* brmu = (const float*)d_in[11];
    const float* atmu = (const float*)d_in[12];
    const float* bmu  = (const float*)d_in[13];
    const float* Wllv = (const float*)d_in[14];
    const float* bllv = (const float*)d_in[15];
    const float* Wrlv = (const float*)d_in[16];
    const float* brlv = (const float*)d_in[17];
    const float* atlv = (const float*)d_in[18];
    const float* blv  = (const float*)d_in[19];

    float* out = (float*)d_out;
    float* ws  = (float*)d_ws;

    float* xl1 = ws;                 // 6.4M floats
    float* xr1 = ws + 6400000;       // 6.4M
    float* h   = ws + 12800000;      // 6.4M

    // layer-2 transforms alias xl1/xr1 (dead after layer-1 gather)
    float* xlmu = ws;
    float* xrmu = ws + 1600000;
    float* xllv = ws + 3200000;
    float* xrlv = ws + 4800000;

    int* ip       = (int*)(ws + 19200000);
    int* deg      = ip;               // 50,000
    int* offs     = ip + 50000;       // 50,001
    int* partials = ip + 100001;      // 256
    int* csr      = ip + 100257;      // 1,650,000

    const int* srcp = ei;
    const int* dstp = ei + EORIG;

    const int NB1 = (NNODES + 255) / 256;   // 196

    // ---- CSR build ----
    hipMemsetAsync(deg, 0, NNODES * sizeof(int), stream);
    hist_kernel<<<(ETOT + 255) / 256, 256, 0, stream>>>(dstp, deg);
    scan1_kernel<<<NB1, 256, 0, stream>>>(deg, offs, partials);
    scan2_kernel<<<1, 256, 0, stream>>>(partials, NB1);
    scan3_kernel<<<NB1, 256, 0, stream>>>(offs, partials);
    scatter_kernel<<<(ETOT + 255) / 256, 256, 0, stream>>>(srcp, dstp, offs, deg, csr);

    // ---- layer 1 ----
    lin_kernel<128,128><<<(NNODES + 7) / 8, 256, 0, stream>>>(
        x, Wl1, bl1, Wr1, br1, xl1, xr1, NNODES);

    gat_gather1<<<(NNODES * 64 + 255) / 256, 256, 0, stream>>>(
        xl1, xr1, att1, b1, offs, csr, h);

    // ---- layer 2 ----
    lin_kernel<128,32><<<(NNODES + 31) / 32, 256, 0, stream>>>(
        h, Wlmu, blmu, Wrmu, brmu, xlmu, xrmu, NNODES);
    lin_kernel<128,32><<<(NNODES + 31) / 32, 256, 0, stream>>>(
        h, Wllv, bllv, Wrlv, brlv, xllv, xrlv, NNODES);

    gat_gather2<<<(NNODES * 64 + 255) / 256, 256, 0, stream>>>(
        xlmu, xrmu, atmu, bmu, xllv, xrlv, atlv, blv, offs, csr, out);
}

// Round 5
// 383.928 us; speedup vs baseline: 12.6826x; 1.2143x over previous
//
#include <hip/hip_runtime.h>
#include <hip/hip_fp16.h>

#define NNODES 50000
#define EORIG  1600000
#define ETOT   (EORIG + NNODES)
#define NEG 0.2f

__device__ __forceinline__ float lrelu(float v) { return fmaxf(v, NEG * v); }

// ---------------------------------------------------------------------------
// Layer-1 dual linear: xl16 = half(x@Wl+bl) [N][128], xr = x@Wr+br f32 [N][128].
// 256 thr = 32 col-groups(8 cols) x 8 row-groups(8 rows) -> 64 rows/block.
// Register-blocked: each LDS float4 feeds 32 FMAs (8 LDS-bytes/FMA -> 1).
// ---------------------------------------------------------------------------
__global__ __launch_bounds__(256) void lin1_kernel(
    const float* __restrict__ x,
    const float* __restrict__ Wl, const float* __restrict__ bl,
    const float* __restrict__ Wr, const float* __restrict__ br,
    __half* __restrict__ xl16, float* __restrict__ xr)
{
    __shared__ float xs[64 * 128];          // 32 KB
    const int r0 = blockIdx.x * 64;

    const float4* x4 = reinterpret_cast<const float4*>(x);
    float4* xs4 = reinterpret_cast<float4*>(xs);
    for (int i = threadIdx.x; i < 64 * 32; i += 256) {
        int row = r0 + (i >> 5);
        xs4[i] = (row < NNODES) ? x4[(size_t)row * 32 + (i & 31)]
                                : make_float4(0.f, 0.f, 0.f, 0.f);
    }
    __syncthreads();

    const int cg = threadIdx.x & 31;        // col-group: cols cg*8 in [0,256)
    const int rg = threadIdx.x >> 5;        // row-group: rows rg*8
    const bool left = cg < 16;              // xl side vs xr side
    const int c0 = (cg & 15) * 8;           // col within side
    const float4* W4 = reinterpret_cast<const float4*>(left ? Wl : Wr); // [128][32 f4]
    const int wc = c0 >> 2;

    float acc[8][8];
    #pragma unroll
    for (int r = 0; r < 8; ++r)
        #pragma unroll
        for (int c = 0; c < 8; ++c) acc[r][c] = 0.f;

    const float4* xsr = reinterpret_cast<const float4*>(xs) + (rg * 8) * 32;

    for (int k4 = 0; k4 < 32; ++k4) {
        float4 xv[8];
        #pragma unroll
        for (int r = 0; r < 8; ++r) xv[r] = xsr[r * 32 + k4];
        #pragma unroll
        for (int kk = 0; kk < 4; ++kk) {
            float4 wa = W4[(k4 * 4 + kk) * 32 + wc];
            float4 wb = W4[(k4 * 4 + kk) * 32 + wc + 1];
            #pragma unroll
            for (int r = 0; r < 8; ++r) {
                float xk = kk == 0 ? xv[r].x : kk == 1 ? xv[r].y
                         : kk == 2 ? xv[r].z : xv[r].w;
                acc[r][0] += xk * wa.x; acc[r][1] += xk * wa.y;
                acc[r][2] += xk * wa.z; acc[r][3] += xk * wa.w;
                acc[r][4] += xk * wb.x; acc[r][5] += xk * wb.y;
                acc[r][6] += xk * wb.z; acc[r][7] += xk * wb.w;
            }
        }
    }

    const float* bp = left ? bl : br;
    float bv[8];
    #pragma unroll
    for (int c = 0; c < 8; ++c) bv[c] = bp[c0 + c];

    #pragma unroll
    for (int r = 0; r < 8; ++r) {
        int row = r0 + rg * 8 + r;
        if (row >= NNODES) continue;
        if (left) {
            __half hv[8];
            #pragma unroll
            for (int c = 0; c < 8; ++c) hv[c] = __float2half(acc[r][c] + bv[c]);
            *reinterpret_cast<uint4*>(&xl16[(size_t)row * 128 + c0]) =
                *reinterpret_cast<uint4*>(hv);
        } else {
            float4 o1 = make_float4(acc[r][0]+bv[0], acc[r][1]+bv[1],
                                    acc[r][2]+bv[2], acc[r][3]+bv[3]);
            float4 o2 = make_float4(acc[r][4]+bv[4], acc[r][5]+bv[5],
                                    acc[r][6]+bv[6], acc[r][7]+bv[7]);
            float4* op = reinterpret_cast<float4*>(xr) + (size_t)row * 32 + (c0 >> 2);
            op[0] = o1; op[1] = o2;
        }
    }
}

// ---------------------------------------------------------------------------
// Layer-2 fused quad linear (reads h once): outputs
//   xi16 [N][64] fp16 interleaved [xlmu 0-31 | xllv 32-63]
//   xr2  [N][64] f32  interleaved [xrmu 0-31 | xrlv 32-63]
// 256 thr = 16 col-groups(8) x 16 row-groups(8) -> 128 rows/block, 64 KB LDS.
// ---------------------------------------------------------------------------
__global__ __launch_bounds__(256) void lin2_kernel(
    const float* __restrict__ h,
    const float* __restrict__ Wlmu, const float* __restrict__ blmu,
    const float* __restrict__ Wllv, const float* __restrict__ bllv,
    const float* __restrict__ Wrmu, const float* __restrict__ brmu,
    const float* __restrict__ Wrlv, const float* __restrict__ brlv,
    __half* __restrict__ xi16, float* __restrict__ xr2)
{
    __shared__ float xs[128 * 128];         // 64 KB
    const int r0 = blockIdx.x * 128;

    const float4* h4 = reinterpret_cast<const float4*>(h);
    float4* xs4 = reinterpret_cast<float4*>(xs);
    for (int i = threadIdx.x; i < 128 * 32; i += 256) {
        int row = r0 + (i >> 5);
        xs4[i] = (row < NNODES) ? h4[(size_t)row * 32 + (i & 31)]
                                : make_float4(0.f, 0.f, 0.f, 0.f);
    }
    __syncthreads();

    const int cg = threadIdx.x & 15;        // 0..15
    const int rg = threadIdx.x >> 4;        // 0..15
    const int sel = cg >> 2;                // 0 xlmu, 1 xllv, 2 xrmu, 3 xrlv
    const int c0 = (cg & 3) * 8;
    const float* Wsel = sel == 0 ? Wlmu : sel == 1 ? Wllv : sel == 2 ? Wrmu : Wrlv;
    const float* bsel = sel == 0 ? blmu : sel == 1 ? bllv : sel == 2 ? brmu : brlv;
    const float4* W4 = reinterpret_cast<const float4*>(Wsel);  // [128][8 f4]
    const int wc = c0 >> 2;

    float acc[8][8];
    #pragma unroll
    for (int r = 0; r < 8; ++r)
        #pragma unroll
        for (int c = 0; c < 8; ++c) acc[r][c] = 0.f;

    const float4* xsr = reinterpret_cast<const float4*>(xs) + (rg * 8) * 32;

    for (int k4 = 0; k4 < 32; ++k4) {
        float4 xv[8];
        #pragma unroll
        for (int r = 0; r < 8; ++r) xv[r] = xsr[r * 32 + k4];
        #pragma unroll
        for (int kk = 0; kk < 4; ++kk) {
            float4 wa = W4[(k4 * 4 + kk) * 8 + wc];
            float4 wb = W4[(k4 * 4 + kk) * 8 + wc + 1];
            #pragma unroll
            for (int r = 0; r < 8; ++r) {
                float xk = kk == 0 ? xv[r].x : kk == 1 ? xv[r].y
                         : kk == 2 ? xv[r].z : xv[r].w;
                acc[r][0] += xk * wa.x; acc[r][1] += xk * wa.y;
                acc[r][2] += xk * wa.z; acc[r][3] += xk * wa.w;
                acc[r][4] += xk * wb.x; acc[r][5] += xk * wb.y;
                acc[r][6] += xk * wb.z; acc[r][7] += xk * wb.w;
            }
        }
    }

    float bv[8];
    #pragma unroll
    for (int c = 0; c < 8; ++c) bv[c] = bsel[c0 + c];
    const int pos = (sel & 1) ? 32 + c0 : c0;    // mu chunk | lv chunk

    #pragma unroll
    for (int r = 0; r < 8; ++r) {
        int row = r0 + rg * 8 + r;
        if (row >= NNODES) continue;
        if (sel < 2) {
            __half hv[8];
            #pragma unroll
            for (int c = 0; c < 8; ++c) hv[c] = __float2half(acc[r][c] + bv[c]);
            *reinterpret_cast<uint4*>(&xi16[(size_t)row * 64 + pos]) =
                *reinterpret_cast<uint4*>(hv);
        } else {
            float4 o1 = make_float4(acc[r][0]+bv[0], acc[r][1]+bv[1],
                                    acc[r][2]+bv[2], acc[r][3]+bv[3]);
            float4 o2 = make_float4(acc[r][4]+bv[4], acc[r][5]+bv[5],
                                    acc[r][6]+bv[6], acc[r][7]+bv[7]);
            float4* op = reinterpret_cast<float4*>(xr2) + (size_t)row * 16 + (pos >> 2);
            op[0] = o1; op[1] = o2;
        }
    }
}

// ---------------------------------------------------------------------------
// CSR build: histogram -> exclusive scan -> scatter (src ids, bucket by dst)
// ---------------------------------------------------------------------------
__global__ __launch_bounds__(256) void hist_kernel(
    const int* __restrict__ dst, int* __restrict__ deg)
{
    int e = blockIdx.x * 256 + threadIdx.x;
    if (e >= ETOT) return;
    int d = (e < EORIG) ? dst[e] : e - EORIG;
    atomicAdd(deg + d, 1);
}

__global__ __launch_bounds__(256) void scan1_kernel(
    const int* __restrict__ deg, int* __restrict__ offs, int* __restrict__ partials)
{
    __shared__ int tmp[256];
    int t = threadIdx.x;
    int i = blockIdx.x * 256 + t;
    int v = (i < NNODES) ? deg[i] : 0;
    tmp[t] = v;
    __syncthreads();
    for (int off = 1; off < 256; off <<= 1) {
        int a = (t >= off) ? tmp[t - off] : 0;
        __syncthreads();
        tmp[t] += a;
        __syncthreads();
    }
    if (i < NNODES) offs[i] = tmp[t] - v;
    if (t == 255) partials[blockIdx.x] = tmp[255];
}

__global__ __launch_bounds__(256) void scan2_kernel(int* __restrict__ partials, int nb)
{
    __shared__ int tmp[256];
    int t = threadIdx.x;
    int v = (t < nb) ? partials[t] : 0;
    tmp[t] = v;
    __syncthreads();
    for (int off = 1; off < 256; off <<= 1) {
        int a = (t >= off) ? tmp[t - off] : 0;
        __syncthreads();
        tmp[t] += a;
        __syncthreads();
    }
    if (t < nb) partials[t] = tmp[t] - v;
}

__global__ __launch_bounds__(256) void scan3_kernel(
    int* __restrict__ offs, const int* __restrict__ partials)
{
    int i = blockIdx.x * 256 + threadIdx.x;
    if (i < NNODES) offs[i] += partials[blockIdx.x];
    if (i == 0) offs[NNODES] = ETOT;
}

__global__ __launch_bounds__(256) void scatter_kernel(
    const int* __restrict__ src, const int* __restrict__ dst,
    const int* __restrict__ offs, int* __restrict__ deg /* destroyed */,
    int* __restrict__ csr)
{
    int e = blockIdx.x * 256 + threadIdx.x;
    if (e >= ETOT) return;
    int s, d;
    if (e < EORIG) { s = src[e]; d = dst[e]; }
    else           { s = e - EORIG; d = s; }
    int old = atomicSub(deg + d, 1);
    csr[offs[d] + old - 1] = s;
}

// ---------------------------------------------------------------------------
// Layer-1 gather, fp16 rows. One wave per node. lane = quarter*16 + q.
// q = 16B chunk (8 ch); head = q>>2. One load instr = 4 full 256B rows.
// 8 edges / iter (2 per quarter). den/acc per (edge-set, head) per lane,
// combined via xor16+xor32.
// ---------------------------------------------------------------------------
__global__ __launch_bounds__(256) void gat_gather1(
    const __half* __restrict__ xl16, const float* __restrict__ xr,
    const float* __restrict__ att, const float* __restrict__ bias,
    const int* __restrict__ offs, const int* __restrict__ csr,
    float* __restrict__ outp)
{
    int d = (blockIdx.x * 256 + threadIdx.x) >> 6;
    if (d >= NNODES) return;
    int lane = threadIdx.x & 63;
    int quarter = lane >> 4;
    int q = lane & 15;

    float xrc[8], atc[8];
    {
        const float4* p = reinterpret_cast<const float4*>(xr) + (size_t)d * 32 + q * 2;
        float4 a = p[0], b = p[1];
        xrc[0]=a.x; xrc[1]=a.y; xrc[2]=a.z; xrc[3]=a.w;
        xrc[4]=b.x; xrc[5]=b.y; xrc[6]=b.z; xrc[7]=b.w;
        const float4* t = reinterpret_cast<const float4*>(att) + q * 2;
        float4 c = t[0], e = t[1];
        atc[0]=c.x; atc[1]=c.y; atc[2]=c.z; atc[3]=c.w;
        atc[4]=e.x; atc[5]=e.y; atc[6]=e.z; atc[7]=e.w;
    }

    int beg = offs[d], end = offs[d + 1];   // deg >= 1 (self-loop)
    float den = 0.f;
    float acc[8] = {0.f,0.f,0.f,0.f,0.f,0.f,0.f,0.f};
    const uint4* xlu = reinterpret_cast<const uint4*>(xl16);

    for (int base = beg; base < end; base += 8) {
        int si[2]; bool val[2];
        #pragma unroll
        for (int k = 0; k < 2; ++k) {
            int sl = base + quarter * 2 + k;
            val[k] = sl < end;
            si[k]  = csr[val[k] ? sl : end - 1];
        }
        uint4 xv[2];
        #pragma unroll
        for (int k = 0; k < 2; ++k)
            xv[k] = xlu[(size_t)si[k] * 16 + q];
        #pragma unroll
        for (int k = 0; k < 2; ++k) {
            union { uint4 u; __half2 h[4]; } U; U.u = xv[k];
            float f[8];
            #pragma unroll
            for (int j = 0; j < 4; ++j) {
                float2 t2 = __half22float2(U.h[j]);
                f[2*j] = t2.x; f[2*j+1] = t2.y;
            }
            float t = 0.f;
            #pragma unroll
            for (int j = 0; j < 8; ++j) t += lrelu(f[j] + xrc[j]) * atc[j];
            t += __shfl_xor(t, 1, 64);
            t += __shfl_xor(t, 2, 64);
            float p = val[k] ? __expf(t) : 0.f;
            den += p;
            #pragma unroll
            for (int j = 0; j < 8; ++j) acc[j] += p * f[j];
        }
    }

    den += __shfl_xor(den, 16, 64);
    den += __shfl_xor(den, 32, 64);
    #pragma unroll
    for (int j = 0; j < 8; ++j) {
        acc[j] += __shfl_xor(acc[j], 16, 64);
        acc[j] += __shfl_xor(acc[j], 32, 64);
    }

    if (quarter == 0) {
        float r = 1.f / den;
        const float4* bp = reinterpret_cast<const float4*>(bias) + q * 2;
        float4 ba = bp[0], bb = bp[1];
        float4 o1 = make_float4(fmaxf(acc[0]*r+ba.x,0.f), fmaxf(acc[1]*r+ba.y,0.f),
                                fmaxf(acc[2]*r+ba.z,0.f), fmaxf(acc[3]*r+ba.w,0.f));
        float4 o2 = make_float4(fmaxf(acc[4]*r+bb.x,0.f), fmaxf(acc[5]*r+bb.y,0.f),
                                fmaxf(acc[6]*r+bb.z,0.f), fmaxf(acc[7]*r+bb.w,0.f));
        float4* op = reinterpret_cast<float4*>(outp) + (size_t)d * 32 + q * 2;
        op[0] = o1; op[1] = o2;
    }
}

// ---------------------------------------------------------------------------
// Layer-2 gather, fp16 interleaved rows [mu|lv] (128B). One wave per node.
// lane = oct*8 + r; r<4 -> mu chunk r, r>=4 -> lv chunk r-4. One load instr
// = 8 full rows (8 edges). 16 edges / iter (2 per oct). Combine octs at end.
// ---------------------------------------------------------------------------
__global__ __launch_bounds__(256) void gat_gather2(
    const __half* __restrict__ xi16, const float* __restrict__ xr2,
    const float* __restrict__ atmu, const float* __restrict__ atlv,
    const float* __restrict__ bmu,  const float* __restrict__ blv,
    const int* __restrict__ offs, const int* __restrict__ csr,
    float* __restrict__ out)
{
    int d = (blockIdx.x * 256 + threadIdx.x) >> 6;
    if (d >= NNODES) return;
    int lane = threadIdx.x & 63;
    int oct = lane >> 3;
    int r   = lane & 7;
    bool lv = r >= 4;
    int cq  = lv ? r - 4 : r;           // chunk within head

    float xrc[8], atc[8];
    {
        const float4* p = reinterpret_cast<const float4*>(xr2) + (size_t)d * 16 + r * 2;
        float4 a = p[0], b = p[1];
        xrc[0]=a.x; xrc[1]=a.y; xrc[2]=a.z; xrc[3]=a.w;
        xrc[4]=b.x; xrc[5]=b.y; xrc[6]=b.z; xrc[7]=b.w;
        const float4* t = reinterpret_cast<const float4*>(lv ? atlv : atmu) + cq * 2;
        float4 c = t[0], e = t[1];
        atc[0]=c.x; atc[1]=c.y; atc[2]=c.z; atc[3]=c.w;
        atc[4]=e.x; atc[5]=e.y; atc[6]=e.z; atc[7]=e.w;
    }

    int beg = offs[d], end = offs[d + 1];
    float den = 0.f;
    float acc[8] = {0.f,0.f,0.f,0.f,0.f,0.f,0.f,0.f};
    const uint4* xiu = reinterpret_cast<const uint4*>(xi16);

    for (int base = beg; base < end; base += 16) {
        int si[2]; bool val[2];
        #pragma unroll
        for (int k = 0; k < 2; ++k) {
            int sl = base + oct * 2 + k;
            val[k] = sl < end;
            si[k]  = csr[val[k] ? sl : end - 1];
        }
        uint4 xv[2];
        #pragma unroll
        for (int k = 0; k < 2; ++k)
            xv[k] = xiu[(size_t)si[k] * 8 + r];
        #pragma unroll
        for (int k = 0; k < 2; ++k) {
            union { uint4 u; __half2 h[4]; } U; U.u = xv[k];
            float f[8];
            #pragma unroll
            for (int j = 0; j < 4; ++j) {
                float2 t2 = __half22float2(U.h[j]);
                f[2*j] = t2.x; f[2*j+1] = t2.y;
            }
            float t = 0.f;
            #pragma unroll
            for (int j = 0; j < 8; ++j) t += lrelu(f[j] + xrc[j]) * atc[j];
            t += __shfl_xor(t, 1, 64);
            t += __shfl_xor(t, 2, 64);
            float p = val[k] ? __expf(t) : 0.f;
            den += p;
            #pragma unroll
            for (int j = 0; j < 8; ++j) acc[j] += p * f[j];
        }
    }

    den += __shfl_xor(den, 8, 64);
    den += __shfl_xor(den, 16, 64);
    den += __shfl_xor(den, 32, 64);
    #pragma unroll
    for (int j = 0; j < 8; ++j) {
        acc[j] += __shfl_xor(acc[j], 8, 64);
        acc[j] += __shfl_xor(acc[j], 16, 64);
        acc[j] += __shfl_xor(acc[j], 32, 64);
    }

    if (oct == 0) {
        float rr = 1.f / den;
        const float4* bp = reinterpret_cast<const float4*>(lv ? blv : bmu) + cq * 2;
        float4 ba = bp[0], bb = bp[1];
        float4 o1 = make_float4(acc[0]*rr+ba.x, acc[1]*rr+ba.y,
                                acc[2]*rr+ba.z, acc[3]*rr+ba.w);
        float4 o2 = make_float4(acc[4]*rr+bb.x, acc[5]*rr+bb.y,
                                acc[6]*rr+bb.z, acc[7]*rr+bb.w);
        float* base_out = out + (lv ? 1600000 : 0);
        float4* op = reinterpret_cast<float4*>(base_out) + (size_t)d * 8 + cq * 2;
        op[0] = o1; op[1] = o2;
    }
}

extern "C" void kernel_launch(void* const* d_in, const int* in_sizes, int n_in,
                              void* d_out, int out_size, void* d_ws, size_t ws_size,
                              hipStream_t stream) {
    const float* x    = (const float*)d_in[0];
    const int*   ei   = (const int*)d_in[1];
    const float* Wl1  = (const float*)d_in[2];
    const float* bl1  = (const float*)d_in[3];
    const float* Wr1  = (const float*)d_in[4];
    const float* br1  = (const float*)d_in[5];
    const float* att1 = (const float*)d_in[6];
    const float* b1   = (const float*)d_in[7];
    const float* Wlmu = (const float*)d_in[8];
    const float* blmu = (const float*)d_in[9];
    const float* Wrmu = (const float*)d_in[10];
    const float* brmu = (const float*)d_in[11];
    const float* atmu = (const float*)d_in[12];
    const float* bmu  = (const float*)d_in[13];
    const float* Wllv = (const float*)d_in[14];
    const float* bllv = (const float*)d_in[15];
    const float* Wrlv = (const float*)d_in[16];
    const float* brlv = (const float*)d_in[17];
    const float* atlv = (const float*)d_in[18];
    const float* blv  = (const float*)d_in[19];

    float* out = (float*)d_out;
    float* ws  = (float*)d_ws;

    float*  xr1  = ws;                               // 6.4M f32
    float*  h    = ws + 6400000;                     // 6.4M f32
    __half* xl16 = (__half*)(ws + 12800000);         // 6.4M halves (3.2M f32)

    // layer-2 buffers alias xr1/xl16 region (dead after gat_gather1)
    __half* xi16 = (__half*)ws;                      // 3.2M halves (1.6M f32)
    float*  xr2  = ws + 1600000;                     // 3.2M f32

    int* ip       = (int*)(ws + 16000000);
    int* deg      = ip;                              // 50,000
    int* offs     = ip + 50000;                      // 50,001
    int* partials = ip + 100001;                     // 256
    int* csr      = ip + 100257;                     // 1,650,000

    const int* srcp = ei;
    const int* dstp = ei + EORIG;

    const int NB1 = (NNODES + 255) / 256;            // 196

    // ---- CSR build ----
    hipMemsetAsync(deg, 0, NNODES * sizeof(int), stream);
    hist_kernel<<<(ETOT + 255) / 256, 256, 0, stream>>>(dstp, deg);
    scan1_kernel<<<NB1, 256, 0, stream>>>(deg, offs, partials);
    scan2_kernel<<<1, 256, 0, stream>>>(partials, NB1);
    scan3_kernel<<<NB1, 256, 0, stream>>>(offs, partials);
    scatter_kernel<<<(ETOT + 255) / 256, 256, 0, stream>>>(srcp, dstp, offs, deg, csr);

    // ---- layer 1 ----
    lin1_kernel<<<(NNODES + 63) / 64, 256, 0, stream>>>(
        x, Wl1, bl1, Wr1, br1, xl16, xr1);

    gat_gather1<<<(NNODES * 64 + 255) / 256, 256, 0, stream>>>(
        xl16, xr1, att1, b1, offs, csr, h);

    // ---- layer 2 ----
    lin2_kernel<<<(NNODES + 127) / 128, 256, 0, stream>>>(
        h, Wlmu, blmu, Wllv, bllv, Wrmu, brmu, Wrlv, brlv, xi16, xr2);

    gat_gather2<<<(NNODES * 64 + 255) / 256, 256, 0, stream>>>(
        xi16, xr2, atmu, atlv, bmu, blv, offs, csr, out);
}

// Round 6
// 335.331 us; speedup vs baseline: 14.5205x; 1.1449x over previous
//
#include <hip/hip_runtime.h>
#include <hip/hip_fp16.h>

#define NNODES 50000
#define EORIG  1600000
#define ETOT   (EORIG + NNODES)
#define NEG 0.2f
#define BSH 7
#define NBUCK ((NNODES + 127) >> BSH)   // 391

__device__ __forceinline__ float lrelu(float v) { return fmaxf(v, NEG * v); }

// ---------------------------------------------------------------------------
// Layer-1 dual linear: xl16 = half(x@Wl+bl) [N][128], xr = x@Wr+br f32 [N][128].
// ---------------------------------------------------------------------------
__global__ __launch_bounds__(256) void lin1_kernel(
    const float* __restrict__ x,
    const float* __restrict__ Wl, const float* __restrict__ bl,
    const float* __restrict__ Wr, const float* __restrict__ br,
    __half* __restrict__ xl16, float* __restrict__ xr)
{
    __shared__ float xs[64 * 128];          // 32 KB
    const int r0 = blockIdx.x * 64;

    const float4* x4 = reinterpret_cast<const float4*>(x);
    float4* xs4 = reinterpret_cast<float4*>(xs);
    for (int i = threadIdx.x; i < 64 * 32; i += 256) {
        int row = r0 + (i >> 5);
        xs4[i] = (row < NNODES) ? x4[(size_t)row * 32 + (i & 31)]
                                : make_float4(0.f, 0.f, 0.f, 0.f);
    }
    __syncthreads();

    const int cg = threadIdx.x & 31;
    const int rg = threadIdx.x >> 5;
    const bool left = cg < 16;
    const int c0 = (cg & 15) * 8;
    const float4* W4 = reinterpret_cast<const float4*>(left ? Wl : Wr);
    const int wc = c0 >> 2;

    float acc[8][8];
    #pragma unroll
    for (int r = 0; r < 8; ++r)
        #pragma unroll
        for (int c = 0; c < 8; ++c) acc[r][c] = 0.f;

    const float4* xsr = reinterpret_cast<const float4*>(xs) + (rg * 8) * 32;

    for (int k4 = 0; k4 < 32; ++k4) {
        float4 xv[8];
        #pragma unroll
        for (int r = 0; r < 8; ++r) xv[r] = xsr[r * 32 + k4];
        #pragma unroll
        for (int kk = 0; kk < 4; ++kk) {
            float4 wa = W4[(k4 * 4 + kk) * 32 + wc];
            float4 wb = W4[(k4 * 4 + kk) * 32 + wc + 1];
            #pragma unroll
            for (int r = 0; r < 8; ++r) {
                float xk = kk == 0 ? xv[r].x : kk == 1 ? xv[r].y
                         : kk == 2 ? xv[r].z : xv[r].w;
                acc[r][0] += xk * wa.x; acc[r][1] += xk * wa.y;
                acc[r][2] += xk * wa.z; acc[r][3] += xk * wa.w;
                acc[r][4] += xk * wb.x; acc[r][5] += xk * wb.y;
                acc[r][6] += xk * wb.z; acc[r][7] += xk * wb.w;
            }
        }
    }

    const float* bp = left ? bl : br;
    float bv[8];
    #pragma unroll
    for (int c = 0; c < 8; ++c) bv[c] = bp[c0 + c];

    #pragma unroll
    for (int r = 0; r < 8; ++r) {
        int row = r0 + rg * 8 + r;
        if (row >= NNODES) continue;
        if (left) {
            __half hv[8];
            #pragma unroll
            for (int c = 0; c < 8; ++c) hv[c] = __float2half(acc[r][c] + bv[c]);
            *reinterpret_cast<uint4*>(&xl16[(size_t)row * 128 + c0]) =
                *reinterpret_cast<uint4*>(hv);
        } else {
            float4 o1 = make_float4(acc[r][0]+bv[0], acc[r][1]+bv[1],
                                    acc[r][2]+bv[2], acc[r][3]+bv[3]);
            float4 o2 = make_float4(acc[r][4]+bv[4], acc[r][5]+bv[5],
                                    acc[r][6]+bv[6], acc[r][7]+bv[7]);
            float4* op = reinterpret_cast<float4*>(xr) + (size_t)row * 32 + (c0 >> 2);
            op[0] = o1; op[1] = o2;
        }
    }
}

// ---------------------------------------------------------------------------
// Layer-2 fused quad linear (reads h once).
// ---------------------------------------------------------------------------
__global__ __launch_bounds__(256) void lin2_kernel(
    const float* __restrict__ h,
    const float* __restrict__ Wlmu, const float* __restrict__ blmu,
    const float* __restrict__ Wllv, const float* __restrict__ bllv,
    const float* __restrict__ Wrmu, const float* __restrict__ brmu,
    const float* __restrict__ Wrlv, const float* __restrict__ brlv,
    __half* __restrict__ xi16, float* __restrict__ xr2)
{
    __shared__ float xs[128 * 128];         // 64 KB
    const int r0 = blockIdx.x * 128;

    const float4* h4 = reinterpret_cast<const float4*>(h);
    float4* xs4 = reinterpret_cast<float4*>(xs);
    for (int i = threadIdx.x; i < 128 * 32; i += 256) {
        int row = r0 + (i >> 5);
        xs4[i] = (row < NNODES) ? h4[(size_t)row * 32 + (i & 31)]
                                : make_float4(0.f, 0.f, 0.f, 0.f);
    }
    __syncthreads();

    const int cg = threadIdx.x & 15;
    const int rg = threadIdx.x >> 4;
    const int sel = cg >> 2;                // 0 xlmu, 1 xllv, 2 xrmu, 3 xrlv
    const int c0 = (cg & 3) * 8;
    const float* Wsel = sel == 0 ? Wlmu : sel == 1 ? Wllv : sel == 2 ? Wrmu : Wrlv;
    const float* bsel = sel == 0 ? blmu : sel == 1 ? bllv : sel == 2 ? brmu : brlv;
    const float4* W4 = reinterpret_cast<const float4*>(Wsel);
    const int wc = c0 >> 2;

    float acc[8][8];
    #pragma unroll
    for (int r = 0; r < 8; ++r)
        #pragma unroll
        for (int c = 0; c < 8; ++c) acc[r][c] = 0.f;

    const float4* xsr = reinterpret_cast<const float4*>(xs) + (rg * 8) * 32;

    for (int k4 = 0; k4 < 32; ++k4) {
        float4 xv[8];
        #pragma unroll
        for (int r = 0; r < 8; ++r) xv[r] = xsr[r * 32 + k4];
        #pragma unroll
        for (int kk = 0; kk < 4; ++kk) {
            float4 wa = W4[(k4 * 4 + kk) * 8 + wc];
            float4 wb = W4[(k4 * 4 + kk) * 8 + wc + 1];
            #pragma unroll
            for (int r = 0; r < 8; ++r) {
                float xk = kk == 0 ? xv[r].x : kk == 1 ? xv[r].y
                         : kk == 2 ? xv[r].z : xv[r].w;
                acc[r][0] += xk * wa.x; acc[r][1] += xk * wa.y;
                acc[r][2] += xk * wa.z; acc[r][3] += xk * wa.w;
                acc[r][4] += xk * wb.x; acc[r][5] += xk * wb.y;
                acc[r][6] += xk * wb.z; acc[r][7] += xk * wb.w;
            }
        }
    }

    float bv[8];
    #pragma unroll
    for (int c = 0; c < 8; ++c) bv[c] = bsel[c0 + c];
    const int pos = (sel & 1) ? 32 + c0 : c0;

    #pragma unroll
    for (int r = 0; r < 8; ++r) {
        int row = r0 + rg * 8 + r;
        if (row >= NNODES) continue;
        if (sel < 2) {
            __half hv[8];
            #pragma unroll
            for (int c = 0; c < 8; ++c) hv[c] = __float2half(acc[r][c] + bv[c]);
            *reinterpret_cast<uint4*>(&xi16[(size_t)row * 64 + pos]) =
                *reinterpret_cast<uint4*>(hv);
        } else {
            float4 o1 = make_float4(acc[r][0]+bv[0], acc[r][1]+bv[1],
                                    acc[r][2]+bv[2], acc[r][3]+bv[3]);
            float4 o2 = make_float4(acc[r][4]+bv[4], acc[r][5]+bv[5],
                                    acc[r][6]+bv[6], acc[r][7]+bv[7]);
            float4* op = reinterpret_cast<float4*>(xr2) + (size_t)row * 16 + (pos >> 2);
            op[0] = o1; op[1] = o2;
        }
    }
}

// ---------------------------------------------------------------------------
// CSR build, locality-staged.
// ---------------------------------------------------------------------------
__global__ __launch_bounds__(256) void hist_kernel(
    const int* __restrict__ dst, int* __restrict__ deg)
{
    int e = blockIdx.x * 256 + threadIdx.x;
    if (e >= ETOT) return;
    int d = (e < EORIG) ? dst[e] : e - EORIG;
    atomicAdd(deg + d, 1);
}

__global__ __launch_bounds__(256) void scan1_kernel(
    const int* __restrict__ deg, int* __restrict__ offs, int* __restrict__ partials)
{
    __shared__ int tmp[256];
    int t = threadIdx.x;
    int i = blockIdx.x * 256 + t;
    int v = (i < NNODES) ? deg[i] : 0;
    tmp[t] = v;
    __syncthreads();
    for (int off = 1; off < 256; off <<= 1) {
        int a = (t >= off) ? tmp[t - off] : 0;
        __syncthreads();
        tmp[t] += a;
        __syncthreads();
    }
    if (i < NNODES) offs[i] = tmp[t] - v;
    if (t == 255) partials[blockIdx.x] = tmp[255];
}

__global__ __launch_bounds__(256) void scan2_kernel(int* __restrict__ partials, int nb)
{
    __shared__ int tmp[256];
    int t = threadIdx.x;
    int v = (t < nb) ? partials[t] : 0;
    tmp[t] = v;
    __syncthreads();
    for (int off = 1; off < 256; off <<= 1) {
        int a = (t >= off) ? tmp[t - off] : 0;
        __syncthreads();
        tmp[t] += a;
        __syncthreads();
    }
    if (t < nb) partials[t] = tmp[t] - v;
}

// adds block base; also emits bucket cursors bcur[b] = offs[b<<BSH]
__global__ __launch_bounds__(256) void scan3_kernel(
    int* __restrict__ offs, const int* __restrict__ partials, int* __restrict__ bcur)
{
    int i = blockIdx.x * 256 + threadIdx.x;
    if (i < NNODES) {
        int nv = offs[i] + partials[blockIdx.x];
        offs[i] = nv;
        if ((i & ((1 << BSH) - 1)) == 0) bcur[i >> BSH] = nv;
    }
    if (i == 0) offs[NNODES] = ETOT;
}

// Partition edges into dst-bucket-ordered (src,dst) pairs. 8192 edges/block.
// Per (block,bucket) writes are contiguous -> line-dense, single-XCD.
__global__ __launch_bounds__(256) void part_kernel(
    const int* __restrict__ src, const int* __restrict__ dst,
    int* __restrict__ bcur, int2* __restrict__ pairs)
{
    __shared__ int cnt[NBUCK];
    __shared__ int gbase[NBUCK];
    const int e0 = blockIdx.x * 8192;

    for (int i = threadIdx.x; i < NBUCK; i += 256) cnt[i] = 0;
    __syncthreads();

    for (int i = threadIdx.x; i < 8192; i += 256) {
        int e = e0 + i;
        if (e >= ETOT) break;
        int d = (e < EORIG) ? dst[e] : e - EORIG;
        atomicAdd(&cnt[d >> BSH], 1);
    }
    __syncthreads();

    for (int b = threadIdx.x; b < NBUCK; b += 256) {
        int c = cnt[b];
        gbase[b] = c ? atomicAdd(&bcur[b], c) : 0;
        cnt[b] = 0;                           // reuse as running slot counter
    }
    __syncthreads();

    for (int i = threadIdx.x; i < 8192; i += 256) {
        int e = e0 + i;
        if (e >= ETOT) break;
        int s, d;
        if (e < EORIG) { s = src[e]; d = dst[e]; }
        else           { s = d = e - EORIG; }
        int b = d >> BSH;
        int slot = atomicAdd(&cnt[b], 1);
        pairs[gbase[b] + slot] = make_int2(s, d);
    }
}

// One block per bucket: fill csr from the bucket's contiguous pair range.
// Slots via LDS atomics; csr writes confined to a ~17 KB single-XCD window.
__global__ __launch_bounds__(256) void csrfill_kernel(
    const int2* __restrict__ pairs, const int* __restrict__ offs,
    int* __restrict__ csr)
{
    __shared__ int lofs[129];
    __shared__ int cnt[128];
    const int n0 = blockIdx.x << BSH;
    const int nn = min(128, NNODES - n0);

    for (int i = threadIdx.x; i < nn + 1; i += 256) lofs[i] = offs[n0 + i];
    for (int i = threadIdx.x; i < 128; i += 256) cnt[i] = 0;
    __syncthreads();

    const int pbeg = lofs[0], pend = lofs[nn];
    for (int i = pbeg + threadIdx.x; i < pend; i += 256) {
        int2 pr = pairs[i];
        int lidx = pr.y - n0;
        int slot = atomicAdd(&cnt[lidx], 1);
        csr[lofs[lidx] + slot] = pr.x;
    }
}

// ---------------------------------------------------------------------------
// Layer-1 gather, fp16 rows. One wave per node. lane = quarter*16 + q.
// ---------------------------------------------------------------------------
__global__ __launch_bounds__(256) void gat_gather1(
    const __half* __restrict__ xl16, const float* __restrict__ xr,
    const float* __restrict__ att, const float* __restrict__ bias,
    const int* __restrict__ offs, const int* __restrict__ csr,
    float* __restrict__ outp)
{
    int d = (blockIdx.x * 256 + threadIdx.x) >> 6;
    if (d >= NNODES) return;
    int lane = threadIdx.x & 63;
    int quarter = lane >> 4;
    int q = lane & 15;

    float xrc[8], atc[8];
    {
        const float4* p = reinterpret_cast<const float4*>(xr) + (size_t)d * 32 + q * 2;
        float4 a = p[0], b = p[1];
        xrc[0]=a.x; xrc[1]=a.y; xrc[2]=a.z; xrc[3]=a.w;
        xrc[4]=b.x; xrc[5]=b.y; xrc[6]=b.z; xrc[7]=b.w;
        const float4* t = reinterpret_cast<const float4*>(att) + q * 2;
        float4 c = t[0], e = t[1];
        atc[0]=c.x; atc[1]=c.y; atc[2]=c.z; atc[3]=c.w;
        atc[4]=e.x; atc[5]=e.y; atc[6]=e.z; atc[7]=e.w;
    }

    int beg = offs[d], end = offs[d + 1];
    float den = 0.f;
    float acc[8] = {0.f,0.f,0.f,0.f,0.f,0.f,0.f,0.f};
    const uint4* xlu = reinterpret_cast<const uint4*>(xl16);

    for (int base = beg; base < end; base += 8) {
        int si[2]; bool val[2];
        #pragma unroll
        for (int k = 0; k < 2; ++k) {
            int sl = base + quarter * 2 + k;
            val[k] = sl < end;
            si[k]  = csr[val[k] ? sl : end - 1];
        }
        uint4 xv[2];
        #pragma unroll
        for (int k = 0; k < 2; ++k)
            xv[k] = xlu[(size_t)si[k] * 16 + q];
        #pragma unroll
        for (int k = 0; k < 2; ++k) {
            union { uint4 u; __half2 h[4]; } U; U.u = xv[k];
            float f[8];
            #pragma unroll
            for (int j = 0; j < 4; ++j) {
                float2 t2 = __half22float2(U.h[j]);
                f[2*j] = t2.x; f[2*j+1] = t2.y;
            }
            float t = 0.f;
            #pragma unroll
            for (int j = 0; j < 8; ++j) t += lrelu(f[j] + xrc[j]) * atc[j];
            t += __shfl_xor(t, 1, 64);
            t += __shfl_xor(t, 2, 64);
            float p = val[k] ? __expf(t) : 0.f;
            den += p;
            #pragma unroll
            for (int j = 0; j < 8; ++j) acc[j] += p * f[j];
        }
    }

    den += __shfl_xor(den, 16, 64);
    den += __shfl_xor(den, 32, 64);
    #pragma unroll
    for (int j = 0; j < 8; ++j) {
        acc[j] += __shfl_xor(acc[j], 16, 64);
        acc[j] += __shfl_xor(acc[j], 32, 64);
    }

    if (quarter == 0) {
        float r = 1.f / den;
        const float4* bp = reinterpret_cast<const float4*>(bias) + q * 2;
        float4 ba = bp[0], bb = bp[1];
        float4 o1 = make_float4(fmaxf(acc[0]*r+ba.x,0.f), fmaxf(acc[1]*r+ba.y,0.f),
                                fmaxf(acc[2]*r+ba.z,0.f), fmaxf(acc[3]*r+ba.w,0.f));
        float4 o2 = make_float4(fmaxf(acc[4]*r+bb.x,0.f), fmaxf(acc[5]*r+bb.y,0.f),
                                fmaxf(acc[6]*r+bb.z,0.f), fmaxf(acc[7]*r+bb.w,0.f));
        float4* op = reinterpret_cast<float4*>(outp) + (size_t)d * 32 + q * 2;
        op[0] = o1; op[1] = o2;
    }
}

// ---------------------------------------------------------------------------
// Layer-2 gather, fp16 interleaved rows [mu|lv]. One wave per node.
// ---------------------------------------------------------------------------
__global__ __launch_bounds__(256) void gat_gather2(
    const __half* __restrict__ xi16, const float* __restrict__ xr2,
    const float* __restrict__ atmu, const float* __restrict__ atlv,
    const float* __restrict__ bmu,  const float* __restrict__ blv,
    const int* __restrict__ offs, const int* __restrict__ csr,
    float* __restrict__ out)
{
    int d = (blockIdx.x * 256 + threadIdx.x) >> 6;
    if (d >= NNODES) return;
    int lane = threadIdx.x & 63;
    int oct = lane >> 3;
    int r   = lane & 7;
    bool lv = r >= 4;
    int cq  = lv ? r - 4 : r;

    float xrc[8], atc[8];
    {
        const float4* p = reinterpret_cast<const float4*>(xr2) + (size_t)d * 16 + r * 2;
        float4 a = p[0], b = p[1];
        xrc[0]=a.x; xrc[1]=a.y; xrc[2]=a.z; xrc[3]=a.w;
        xrc[4]=b.x; xrc[5]=b.y; xrc[6]=b.z; xrc[7]=b.w;
        const float4* t = reinterpret_cast<const float4*>(lv ? atlv : atmu) + cq * 2;
        float4 c = t[0], e = t[1];
        atc[0]=c.x; atc[1]=c.y; atc[2]=c.z; atc[3]=c.w;
        atc[4]=e.x; atc[5]=e.y; atc[6]=e.z; atc[7]=e.w;
    }

    int beg = offs[d], end = offs[d + 1];
    float den = 0.f;
    float acc[8] = {0.f,0.f,0.f,0.f,0.f,0.f,0.f,0.f};
    const uint4* xiu = reinterpret_cast<const uint4*>(xi16);

    for (int base = beg; base < end; base += 16) {
        int si[2]; bool val[2];
        #pragma unroll
        for (int k = 0; k < 2; ++k) {
            int sl = base + oct * 2 + k;
            val[k] = sl < end;
            si[k]  = csr[val[k] ? sl : end - 1];
        }
        uint4 xv[2];
        #pragma unroll
        for (int k = 0; k < 2; ++k)
            xv[k] = xiu[(size_t)si[k] * 8 + r];
        #pragma unroll
        for (int k = 0; k < 2; ++k) {
            union { uint4 u; __half2 h[4]; } U; U.u = xv[k];
            float f[8];
            #pragma unroll
            for (int j = 0; j < 4; ++j) {
                float2 t2 = __half22float2(U.h[j]);
                f[2*j] = t2.x; f[2*j+1] = t2.y;
            }
            float t = 0.f;
            #pragma unroll
            for (int j = 0; j < 8; ++j) t += lrelu(f[j] + xrc[j]) * atc[j];
            t += __shfl_xor(t, 1, 64);
            t += __shfl_xor(t, 2, 64);
            float p = val[k] ? __expf(t) : 0.f;
            den += p;
            #pragma unroll
            for (int j = 0; j < 8; ++j) acc[j] += p * f[j];
        }
    }

    den += __shfl_xor(den, 8, 64);
    den += __shfl_xor(den, 16, 64);
    den += __shfl_xor(den, 32, 64);
    #pragma unroll
    for (int j = 0; j < 8; ++j) {
        acc[j] += __shfl_xor(acc[j], 8, 64);
        acc[j] += __shfl_xor(acc[j], 16, 64);
        acc[j] += __shfl_xor(acc[j], 32, 64);
    }

    if (oct == 0) {
        float rr = 1.f / den;
        const float4* bp = reinterpret_cast<const float4*>(lv ? blv : bmu) + cq * 2;
        float4 ba = bp[0], bb = bp[1];
        float4 o1 = make_float4(acc[0]*rr+ba.x, acc[1]*rr+ba.y,
                                acc[2]*rr+ba.z, acc[3]*rr+ba.w);
        float4 o2 = make_float4(acc[4]*rr+bb.x, acc[5]*rr+bb.y,
                                acc[6]*rr+bb.z, acc[7]*rr+bb.w);
        float* base_out = out + (lv ? 1600000 : 0);
        float4* op = reinterpret_cast<float4*>(base_out) + (size_t)d * 8 + cq * 2;
        op[0] = o1; op[1] = o2;
    }
}

extern "C" void kernel_launch(void* const* d_in, const int* in_sizes, int n_in,
                              void* d_out, int out_size, void* d_ws, size_t ws_size,
                              hipStream_t stream) {
    const float* x    = (const float*)d_in[0];
    const int*   ei   = (const int*)d_in[1];
    const float* Wl1  = (const float*)d_in[2];
    const float* bl1  = (const float*)d_in[3];
    const float* Wr1  = (const float*)d_in[4];
    const float* br1  = (const float*)d_in[5];
    const float* att1 = (const float*)d_in[6];
    const float* b1   = (const float*)d_in[7];
    const float* Wlmu = (const float*)d_in[8];
    const float* blmu = (const float*)d_in[9];
    const float* Wrmu = (const float*)d_in[10];
    const float* brmu = (const float*)d_in[11];
    const float* atmu = (const float*)d_in[12];
    const float* bmu  = (const float*)d_in[13];
    const float* Wllv = (const float*)d_in[14];
    const float* bllv = (const float*)d_in[15];
    const float* Wrlv = (const float*)d_in[16];
    const float* brlv = (const float*)d_in[17];
    const float* atlv = (const float*)d_in[18];
    const float* blv  = (const float*)d_in[19];

    float* out = (float*)d_out;
    float* ws  = (float*)d_ws;

    float*  xr1  = ws;                               // 6.4M f32
    float*  h    = ws + 6400000;                     // 6.4M f32
    __half* xl16 = (__half*)(ws + 12800000);         // 6.4M halves

    // layer-2 buffers alias xr1/xl16 region (dead after gat_gather1)
    __half* xi16 = (__half*)ws;                      // 3.2M halves
    float*  xr2  = ws + 1600000;                     // 3.2M f32

    int*  ip       = (int*)(ws + 16000000);
    int2* pairs    = (int2*)ip;                      // 1,650,000 int2 (8B-aligned)
    int*  deg      = ip + 3300000;                   // 50,000
    int*  offs     = ip + 3350000;                   // 50,001
    int*  partials = ip + 3400001;                   // 256
    int*  bcur     = ip + 3400257;                   // 512
    int*  csr      = ip + 3400769;                   // 1,650,000

    const int* srcp = ei;
    const int* dstp = ei + EORIG;

    const int NB1 = (NNODES + 255) / 256;            // 196

    // ---- CSR build (locality-staged) ----
    hipMemsetAsync(deg, 0, NNODES * sizeof(int), stream);
    hist_kernel<<<(ETOT + 255) / 256, 256, 0, stream>>>(dstp, deg);
    scan1_kernel<<<NB1, 256, 0, stream>>>(deg, offs, partials);
    scan2_kernel<<<1, 256, 0, stream>>>(partials, NB1);
    scan3_kernel<<<NB1, 256, 0, stream>>>(offs, partials, bcur);
    part_kernel<<<(ETOT + 8191) / 8192, 256, 0, stream>>>(srcp, dstp, bcur, pairs);
    csrfill_kernel<<<NBUCK, 256, 0, stream>>>(pairs, offs, csr);

    // ---- layer 1 ----
    lin1_kernel<<<(NNODES + 63) / 64, 256, 0, stream>>>(
        x, Wl1, bl1, Wr1, br1, xl16, xr1);

    gat_gather1<<<(NNODES * 64 + 255) / 256, 256, 0, stream>>>(
        xl16, xr1, att1, b1, offs, csr, h);

    // ---- layer 2 ----
    lin2_kernel<<<(NNODES + 127) / 128, 256, 0, stream>>>(
        h, Wlmu, blmu, Wllv, bllv, Wrmu, brmu, Wrlv, brlv, xi16, xr2);

    gat_gather2<<<(NNODES * 64 + 255) / 256, 256, 0, stream>>>(
        xi16, xr2, atmu, atlv, bmu, blv, offs, csr, out);
}

// Round 8
// 243.474 us; speedup vs baseline: 19.9988x; 1.3773x over previous
//
#include <hip/hip_runtime.h>
#include <hip/hip_fp16.h>

#define NNODES 50000
#define EORIG  1600000
#define ETOT   (EORIG + NNODES)
#define NEG 0.2f
#define BSH 7
#define NBUCK ((NNODES + 127) >> BSH)   // 391

typedef _Float16 v2h __attribute__((ext_vector_type(2)));

__device__ __forceinline__ float hdot2v(v2h a, v2h b, float c) {
#if __has_builtin(__builtin_amdgcn_fdot2)
    return __builtin_amdgcn_fdot2(a, b, c, false);
#else
    return c + (float)a.x * (float)b.x + (float)a.y * (float)b.y;
#endif
}

// ---------------------------------------------------------------------------
// Layer-1 dual linear: xl16 = half(x@Wl+bl), xr16 = half(x@Wr+br), [N][128].
// ---------------------------------------------------------------------------
__global__ __launch_bounds__(256) void lin1_kernel(
    const float* __restrict__ x,
    const float* __restrict__ Wl, const float* __restrict__ bl,
    const float* __restrict__ Wr, const float* __restrict__ br,
    __half* __restrict__ xl16, __half* __restrict__ xr16)
{
    __shared__ float xs[64 * 128];          // 32 KB
    const int r0 = blockIdx.x * 64;

    const float4* x4 = reinterpret_cast<const float4*>(x);
    float4* xs4 = reinterpret_cast<float4*>(xs);
    for (int i = threadIdx.x; i < 64 * 32; i += 256) {
        int row = r0 + (i >> 5);
        xs4[i] = (row < NNODES) ? x4[(size_t)row * 32 + (i & 31)]
                                : make_float4(0.f, 0.f, 0.f, 0.f);
    }
    __syncthreads();

    const int cg = threadIdx.x & 31;
    const int rg = threadIdx.x >> 5;
    const bool left = cg < 16;
    const int c0 = (cg & 15) * 8;
    const float4* W4 = reinterpret_cast<const float4*>(left ? Wl : Wr);
    const int wc = c0 >> 2;

    float acc[8][8];
    #pragma unroll
    for (int r = 0; r < 8; ++r)
        #pragma unroll
        for (int c = 0; c < 8; ++c) acc[r][c] = 0.f;

    const float4* xsr = reinterpret_cast<const float4*>(xs) + (rg * 8) * 32;

    for (int k4 = 0; k4 < 32; ++k4) {
        float4 xv[8];
        #pragma unroll
        for (int r = 0; r < 8; ++r) xv[r] = xsr[r * 32 + k4];
        #pragma unroll
        for (int kk = 0; kk < 4; ++kk) {
            float4 wa = W4[(k4 * 4 + kk) * 32 + wc];
            float4 wb = W4[(k4 * 4 + kk) * 32 + wc + 1];
            #pragma unroll
            for (int r = 0; r < 8; ++r) {
                float xk = kk == 0 ? xv[r].x : kk == 1 ? xv[r].y
                         : kk == 2 ? xv[r].z : xv[r].w;
                acc[r][0] += xk * wa.x; acc[r][1] += xk * wa.y;
                acc[r][2] += xk * wa.z; acc[r][3] += xk * wa.w;
                acc[r][4] += xk * wb.x; acc[r][5] += xk * wb.y;
                acc[r][6] += xk * wb.z; acc[r][7] += xk * wb.w;
            }
        }
    }

    const float* bp = left ? bl : br;
    float bv[8];
    #pragma unroll
    for (int c = 0; c < 8; ++c) bv[c] = bp[c0 + c];
    __half* dst16 = left ? xl16 : xr16;

    #pragma unroll
    for (int r = 0; r < 8; ++r) {
        int row = r0 + rg * 8 + r;
        if (row >= NNODES) continue;
        __half hv[8];
        #pragma unroll
        for (int c = 0; c < 8; ++c) hv[c] = __float2half(acc[r][c] + bv[c]);
        *reinterpret_cast<uint4*>(&dst16[(size_t)row * 128 + c0]) =
            *reinterpret_cast<uint4*>(hv);
    }
}

// ---------------------------------------------------------------------------
// Layer-2 fused quad linear (reads h once): xi16 [N][64] = [xlmu|xllv] fp16,
// xrI16 [N][64] = [xrmu|xrlv] fp16.
// ---------------------------------------------------------------------------
__global__ __launch_bounds__(256) void lin2_kernel(
    const float* __restrict__ h,
    const float* __restrict__ Wlmu, const float* __restrict__ blmu,
    const float* __restrict__ Wllv, const float* __restrict__ bllv,
    const float* __restrict__ Wrmu, const float* __restrict__ brmu,
    const float* __restrict__ Wrlv, const float* __restrict__ brlv,
    __half* __restrict__ xi16, __half* __restrict__ xrI16)
{
    __shared__ float xs[128 * 128];         // 64 KB
    const int r0 = blockIdx.x * 128;

    const float4* h4 = reinterpret_cast<const float4*>(h);
    float4* xs4 = reinterpret_cast<float4*>(xs);
    for (int i = threadIdx.x; i < 128 * 32; i += 256) {
        int row = r0 + (i >> 5);
        xs4[i] = (row < NNODES) ? h4[(size_t)row * 32 + (i & 31)]
                                : make_float4(0.f, 0.f, 0.f, 0.f);
    }
    __syncthreads();

    const int cg = threadIdx.x & 15;
    const int rg = threadIdx.x >> 4;
    const int sel = cg >> 2;                // 0 xlmu, 1 xllv, 2 xrmu, 3 xrlv
    const int c0 = (cg & 3) * 8;
    const float* Wsel = sel == 0 ? Wlmu : sel == 1 ? Wllv : sel == 2 ? Wrmu : Wrlv;
    const float* bsel = sel == 0 ? blmu : sel == 1 ? bllv : sel == 2 ? brmu : brlv;
    const float4* W4 = reinterpret_cast<const float4*>(Wsel);
    const int wc = c0 >> 2;

    float acc[8][8];
    #pragma unroll
    for (int r = 0; r < 8; ++r)
        #pragma unroll
        for (int c = 0; c < 8; ++c) acc[r][c] = 0.f;

    const float4* xsr = reinterpret_cast<const float4*>(xs) + (rg * 8) * 32;

    for (int k4 = 0; k4 < 32; ++k4) {
        float4 xv[8];
        #pragma unroll
        for (int r = 0; r < 8; ++r) xv[r] = xsr[r * 32 + k4];
        #pragma unroll
        for (int kk = 0; kk < 4; ++kk) {
            float4 wa = W4[(k4 * 4 + kk) * 8 + wc];
            float4 wb = W4[(k4 * 4 + kk) * 8 + wc + 1];
            #pragma unroll
            for (int r = 0; r < 8; ++r) {
                float xk = kk == 0 ? xv[r].x : kk == 1 ? xv[r].y
                         : kk == 2 ? xv[r].z : xv[r].w;
                acc[r][0] += xk * wa.x; acc[r][1] += xk * wa.y;
                acc[r][2] += xk * wa.z; acc[r][3] += xk * wa.w;
                acc[r][4] += xk * wb.x; acc[r][5] += xk * wb.y;
                acc[r][6] += xk * wb.z; acc[r][7] += xk * wb.w;
            }
        }
    }

    float bv[8];
    #pragma unroll
    for (int c = 0; c < 8; ++c) bv[c] = bsel[c0 + c];
    const int pos = (sel & 1) ? 32 + c0 : c0;
    __half* dst16 = (sel < 2) ? xi16 : xrI16;

    #pragma unroll
    for (int r = 0; r < 8; ++r) {
        int row = r0 + rg * 8 + r;
        if (row >= NNODES) continue;
        __half hv[8];
        #pragma unroll
        for (int c = 0; c < 8; ++c) hv[c] = __float2half(acc[r][c] + bv[c]);
        *reinterpret_cast<uint4*>(&dst16[(size_t)row * 64 + pos]) =
            *reinterpret_cast<uint4*>(hv);
    }
}

// ---------------------------------------------------------------------------
// CSR build: bucket histogram -> tiny scan -> partition -> local fill.
// ---------------------------------------------------------------------------
__global__ __launch_bounds__(256) void bhist_kernel(
    const int* __restrict__ dst, int* __restrict__ btot)
{
    __shared__ int cnt[NBUCK];
    for (int i = threadIdx.x; i < NBUCK; i += 256) cnt[i] = 0;
    __syncthreads();
    const int e0 = blockIdx.x * 8192;
    for (int i = threadIdx.x; i < 8192; i += 256) {
        int e = e0 + i;
        if (e >= ETOT) break;
        int d = (e < EORIG) ? dst[e] : e - EORIG;
        atomicAdd(&cnt[d >> BSH], 1);
    }
    __syncthreads();
    for (int i = threadIdx.x; i < NBUCK; i += 256)
        if (cnt[i]) atomicAdd(&btot[i], cnt[i]);
}

__global__ __launch_bounds__(512) void bscan_kernel(
    const int* __restrict__ btot, int* __restrict__ bbase, int* __restrict__ bcur)
{
    __shared__ int tmp[512];
    int t = threadIdx.x;
    int v = (t < NBUCK) ? btot[t] : 0;
    tmp[t] = v;
    __syncthreads();
    for (int off = 1; off < 512; off <<= 1) {
        int a = (t >= off) ? tmp[t - off] : 0;
        __syncthreads();
        tmp[t] += a;
        __syncthreads();
    }
    if (t < NBUCK) { int e = tmp[t] - v; bbase[t] = e; bcur[t] = e; }
    if (t == 0) bbase[NBUCK] = ETOT;
}

// Partition edges into dst-bucket-ordered (src,dst) pairs. 8192 edges/block.
__global__ __launch_bounds__(256) void part_kernel(
    const int* __restrict__ src, const int* __restrict__ dst,
    int* __restrict__ bcur, int2* __restrict__ pairs)
{
    __shared__ int cnt[NBUCK];
    __shared__ int gbase[NBUCK];
    const int e0 = blockIdx.x * 8192;

    for (int i = threadIdx.x; i < NBUCK; i += 256) cnt[i] = 0;
    __syncthreads();

    for (int i = threadIdx.x; i < 8192; i += 256) {
        int e = e0 + i;
        if (e >= ETOT) break;
        int d = (e < EORIG) ? dst[e] : e - EORIG;
        atomicAdd(&cnt[d >> BSH], 1);
    }
    __syncthreads();

    for (int b = threadIdx.x; b < NBUCK; b += 256) {
        int c = cnt[b];
        gbase[b] = c ? atomicAdd(&bcur[b], c) : 0;
        cnt[b] = 0;
    }
    __syncthreads();

    for (int i = threadIdx.x; i < 8192; i += 256) {
        int e = e0 + i;
        if (e >= ETOT) break;
        int s, d;
        if (e < EORIG) { s = src[e]; d = dst[e]; }
        else           { s = d = e - EORIG; }
        int b = d >> BSH;
        int slot = atomicAdd(&cnt[b], 1);
        pairs[gbase[b] + slot] = make_int2(s, d);
    }
}

// One block per bucket: local degree hist + scan in LDS, writes offs AND csr.
__global__ __launch_bounds__(256) void csrfill_kernel(
    const int2* __restrict__ pairs, const int* __restrict__ bbase,
    int* __restrict__ offs, int* __restrict__ csr)
{
    __shared__ int cnt[128];
    __shared__ int lofs[128];
    __shared__ int scnt[128];
    const int b = blockIdx.x, n0 = b << BSH;
    const int nn = min(128, NNODES - n0);
    const int pbeg = bbase[b], pend = bbase[b + 1];
    const int t = threadIdx.x;

    if (t < 128) { cnt[t] = 0; scnt[t] = 0; }
    __syncthreads();
    for (int i = pbeg + t; i < pend; i += 256)
        atomicAdd(&cnt[pairs[i].y - n0], 1);
    __syncthreads();

    if (t < 128) lofs[t] = cnt[t];
    __syncthreads();
    for (int off = 1; off < 128; off <<= 1) {
        int v = (t < 128 && t >= off) ? lofs[t - off] : 0;
        __syncthreads();
        if (t < 128) lofs[t] += v;
        __syncthreads();
    }
    if (t < 128) lofs[t] = pbeg + lofs[t] - cnt[t];   // exclusive + bucket base
    __syncthreads();

    if (t < nn) offs[n0 + t] = lofs[t];
    if (b == NBUCK - 1 && t == 0) offs[NNODES] = ETOT;

    for (int i = pbeg + t; i < pend; i += 256) {
        int2 pr = pairs[i];
        int l = pr.y - n0;
        int slot = atomicAdd(&scnt[l], 1);
        csr[lofs[l] + slot] = pr.x;
    }
}

// ---------------------------------------------------------------------------
// Layer-1 gather, packed fp16 (v2h). One wave per node. lane = quarter*16+q.
// ---------------------------------------------------------------------------
__global__ __launch_bounds__(256) void gat_gather1(
    const __half* __restrict__ xl16, const __half* __restrict__ xr16,
    const float* __restrict__ att, const float* __restrict__ bias,
    const int* __restrict__ offs, const int* __restrict__ csr,
    float* __restrict__ outp)
{
    int d = (blockIdx.x * 256 + threadIdx.x) >> 6;
    if (d >= NNODES) return;
    int lane = threadIdx.x & 63;
    int quarter = lane >> 4;
    int q = lane & 15;

    v2h xrh[4], ath[4];
    {
        union { uint4 u; v2h v[4]; } R;
        R.u = reinterpret_cast<const uint4*>(xr16)[(size_t)d * 16 + q];
        #pragma unroll
        for (int j = 0; j < 4; ++j) xrh[j] = R.v[j];
        const float4* t4 = reinterpret_cast<const float4*>(att) + q * 2;
        float4 a = t4[0], b = t4[1];
        ath[0] = (v2h){(_Float16)a.x, (_Float16)a.y};
        ath[1] = (v2h){(_Float16)a.z, (_Float16)a.w};
        ath[2] = (v2h){(_Float16)b.x, (_Float16)b.y};
        ath[3] = (v2h){(_Float16)b.z, (_Float16)b.w};
    }
    const v2h neg2 = (v2h){(_Float16)NEG, (_Float16)NEG};

    int beg = offs[d], end = offs[d + 1];
    float den = 0.f;
    float acc[8] = {0.f,0.f,0.f,0.f,0.f,0.f,0.f,0.f};
    const uint4* xlu = reinterpret_cast<const uint4*>(xl16);

    for (int base = beg; base < end; base += 8) {
        int si[2]; bool val[2];
        #pragma unroll
        for (int k = 0; k < 2; ++k) {
            int sl = base + quarter * 2 + k;
            val[k] = sl < end;
            si[k]  = csr[val[k] ? sl : end - 1];
        }
        uint4 xv[2];
        #pragma unroll
        for (int k = 0; k < 2; ++k)
            xv[k] = xlu[(size_t)si[k] * 16 + q];
        #pragma unroll
        for (int k = 0; k < 2; ++k) {
            union { uint4 u; v2h v[4]; } U; U.u = xv[k];
            float t = 0.f;
            #pragma unroll
            for (int j = 0; j < 4; ++j) {
                v2h s = U.v[j] + xrh[j];
                v2h l = __builtin_elementwise_max(s, s * neg2);
                t = hdot2v(l, ath[j], t);
            }
            t += __shfl_xor(t, 1, 64);
            t += __shfl_xor(t, 2, 64);
            float p = val[k] ? __expf(t) : 0.f;
            den += p;
            #pragma unroll
            for (int j = 0; j < 4; ++j) {
                acc[2*j]   += p * (float)U.v[j].x;
                acc[2*j+1] += p * (float)U.v[j].y;
            }
        }
    }

    den += __shfl_xor(den, 16, 64);
    den += __shfl_xor(den, 32, 64);
    #pragma unroll
    for (int j = 0; j < 8; ++j) {
        acc[j] += __shfl_xor(acc[j], 16, 64);
        acc[j] += __shfl_xor(acc[j], 32, 64);
    }

    if (quarter == 0) {
        float r = 1.f / den;
        const float4* bp = reinterpret_cast<const float4*>(bias) + q * 2;
        float4 ba = bp[0], bb = bp[1];
        float4 o1 = make_float4(fmaxf(acc[0]*r+ba.x,0.f), fmaxf(acc[1]*r+ba.y,0.f),
                                fmaxf(acc[2]*r+ba.z,0.f), fmaxf(acc[3]*r+ba.w,0.f));
        float4 o2 = make_float4(fmaxf(acc[4]*r+bb.x,0.f), fmaxf(acc[5]*r+bb.y,0.f),
                                fmaxf(acc[6]*r+bb.z,0.f), fmaxf(acc[7]*r+bb.w,0.f));
        float4* op = reinterpret_cast<float4*>(outp) + (size_t)d * 32 + q * 2;
        op[0] = o1; op[1] = o2;
    }
}

// ---------------------------------------------------------------------------
// Layer-2 gather, packed fp16 (v2h), interleaved [mu|lv]. One wave per node.
// lane = oct*8 + r; r<4 -> mu chunk r, r>=4 -> lv chunk r-4.
// ---------------------------------------------------------------------------
__global__ __launch_bounds__(256) void gat_gather2(
    const __half* __restrict__ xi16, const __half* __restrict__ xrI16,
    const float* __restrict__ atmu, const float* __restrict__ atlv,
    const float* __restrict__ bmu,  const float* __restrict__ blv,
    const int* __restrict__ offs, const int* __restrict__ csr,
    float* __restrict__ out)
{
    int d = (blockIdx.x * 256 + threadIdx.x) >> 6;
    if (d >= NNODES) return;
    int lane = threadIdx.x & 63;
    int oct = lane >> 3;
    int r   = lane & 7;
    bool lv = r >= 4;
    int cq  = lv ? r - 4 : r;

    v2h xrh[4], ath[4];
    {
        union { uint4 u; v2h v[4]; } R;
        R.u = reinterpret_cast<const uint4*>(xrI16)[(size_t)d * 8 + r];
        #pragma unroll
        for (int j = 0; j < 4; ++j) xrh[j] = R.v[j];
        const float4* t4 = reinterpret_cast<const float4*>(lv ? atlv : atmu) + cq * 2;
        float4 a = t4[0], b = t4[1];
        ath[0] = (v2h){(_Float16)a.x, (_Float16)a.y};
        ath[1] = (v2h){(_Float16)a.z, (_Float16)a.w};
        ath[2] = (v2h){(_Float16)b.x, (_Float16)b.y};
        ath[3] = (v2h){(_Float16)b.z, (_Float16)b.w};
    }
    const v2h neg2 = (v2h){(_Float16)NEG, (_Float16)NEG};

    int beg = offs[d], end = offs[d + 1];
    float den = 0.f;
    float acc[8] = {0.f,0.f,0.f,0.f,0.f,0.f,0.f,0.f};
    const uint4* xiu = reinterpret_cast<const uint4*>(xi16);

    for (int base = beg; base < end; base += 16) {
        int si[2]; bool val[2];
        #pragma unroll
        for (int k = 0; k < 2; ++k) {
            int sl = base + oct * 2 + k;
            val[k] = sl < end;
            si[k]  = csr[val[k] ? sl : end - 1];
        }
        uint4 xv[2];
        #pragma unroll
        for (int k = 0; k < 2; ++k)
            xv[k] = xiu[(size_t)si[k] * 8 + r];
        #pragma unroll
        for (int k = 0; k < 2; ++k) {
            union { uint4 u; v2h v[4]; } U; U.u = xv[k];
            float t = 0.f;
            #pragma unroll
            for (int j = 0; j < 4; ++j) {
                v2h s = U.v[j] + xrh[j];
                v2h l = __builtin_elementwise_max(s, s * neg2);
                t = hdot2v(l, ath[j], t);
            }
            t += __shfl_xor(t, 1, 64);
            t += __shfl_xor(t, 2, 64);
            float p = val[k] ? __expf(t) : 0.f;
            den += p;
            #pragma unroll
            for (int j = 0; j < 4; ++j) {
                acc[2*j]   += p * (float)U.v[j].x;
                acc[2*j+1] += p * (float)U.v[j].y;
            }
        }
    }

    den += __shfl_xor(den, 8, 64);
    den += __shfl_xor(den, 16, 64);
    den += __shfl_xor(den, 32, 64);
    #pragma unroll
    for (int j = 0; j < 8; ++j) {
        acc[j] += __shfl_xor(acc[j], 8, 64);
        acc[j] += __shfl_xor(acc[j], 16, 64);
        acc[j] += __shfl_xor(acc[j], 32, 64);
    }

    if (oct == 0) {
        float rr = 1.f / den;
        const float4* bp = reinterpret_cast<const float4*>(lv ? blv : bmu) + cq * 2;
        float4 ba = bp[0], bb = bp[1];
        float4 o1 = make_float4(acc[0]*rr+ba.x, acc[1]*rr+ba.y,
                                acc[2]*rr+ba.z, acc[3]*rr+ba.w);
        float4 o2 = make_float4(acc[4]*rr+bb.x, acc[5]*rr+bb.y,
                                acc[6]*rr+bb.z, acc[7]*rr+bb.w);
        float* base_out = out + (lv ? 1600000 : 0);
        float4* op = reinterpret_cast<float4*>(base_out) + (size_t)d * 8 + cq * 2;
        op[0] = o1; op[1] = o2;
    }
}

extern "C" void kernel_launch(void* const* d_in, const int* in_sizes, int n_in,
                              void* d_out, int out_size, void* d_ws, size_t ws_size,
                              hipStream_t stream) {
    const float* x    = (const float*)d_in[0];
    const int*   ei   = (const int*)d_in[1];
    const float* Wl1  = (const float*)d_in[2];
    const float* bl1  = (const float*)d_in[3];
    const float* Wr1  = (const float*)d_in[4];
    const float* br1  = (const float*)d_in[5];
    const float* att1 = (const float*)d_in[6];
    const float* b1   = (const float*)d_in[7];
    const float* Wlmu = (const float*)d_in[8];
    const float* blmu = (const float*)d_in[9];
    const float* Wrmu = (const float*)d_in[10];
    const float* brmu = (const float*)d_in[11];
    const float* atmu = (const float*)d_in[12];
    const float* bmu  = (const float*)d_in[13];
    const float* Wllv = (const float*)d_in[14];
    const float* bllv = (const float*)d_in[15];
    const float* Wrlv = (const float*)d_in[16];
    const float* brlv = (const float*)d_in[17];
    const float* atlv = (const float*)d_in[18];
    const float* blv  = (const float*)d_in[19];

    float* out = (float*)d_out;
    float* ws  = (float*)d_ws;

    __half* xl16 = (__half*)ws;                      // 6.4M halves
    __half* xr16 = (__half*)(ws + 3200000);          // 6.4M halves
    float*  h    = ws + 6400000;                     // 6.4M f32

    // layer-2 buffers alias xl16/xr16 region (dead after gat_gather1)
    __half* xi16  = (__half*)ws;                     // 3.2M halves
    __half* xrI16 = (__half*)(ws + 1600000);         // 3.2M halves

    int*  ip    = (int*)(ws + 12800000);
    int2* pairs = (int2*)ip;                         // 3,300,000 ints
    int*  btot  = ip + 3300000;                      // 391
    int*  bbase = ip + 3300400;                      // 392
    int*  bcur  = ip + 3300800;                      // 391
    int*  offs  = ip + 3301200;                      // 50,001
    int*  csr   = ip + 3351204;                      // 1,650,000

    const int* srcp = ei;
    const int* dstp = ei + EORIG;

    const int NBE = (ETOT + 8191) / 8192;            // 202

    // ---- CSR build ----
    hipMemsetAsync(btot, 0, NBUCK * sizeof(int), stream);
    bhist_kernel<<<NBE, 256, 0, stream>>>(dstp, btot);
    bscan_kernel<<<1, 512, 0, stream>>>(btot, bbase, bcur);
    part_kernel<<<NBE, 256, 0, stream>>>(srcp, dstp, bcur, pairs);
    csrfill_kernel<<<NBUCK, 256, 0, stream>>>(pairs, bbase, offs, csr);

    // ---- layer 1 ----
    lin1_kernel<<<(NNODES + 63) / 64, 256, 0, stream>>>(
        x, Wl1, bl1, Wr1, br1, xl16, xr16);

    gat_gather1<<<(NNODES * 64 + 255) / 256, 256, 0, stream>>>(
        xl16, xr16, att1, b1, offs, csr, h);

    // ---- layer 2 ----
    lin2_kernel<<<(NNODES + 127) / 128, 256, 0, stream>>>(
        h, Wlmu, blmu, Wllv, bllv, Wrmu, brmu, Wrlv, brlv, xi16, xrI16);

    gat_gather2<<<(NNODES * 64 + 255) / 256, 256, 0, stream>>>(
        xi16, xrI16, atmu, atlv, bmu, blv, offs, csr, out);
}

// Round 9
// 221.029 us; speedup vs baseline: 22.0296x; 1.1015x over previous
//
#include <hip/hip_runtime.h>
#include <hip/hip_fp16.h>

#define NNODES 50000
#define EORIG  1600000
#define ETOT   (EORIG + NNODES)
#define NEG 0.2f
#define BSH 7
#define NBUCK ((NNODES + 127) >> BSH)   // 391
#define NRT (NNODES / 16)               // 3125 row-tiles

typedef _Float16 v2h __attribute__((ext_vector_type(2)));
typedef _Float16 v8h __attribute__((ext_vector_type(8)));
typedef float    v4f __attribute__((ext_vector_type(4)));

__device__ __forceinline__ float hdot2v(v2h a, v2h b, float c) {
#if __has_builtin(__builtin_amdgcn_fdot2)
    return __builtin_amdgcn_fdot2(a, b, c, false);
#else
    return c + (float)a.x * (float)b.x + (float)a.y * (float)b.y;
#endif
}

// ---------------------------------------------------------------------------
// Weight pack: WT [256][128] fp16 (row c = [Wl|Wr] output col c, transposed),
//              WT2 [128][128] fp16 (row c = [Wlmu|Wllv|Wrmu|Wrlv] col).
// ---------------------------------------------------------------------------
__global__ __launch_bounds__(256) void wcvt_kernel(
    const float* __restrict__ Wl, const float* __restrict__ Wr,
    const float* __restrict__ Wlmu, const float* __restrict__ Wllv,
    const float* __restrict__ Wrmu, const float* __restrict__ Wrlv,
    __half* __restrict__ WT, __half* __restrict__ WT2)
{
    int id = blockIdx.x * 256 + threadIdx.x;
    if (id < 32768) {
        int k = id >> 8, c = id & 255;          // coalesced read over c
        float v = (c < 128) ? Wl[k * 128 + c] : Wr[k * 128 + (c - 128)];
        WT[c * 128 + k] = __float2half(v);
    } else if (id < 49152) {
        int loc = id - 32768;
        int k = loc >> 7, c = loc & 127;
        int sel = c >> 5, cc = c & 31;
        const float* W = sel == 0 ? Wlmu : sel == 1 ? Wllv : sel == 2 ? Wrmu : Wrlv;
        WT2[c * 128 + k] = __float2half(W[k * 32 + cc]);
    }
}

// ---------------------------------------------------------------------------
// Layer-1 dual linear via MFMA: xl16|xr16 = half(x @ [Wl|Wr] + [bl|br]).
// One wave per 16-row tile. A: f32 x converted to fp16 fragments in-register.
// B: WT rows (col-major weights), 16B/lane loads. 16 col-tiles x 4 k-steps.
// ---------------------------------------------------------------------------
__global__ __launch_bounds__(256) void lin1_kernel(
    const float* __restrict__ x, const __half* __restrict__ WT,
    const float* __restrict__ bl, const float* __restrict__ br,
    __half* __restrict__ xl16, __half* __restrict__ xr16)
{
    int rt = (blockIdx.x * 256 + threadIdx.x) >> 6;
    if (rt >= NRT) return;
    int l  = threadIdx.x & 63;
    int lr = l & 15, lg = l >> 4;
    int row = rt * 16 + lr;

    v8h a[4];
    const float4* xrow = reinterpret_cast<const float4*>(x + (size_t)row * 128);
    #pragma unroll
    for (int ks = 0; ks < 4; ++ks) {
        float4 f0 = xrow[ks * 8 + lg * 2];
        float4 f1 = xrow[ks * 8 + lg * 2 + 1];
        v8h t;
        t[0]=(_Float16)f0.x; t[1]=(_Float16)f0.y; t[2]=(_Float16)f0.z; t[3]=(_Float16)f0.w;
        t[4]=(_Float16)f1.x; t[5]=(_Float16)f1.y; t[6]=(_Float16)f1.z; t[7]=(_Float16)f1.w;
        a[ks] = t;
    }

    const uint4* wt4 = reinterpret_cast<const uint4*>(WT);   // [256][16 uint4]
    #pragma unroll 4
    for (int ct = 0; ct < 16; ++ct) {
        int c = ct * 16 + lr;
        v4f acc = {0.f, 0.f, 0.f, 0.f};
        #pragma unroll
        for (int ks = 0; ks < 4; ++ks) {
            union { uint4 u; v8h h; } B;
            B.u = wt4[(size_t)c * 16 + ks * 4 + lg];
            acc = __builtin_amdgcn_mfma_f32_16x16x32_f16(a[ks], B.h, acc, 0, 0, 0);
        }
        float bb = (c < 128) ? bl[c] : br[c - 128];
        #pragma unroll
        for (int j = 0; j < 4; ++j) {
            int orow = rt * 16 + lg * 4 + j;
            __half hv = __float2half(acc[j] + bb);
            if (c < 128) xl16[(size_t)orow * 128 + c] = hv;
            else         xr16[(size_t)orow * 128 + (c - 128)] = hv;
        }
    }
}

// ---------------------------------------------------------------------------
// Layer-2 quad linear via MFMA: xi16|xrI16 = half(h16 @ WT2^T + bias).
// A = h16 fp16 rows (direct 16B loads). 8 col-tiles x 4 k-steps.
// ---------------------------------------------------------------------------
__global__ __launch_bounds__(256) void lin2_kernel(
    const __half* __restrict__ h16, const __half* __restrict__ WT2,
    const float* __restrict__ blmu, const float* __restrict__ bllv,
    const float* __restrict__ brmu, const float* __restrict__ brlv,
    __half* __restrict__ xi16, __half* __restrict__ xrI16)
{
    int rt = (blockIdx.x * 256 + threadIdx.x) >> 6;
    if (rt >= NRT) return;
    int l  = threadIdx.x & 63;
    int lr = l & 15, lg = l >> 4;
    int row = rt * 16 + lr;

    v8h a[4];
    const uint4* hrow = reinterpret_cast<const uint4*>(h16 + (size_t)row * 128);
    #pragma unroll
    for (int ks = 0; ks < 4; ++ks) {
        union { uint4 u; v8h h; } A;
        A.u = hrow[ks * 4 + lg];
        a[ks] = A.h;
    }

    const uint4* wt4 = reinterpret_cast<const uint4*>(WT2);  // [128][16 uint4]
    #pragma unroll 4
    for (int ct = 0; ct < 8; ++ct) {
        int c = ct * 16 + lr;
        v4f acc = {0.f, 0.f, 0.f, 0.f};
        #pragma unroll
        for (int ks = 0; ks < 4; ++ks) {
            union { uint4 u; v8h h; } B;
            B.u = wt4[(size_t)c * 16 + ks * 4 + lg];
            acc = __builtin_amdgcn_mfma_f32_16x16x32_f16(a[ks], B.h, acc, 0, 0, 0);
        }
        int sel = c >> 5, cc = c & 31;
        const float* bp = sel == 0 ? blmu : sel == 1 ? bllv : sel == 2 ? brmu : brlv;
        float bb = bp[cc];
        #pragma unroll
        for (int j = 0; j < 4; ++j) {
            int orow = rt * 16 + lg * 4 + j;
            __half hv = __float2half(acc[j] + bb);
            if (c < 64) xi16 [(size_t)orow * 64 + c]      = hv;
            else        xrI16[(size_t)orow * 64 + (c-64)] = hv;
        }
    }
}

// ---------------------------------------------------------------------------
// CSR build: bucket histogram -> tiny scan -> partition -> local fill.
// ---------------------------------------------------------------------------
__global__ __launch_bounds__(256) void bhist_kernel(
    const int* __restrict__ dst, int* __restrict__ btot)
{
    __shared__ int cnt[NBUCK];
    for (int i = threadIdx.x; i < NBUCK; i += 256) cnt[i] = 0;
    __syncthreads();
    const int e0 = blockIdx.x * 8192;
    for (int i = threadIdx.x; i < 8192; i += 256) {
        int e = e0 + i;
        if (e >= ETOT) break;
        int d = (e < EORIG) ? dst[e] : e - EORIG;
        atomicAdd(&cnt[d >> BSH], 1);
    }
    __syncthreads();
    for (int i = threadIdx.x; i < NBUCK; i += 256)
        if (cnt[i]) atomicAdd(&btot[i], cnt[i]);
}

__global__ __launch_bounds__(512) void bscan_kernel(
    const int* __restrict__ btot, int* __restrict__ bbase, int* __restrict__ bcur)
{
    __shared__ int tmp[512];
    int t = threadIdx.x;
    int v = (t < NBUCK) ? btot[t] : 0;
    tmp[t] = v;
    __syncthreads();
    for (int off = 1; off < 512; off <<= 1) {
        int a = (t >= off) ? tmp[t - off] : 0;
        __syncthreads();
        tmp[t] += a;
        __syncthreads();
    }
    if (t < NBUCK) { int e = tmp[t] - v; bbase[t] = e; bcur[t] = e; }
    if (t == 0) bbase[NBUCK] = ETOT;
}

__global__ __launch_bounds__(256) void part_kernel(
    const int* __restrict__ src, const int* __restrict__ dst,
    int* __restrict__ bcur, int2* __restrict__ pairs)
{
    __shared__ int cnt[NBUCK];
    __shared__ int gbase[NBUCK];
    const int e0 = blockIdx.x * 8192;

    for (int i = threadIdx.x; i < NBUCK; i += 256) cnt[i] = 0;
    __syncthreads();

    for (int i = threadIdx.x; i < 8192; i += 256) {
        int e = e0 + i;
        if (e >= ETOT) break;
        int d = (e < EORIG) ? dst[e] : e - EORIG;
        atomicAdd(&cnt[d >> BSH], 1);
    }
    __syncthreads();

    for (int b = threadIdx.x; b < NBUCK; b += 256) {
        int c = cnt[b];
        gbase[b] = c ? atomicAdd(&bcur[b], c) : 0;
        cnt[b] = 0;
    }
    __syncthreads();

    for (int i = threadIdx.x; i < 8192; i += 256) {
        int e = e0 + i;
        if (e >= ETOT) break;
        int s, d;
        if (e < EORIG) { s = src[e]; d = dst[e]; }
        else           { s = d = e - EORIG; }
        int b = d >> BSH;
        int slot = atomicAdd(&cnt[b], 1);
        pairs[gbase[b] + slot] = make_int2(s, d);
    }
}

__global__ __launch_bounds__(256) void csrfill_kernel(
    const int2* __restrict__ pairs, const int* __restrict__ bbase,
    int* __restrict__ offs, int* __restrict__ csr)
{
    __shared__ int cnt[128];
    __shared__ int lofs[128];
    __shared__ int scnt[128];
    const int b = blockIdx.x, n0 = b << BSH;
    const int nn = min(128, NNODES - n0);
    const int pbeg = bbase[b], pend = bbase[b + 1];
    const int t = threadIdx.x;

    if (t < 128) { cnt[t] = 0; scnt[t] = 0; }
    __syncthreads();
    for (int i = pbeg + t; i < pend; i += 256)
        atomicAdd(&cnt[pairs[i].y - n0], 1);
    __syncthreads();

    if (t < 128) lofs[t] = cnt[t];
    __syncthreads();
    for (int off = 1; off < 128; off <<= 1) {
        int v = (t < 128 && t >= off) ? lofs[t - off] : 0;
        __syncthreads();
        if (t < 128) lofs[t] += v;
        __syncthreads();
    }
    if (t < 128) lofs[t] = pbeg + lofs[t] - cnt[t];
    __syncthreads();

    if (t < nn) offs[n0 + t] = lofs[t];
    if (b == NBUCK - 1 && t == 0) offs[NNODES] = ETOT;

    for (int i = pbeg + t; i < pend; i += 256) {
        int2 pr = pairs[i];
        int l = pr.y - n0;
        int slot = atomicAdd(&scnt[l], 1);
        csr[lofs[l] + slot] = pr.x;
    }
}

// ---------------------------------------------------------------------------
// Layer-1 gather, packed fp16 (v2h). One wave per node. Writes h16 fp16.
// ---------------------------------------------------------------------------
__global__ __launch_bounds__(256) void gat_gather1(
    const __half* __restrict__ xl16, const __half* __restrict__ xr16,
    const float* __restrict__ att, const float* __restrict__ bias,
    const int* __restrict__ offs, const int* __restrict__ csr,
    __half* __restrict__ h16)
{
    int d = (blockIdx.x * 256 + threadIdx.x) >> 6;
    if (d >= NNODES) return;
    int lane = threadIdx.x & 63;
    int quarter = lane >> 4;
    int q = lane & 15;

    v2h xrh[4], ath[4];
    {
        union { uint4 u; v2h v[4]; } R;
        R.u = reinterpret_cast<const uint4*>(xr16)[(size_t)d * 16 + q];
        #pragma unroll
        for (int j = 0; j < 4; ++j) xrh[j] = R.v[j];
        const float4* t4 = reinterpret_cast<const float4*>(att) + q * 2;
        float4 a = t4[0], b = t4[1];
        ath[0] = (v2h){(_Float16)a.x, (_Float16)a.y};
        ath[1] = (v2h){(_Float16)a.z, (_Float16)a.w};
        ath[2] = (v2h){(_Float16)b.x, (_Float16)b.y};
        ath[3] = (v2h){(_Float16)b.z, (_Float16)b.w};
    }
    const v2h neg2 = (v2h){(_Float16)NEG, (_Float16)NEG};

    int beg = offs[d], end = offs[d + 1];
    float den = 0.f;
    float acc[8] = {0.f,0.f,0.f,0.f,0.f,0.f,0.f,0.f};
    const uint4* xlu = reinterpret_cast<const uint4*>(xl16);

    for (int base = beg; base < end; base += 8) {
        int si[2]; bool val[2];
        #pragma unroll
        for (int k = 0; k < 2; ++k) {
            int sl = base + quarter * 2 + k;
            val[k] = sl < end;
            si[k]  = csr[val[k] ? sl : end - 1];
        }
        uint4 xv[2];
        #pragma unroll
        for (int k = 0; k < 2; ++k)
            xv[k] = xlu[(size_t)si[k] * 16 + q];
        #pragma unroll
        for (int k = 0; k < 2; ++k) {
            union { uint4 u; v2h v[4]; } U; U.u = xv[k];
            float t = 0.f;
            #pragma unroll
            for (int j = 0; j < 4; ++j) {
                v2h s = U.v[j] + xrh[j];
                v2h l = __builtin_elementwise_max(s, s * neg2);
                t = hdot2v(l, ath[j], t);
            }
            t += __shfl_xor(t, 1, 64);
            t += __shfl_xor(t, 2, 64);
            float p = val[k] ? __expf(t) : 0.f;
            den += p;
            #pragma unroll
            for (int j = 0; j < 4; ++j) {
                acc[2*j]   += p * (float)U.v[j].x;
                acc[2*j+1] += p * (float)U.v[j].y;
            }
        }
    }

    den += __shfl_xor(den, 16, 64);
    den += __shfl_xor(den, 32, 64);
    #pragma unroll
    for (int j = 0; j < 8; ++j) {
        acc[j] += __shfl_xor(acc[j], 16, 64);
        acc[j] += __shfl_xor(acc[j], 32, 64);
    }

    if (quarter == 0) {
        float r = 1.f / den;
        const float4* bp = reinterpret_cast<const float4*>(bias) + q * 2;
        float4 ba = bp[0], bb = bp[1];
        __half hv[8];
        hv[0] = __float2half(fmaxf(acc[0]*r+ba.x, 0.f));
        hv[1] = __float2half(fmaxf(acc[1]*r+ba.y, 0.f));
        hv[2] = __float2half(fmaxf(acc[2]*r+ba.z, 0.f));
        hv[3] = __float2half(fmaxf(acc[3]*r+ba.w, 0.f));
        hv[4] = __float2half(fmaxf(acc[4]*r+bb.x, 0.f));
        hv[5] = __float2half(fmaxf(acc[5]*r+bb.y, 0.f));
        hv[6] = __float2half(fmaxf(acc[6]*r+bb.z, 0.f));
        hv[7] = __float2half(fmaxf(acc[7]*r+bb.w, 0.f));
        *reinterpret_cast<uint4*>(&h16[(size_t)d * 128 + q * 8]) =
            *reinterpret_cast<uint4*>(hv);
    }
}

// ---------------------------------------------------------------------------
// Layer-2 gather, packed fp16 (v2h), interleaved [mu|lv]. One wave per node.
// ---------------------------------------------------------------------------
__global__ __launch_bounds__(256) void gat_gather2(
    const __half* __restrict__ xi16, const __half* __restrict__ xrI16,
    const float* __restrict__ atmu, const float* __restrict__ atlv,
    const float* __restrict__ bmu,  const float* __restrict__ blv,
    const int* __restrict__ offs, const int* __restrict__ csr,
    float* __restrict__ out)
{
    int d = (blockIdx.x * 256 + threadIdx.x) >> 6;
    if (d >= NNODES) return;
    int lane = threadIdx.x & 63;
    int oct = lane >> 3;
    int r   = lane & 7;
    bool lv = r >= 4;
    int cq  = lv ? r - 4 : r;

    v2h xrh[4], ath[4];
    {
        union { uint4 u; v2h v[4]; } R;
        R.u = reinterpret_cast<const uint4*>(xrI16)[(size_t)d * 8 + r];
        #pragma unroll
        for (int j = 0; j < 4; ++j) xrh[j] = R.v[j];
        const float4* t4 = reinterpret_cast<const float4*>(lv ? atlv : atmu) + cq * 2;
        float4 a = t4[0], b = t4[1];
        ath[0] = (v2h){(_Float16)a.x, (_Float16)a.y};
        ath[1] = (v2h){(_Float16)a.z, (_Float16)a.w};
        ath[2] = (v2h){(_Float16)b.x, (_Float16)b.y};
        ath[3] = (v2h){(_Float16)b.z, (_Float16)b.w};
    }
    const v2h neg2 = (v2h){(_Float16)NEG, (_Float16)NEG};

    int beg = offs[d], end = offs[d + 1];
    float den = 0.f;
    float acc[8] = {0.f,0.f,0.f,0.f,0.f,0.f,0.f,0.f};
    const uint4* xiu = reinterpret_cast<const uint4*>(xi16);

    for (int base = beg; base < end; base += 16) {
        int si[2]; bool val[2];
        #pragma unroll
        for (int k = 0; k < 2; ++k) {
            int sl = base + oct * 2 + k;
            val[k] = sl < end;
            si[k]  = csr[val[k] ? sl : end - 1];
        }
        uint4 xv[2];
        #pragma unroll
        for (int k = 0; k < 2; ++k)
            xv[k] = xiu[(size_t)si[k] * 8 + r];
        #pragma unroll
        for (int k = 0; k < 2; ++k) {
            union { uint4 u; v2h v[4]; } U; U.u = xv[k];
            float t = 0.f;
            #pragma unroll
            for (int j = 0; j < 4; ++j) {
                v2h s = U.v[j] + xrh[j];
                v2h l = __builtin_elementwise_max(s, s * neg2);
                t = hdot2v(l, ath[j], t);
            }
            t += __shfl_xor(t, 1, 64);
            t += __shfl_xor(t, 2, 64);
            float p = val[k] ? __expf(t) : 0.f;
            den += p;
            #pragma unroll
            for (int j = 0; j < 4; ++j) {
                acc[2*j]   += p * (float)U.v[j].x;
                acc[2*j+1] += p * (float)U.v[j].y;
            }
        }
    }

    den += __shfl_xor(den, 8, 64);
    den += __shfl_xor(den, 16, 64);
    den += __shfl_xor(den, 32, 64);
    #pragma unroll
    for (int j = 0; j < 8; ++j) {
        acc[j] += __shfl_xor(acc[j], 8, 64);
        acc[j] += __shfl_xor(acc[j], 16, 64);
        acc[j] += __shfl_xor(acc[j], 32, 64);
    }

    if (oct == 0) {
        float rr = 1.f / den;
        const float4* bp = reinterpret_cast<const float4*>(lv ? blv : bmu) + cq * 2;
        float4 ba = bp[0], bb = bp[1];
        float4 o1 = make_float4(acc[0]*rr+ba.x, acc[1]*rr+ba.y,
                                acc[2]*rr+ba.z, acc[3]*rr+ba.w);
        float4 o2 = make_float4(acc[4]*rr+bb.x, acc[5]*rr+bb.y,
                                acc[6]*rr+bb.z, acc[7]*rr+bb.w);
        float* base_out = out + (lv ? 1600000 : 0);
        float4* op = reinterpret_cast<float4*>(base_out) + (size_t)d * 8 + cq * 2;
        op[0] = o1; op[1] = o2;
    }
}

extern "C" void kernel_launch(void* const* d_in, const int* in_sizes, int n_in,
                              void* d_out, int out_size, void* d_ws, size_t ws_size,
                              hipStream_t stream) {
    const float* x    = (const float*)d_in[0];
    const int*   ei   = (const int*)d_in[1];
    const float* Wl1  = (const float*)d_in[2];
    const float* bl1  = (const float*)d_in[3];
    const float* Wr1  = (const float*)d_in[4];
    const float* br1  = (const float*)d_in[5];
    const float* att1 = (const float*)d_in[6];
    const float* b1   = (const float*)d_in[7];
    const float* Wlmu = (const float*)d_in[8];
    const float* blmu = (const float*)d_in[9];
    const float* Wrmu = (const float*)d_in[10];
    const float* brmu = (const float*)d_in[11];
    const float* atmu = (const float*)d_in[12];
    const float* bmu  = (const float*)d_in[13];
    const float* Wllv = (const float*)d_in[14];
    const float* bllv = (const float*)d_in[15];
    const float* Wrlv = (const float*)d_in[16];
    const float* brlv = (const float*)d_in[17];
    const float* atlv = (const float*)d_in[18];
    const float* blv  = (const float*)d_in[19];

    float* out = (float*)d_out;
    float* ws  = (float*)d_ws;

    __half* xl16 = (__half*)ws;                      // [0, 3.2M f32)
    __half* xr16 = (__half*)(ws + 3200000);          // [3.2M, 6.4M)
    __half* h16  = (__half*)(ws + 6400000);          // [6.4M, 9.6M)
    __half* WT   = (__half*)(ws + 9600000);          // 32768 halves
    __half* WT2  = (__half*)(ws + 9620000);          // 16384 halves

    // layer-2 buffers alias xl16/xr16 region (dead after gat_gather1)
    __half* xi16  = (__half*)ws;                     // 3.2M halves
    __half* xrI16 = (__half*)(ws + 1600000);         // 3.2M halves

    int*  ip    = (int*)(ws + 10000000);
    int2* pairs = (int2*)ip;                         // 1.65M int2
    int*  btot  = ip + 3300000;                      // 391
    int*  bbase = ip + 3300400;                      // 392
    int*  bcur  = ip + 3300800;                      // 391
    int*  offs  = ip + 3301200;                      // 50,001
    int*  csr   = ip + 3351204;                      // 1,650,000

    const int* srcp = ei;
    const int* dstp = ei + EORIG;

    const int NBE = (ETOT + 8191) / 8192;            // 202

    // ---- weight pack ----
    wcvt_kernel<<<192, 256, 0, stream>>>(Wl1, Wr1, Wlmu, Wllv, Wrmu, Wrlv, WT, WT2);

    // ---- CSR build ----
    hipMemsetAsync(btot, 0, NBUCK * sizeof(int), stream);
    bhist_kernel<<<NBE, 256, 0, stream>>>(dstp, btot);
    bscan_kernel<<<1, 512, 0, stream>>>(btot, bbase, bcur);
    part_kernel<<<NBE, 256, 0, stream>>>(srcp, dstp, bcur, pairs);
    csrfill_kernel<<<NBUCK, 256, 0, stream>>>(pairs, bbase, offs, csr);

    // ---- layer 1 ----
    lin1_kernel<<<(NRT + 3) / 4, 256, 0, stream>>>(x, WT, bl1, br1, xl16, xr16);

    gat_gather1<<<(NNODES * 64 + 255) / 256, 256, 0, stream>>>(
        xl16, xr16, att1, b1, offs, csr, h16);

    // ---- layer 2 ----
    lin2_kernel<<<(NRT + 3) / 4, 256, 0, stream>>>(
        h16, WT2, blmu, bllv, brmu, brlv, xi16, xrI16);

    gat_gather2<<<(NNODES * 64 + 255) / 256, 256, 0, stream>>>(
        xi16, xrI16, atmu, atlv, bmu, blv, offs, csr, out);
}

// Round 10
// 210.276 us; speedup vs baseline: 23.1562x; 1.0511x over previous
//
#include <hip/hip_runtime.h>
#include <hip/hip_fp16.h>

#define NNODES 50000
#define EORIG  1600000
#define ETOT   (EORIG + NNODES)
#define NEG 0.2f
#define BSH 7
#define NBUCK ((NNODES + 127) >> BSH)   // 391
#define NRT (NNODES / 16)               // 3125 row-tiles
#define EPB 4096

typedef _Float16 v2h __attribute__((ext_vector_type(2)));
typedef _Float16 v8h __attribute__((ext_vector_type(8)));
typedef float    v4f __attribute__((ext_vector_type(4)));

__device__ __forceinline__ float hdot2v(v2h a, v2h b, float c) {
#if __has_builtin(__builtin_amdgcn_fdot2)
    return __builtin_amdgcn_fdot2(a, b, c, false);
#else
    return c + (float)a.x * (float)b.x + (float)a.y * (float)b.y;
#endif
}

// ---------------------------------------------------------------------------
// Weight pack + btot zero-init.
// ---------------------------------------------------------------------------
__global__ __launch_bounds__(256) void wcvt_kernel(
    const float* __restrict__ Wl, const float* __restrict__ Wr,
    const float* __restrict__ Wlmu, const float* __restrict__ Wllv,
    const float* __restrict__ Wrmu, const float* __restrict__ Wrlv,
    __half* __restrict__ WT, __half* __restrict__ WT2, int* __restrict__ btot)
{
    int id = blockIdx.x * 256 + threadIdx.x;
    if (id < NBUCK) btot[id] = 0;
    if (id < 32768) {
        int k = id >> 8, c = id & 255;
        float v = (c < 128) ? Wl[k * 128 + c] : Wr[k * 128 + (c - 128)];
        WT[c * 128 + k] = __float2half(v);
    } else if (id < 49152) {
        int loc = id - 32768;
        int k = loc >> 7, c = loc & 127;
        int sel = c >> 5, cc = c & 31;
        const float* W = sel == 0 ? Wlmu : sel == 1 ? Wllv : sel == 2 ? Wrmu : Wrlv;
        WT2[c * 128 + k] = __float2half(W[k * 32 + cc]);
    }
}

// ---------------------------------------------------------------------------
// Layer-1 dual linear via MFMA (16x16x32 f16).
// ---------------------------------------------------------------------------
__global__ __launch_bounds__(256) void lin1_kernel(
    const float* __restrict__ x, const __half* __restrict__ WT,
    const float* __restrict__ bl, const float* __restrict__ br,
    __half* __restrict__ xl16, __half* __restrict__ xr16)
{
    int rt = (blockIdx.x * 256 + threadIdx.x) >> 6;
    if (rt >= NRT) return;
    int l  = threadIdx.x & 63;
    int lr = l & 15, lg = l >> 4;
    int row = rt * 16 + lr;

    v8h a[4];
    const float4* xrow = reinterpret_cast<const float4*>(x + (size_t)row * 128);
    #pragma unroll
    for (int ks = 0; ks < 4; ++ks) {
        float4 f0 = xrow[ks * 8 + lg * 2];
        float4 f1 = xrow[ks * 8 + lg * 2 + 1];
        v8h t;
        t[0]=(_Float16)f0.x; t[1]=(_Float16)f0.y; t[2]=(_Float16)f0.z; t[3]=(_Float16)f0.w;
        t[4]=(_Float16)f1.x; t[5]=(_Float16)f1.y; t[6]=(_Float16)f1.z; t[7]=(_Float16)f1.w;
        a[ks] = t;
    }

    const uint4* wt4 = reinterpret_cast<const uint4*>(WT);
    #pragma unroll 4
    for (int ct = 0; ct < 16; ++ct) {
        int c = ct * 16 + lr;
        v4f acc = {0.f, 0.f, 0.f, 0.f};
        #pragma unroll
        for (int ks = 0; ks < 4; ++ks) {
            union { uint4 u; v8h h; } B;
            B.u = wt4[(size_t)c * 16 + ks * 4 + lg];
            acc = __builtin_amdgcn_mfma_f32_16x16x32_f16(a[ks], B.h, acc, 0, 0, 0);
        }
        float bb = (c < 128) ? bl[c] : br[c - 128];
        #pragma unroll
        for (int j = 0; j < 4; ++j) {
            int orow = rt * 16 + lg * 4 + j;
            __half hv = __float2half(acc[j] + bb);
            if (c < 128) xl16[(size_t)orow * 128 + c] = hv;
            else         xr16[(size_t)orow * 128 + (c - 128)] = hv;
        }
    }
}

// ---------------------------------------------------------------------------
// Layer-2 quad linear via MFMA.
// ---------------------------------------------------------------------------
__global__ __launch_bounds__(256) void lin2_kernel(
    const __half* __restrict__ h16, const __half* __restrict__ WT2,
    const float* __restrict__ blmu, const float* __restrict__ bllv,
    const float* __restrict__ brmu, const float* __restrict__ brlv,
    __half* __restrict__ xi16, __half* __restrict__ xrI16)
{
    int rt = (blockIdx.x * 256 + threadIdx.x) >> 6;
    if (rt >= NRT) return;
    int l  = threadIdx.x & 63;
    int lr = l & 15, lg = l >> 4;
    int row = rt * 16 + lr;

    v8h a[4];
    const uint4* hrow = reinterpret_cast<const uint4*>(h16 + (size_t)row * 128);
    #pragma unroll
    for (int ks = 0; ks < 4; ++ks) {
        union { uint4 u; v8h h; } A;
        A.u = hrow[ks * 4 + lg];
        a[ks] = A.h;
    }

    const uint4* wt4 = reinterpret_cast<const uint4*>(WT2);
    #pragma unroll 4
    for (int ct = 0; ct < 8; ++ct) {
        int c = ct * 16 + lr;
        v4f acc = {0.f, 0.f, 0.f, 0.f};
        #pragma unroll
        for (int ks = 0; ks < 4; ++ks) {
            union { uint4 u; v8h h; } B;
            B.u = wt4[(size_t)c * 16 + ks * 4 + lg];
            acc = __builtin_amdgcn_mfma_f32_16x16x32_f16(a[ks], B.h, acc, 0, 0, 0);
        }
        int sel = c >> 5, cc = c & 31;
        const float* bp = sel == 0 ? blmu : sel == 1 ? bllv : sel == 2 ? brmu : brlv;
        float bb = bp[cc];
        #pragma unroll
        for (int j = 0; j < 4; ++j) {
            int orow = rt * 16 + lg * 4 + j;
            __half hv = __float2half(acc[j] + bb);
            if (c < 64) xi16 [(size_t)orow * 64 + c]      = hv;
            else        xrI16[(size_t)orow * 64 + (c-64)] = hv;
        }
    }
}

// ---------------------------------------------------------------------------
// CSR build: bucket histogram -> tiny scan -> partition -> local fill.
// pairs packed: src (16b) | dst-local (7b) << 16.  csr: ushort src.
// ---------------------------------------------------------------------------
__global__ __launch_bounds__(256) void bhist_kernel(
    const int* __restrict__ dst, int* __restrict__ btot)
{
    __shared__ int cnt[NBUCK];
    for (int i = threadIdx.x; i < NBUCK; i += 256) cnt[i] = 0;
    __syncthreads();
    const int e0 = blockIdx.x * EPB;
    for (int i = threadIdx.x; i < EPB; i += 256) {
        int e = e0 + i;
        if (e >= ETOT) break;
        int d = (e < EORIG) ? dst[e] : e - EORIG;
        atomicAdd(&cnt[d >> BSH], 1);
    }
    __syncthreads();
    for (int i = threadIdx.x; i < NBUCK; i += 256)
        if (cnt[i]) atomicAdd(&btot[i], cnt[i]);
}

__global__ __launch_bounds__(512) void bscan_kernel(
    const int* __restrict__ btot, int* __restrict__ bbase, int* __restrict__ bcur)
{
    __shared__ int tmp[512];
    int t = threadIdx.x;
    int v = (t < NBUCK) ? btot[t] : 0;
    tmp[t] = v;
    __syncthreads();
    for (int off = 1; off < 512; off <<= 1) {
        int a = (t >= off) ? tmp[t - off] : 0;
        __syncthreads();
        tmp[t] += a;
        __syncthreads();
    }
    if (t < NBUCK) { int e = tmp[t] - v; bbase[t] = e; bcur[t] = e; }
    if (t == 0) bbase[NBUCK] = ETOT;
}

__global__ __launch_bounds__(256) void part_kernel(
    const int* __restrict__ src, const int* __restrict__ dst,
    int* __restrict__ bcur, unsigned int* __restrict__ pairs)
{
    __shared__ int cnt[NBUCK];
    __shared__ int gbase[NBUCK];
    const int e0 = blockIdx.x * EPB;

    for (int i = threadIdx.x; i < NBUCK; i += 256) cnt[i] = 0;
    __syncthreads();

    for (int i = threadIdx.x; i < EPB; i += 256) {
        int e = e0 + i;
        if (e >= ETOT) break;
        int d = (e < EORIG) ? dst[e] : e - EORIG;
        atomicAdd(&cnt[d >> BSH], 1);
    }
    __syncthreads();

    for (int b = threadIdx.x; b < NBUCK; b += 256) {
        int c = cnt[b];
        gbase[b] = c ? atomicAdd(&bcur[b], c) : 0;
        cnt[b] = 0;
    }
    __syncthreads();

    for (int i = threadIdx.x; i < EPB; i += 256) {
        int e = e0 + i;
        if (e >= ETOT) break;
        int s, d;
        if (e < EORIG) { s = src[e]; d = dst[e]; }
        else           { s = d = e - EORIG; }
        int b = d >> BSH;
        int slot = atomicAdd(&cnt[b], 1);
        pairs[gbase[b] + slot] = (unsigned)s | ((unsigned)(d & 127) << 16);
    }
}

__global__ __launch_bounds__(256) void csrfill_kernel(
    const unsigned int* __restrict__ pairs, const int* __restrict__ bbase,
    int* __restrict__ offs, unsigned short* __restrict__ csr)
{
    __shared__ int cnt[128];
    __shared__ int lofs[128];
    __shared__ int scnt[128];
    const int b = blockIdx.x, n0 = b << BSH;
    const int nn = min(128, NNODES - n0);
    const int pbeg = bbase[b], pend = bbase[b + 1];
    const int t = threadIdx.x;

    if (t < 128) { cnt[t] = 0; scnt[t] = 0; }
    __syncthreads();
    for (int i = pbeg + t; i < pend; i += 256)
        atomicAdd(&cnt[pairs[i] >> 16], 1);
    __syncthreads();

    if (t < 128) lofs[t] = cnt[t];
    __syncthreads();
    for (int off = 1; off < 128; off <<= 1) {
        int v = (t < 128 && t >= off) ? lofs[t - off] : 0;
        __syncthreads();
        if (t < 128) lofs[t] += v;
        __syncthreads();
    }
    if (t < 128) lofs[t] = pbeg + lofs[t] - cnt[t];
    __syncthreads();

    if (t < nn) offs[n0 + t] = lofs[t];
    if (b == NBUCK - 1 && t == 0) offs[NNODES] = ETOT;

    for (int i = pbeg + t; i < pend; i += 256) {
        unsigned pr = pairs[i];
        int l = pr >> 16;
        int slot = atomicAdd(&scnt[l], 1);
        csr[lofs[l] + slot] = (unsigned short)(pr & 0xFFFFu);
    }
}

// ---------------------------------------------------------------------------
// Layer-1 gather, packed fp16, depth-2 pipelined (idx n+2, rows n+1, compute n).
// One wave per node. lane = quarter*16 + q. 8 edges/iter.
// ---------------------------------------------------------------------------
__global__ __launch_bounds__(256) void gat_gather1(
    const __half* __restrict__ xl16, const __half* __restrict__ xr16,
    const float* __restrict__ att, const float* __restrict__ bias,
    const int* __restrict__ offs, const unsigned short* __restrict__ csr,
    __half* __restrict__ h16)
{
    int d = (blockIdx.x * 256 + threadIdx.x) >> 6;
    if (d >= NNODES) return;
    int lane = threadIdx.x & 63;
    int quarter = lane >> 4;
    int q = lane & 15;
    int off0 = quarter * 2, off1 = off0 + 1;

    v2h xrh[4], ath[4];
    {
        union { uint4 u; v2h v[4]; } R;
        R.u = reinterpret_cast<const uint4*>(xr16)[(size_t)d * 16 + q];
        #pragma unroll
        for (int j = 0; j < 4; ++j) xrh[j] = R.v[j];
        const float4* t4 = reinterpret_cast<const float4*>(att) + q * 2;
        float4 a = t4[0], b = t4[1];
        ath[0] = (v2h){(_Float16)a.x, (_Float16)a.y};
        ath[1] = (v2h){(_Float16)a.z, (_Float16)a.w};
        ath[2] = (v2h){(_Float16)b.x, (_Float16)b.y};
        ath[3] = (v2h){(_Float16)b.z, (_Float16)b.w};
    }
    const v2h neg2 = (v2h){(_Float16)NEG, (_Float16)NEG};

    int beg = offs[d], end = offs[d + 1];
    int nI = (end - beg + 7) >> 3;
    const uint4* xlu = reinterpret_cast<const uint4*>(xl16);

    float den = 0.f;
    float acc[8] = {0.f,0.f,0.f,0.f,0.f,0.f,0.f,0.f};

    auto compute = [&](uint4 U, bool val) {
        union { uint4 u; v2h v[4]; } X; X.u = U;
        float t = 0.f;
        #pragma unroll
        for (int j = 0; j < 4; ++j) {
            v2h s = X.v[j] + xrh[j];
            v2h l = __builtin_elementwise_max(s, s * neg2);
            t = hdot2v(l, ath[j], t);
        }
        t += __shfl_xor(t, 1, 64);
        t += __shfl_xor(t, 2, 64);
        float p = val ? __expf(t) : 0.f;
        den += p;
        #pragma unroll
        for (int j = 0; j < 4; ++j) {
            acc[2*j]   += p * (float)X.v[j].x;
            acc[2*j+1] += p * (float)X.v[j].y;
        }
    };

    // pipeline prologue
    int sA0 = beg + off0, sA1 = beg + off1;
    bool vA0 = sA0 < end, vA1 = sA1 < end;
    int iA0 = csr[vA0 ? sA0 : end - 1];
    int iA1 = csr[vA1 ? sA1 : end - 1];
    uint4 rA0 = xlu[(size_t)iA0 * 16 + q];
    uint4 rA1 = xlu[(size_t)iA1 * 16 + q];

    int sB0 = beg + 8 + off0, sB1 = beg + 8 + off1;
    bool vB0 = sB0 < end, vB1 = sB1 < end;
    int iB0 = csr[vB0 ? sB0 : end - 1];
    int iB1 = csr[vB1 ? sB1 : end - 1];

    for (int it = 0; it < nI; ++it) {
        // prefetch indices for it+2 (clamped, branchless)
        int b2 = beg + (it + 2) * 8;
        int sC0 = b2 + off0, sC1 = b2 + off1;
        bool vC0 = sC0 < end, vC1 = sC1 < end;
        int iC0 = csr[vC0 ? sC0 : end - 1];
        int iC1 = csr[vC1 ? sC1 : end - 1];
        // rows for it+1
        uint4 rB0 = xlu[(size_t)iB0 * 16 + q];
        uint4 rB1 = xlu[(size_t)iB1 * 16 + q];
        // compute it
        compute(rA0, vA0);
        compute(rA1, vA1);
        // rotate
        rA0 = rB0; rA1 = rB1; vA0 = vB0; vA1 = vB1;
        iB0 = iC0; iB1 = iC1; vB0 = vC0; vB1 = vC1;
    }

    den += __shfl_xor(den, 16, 64);
    den += __shfl_xor(den, 32, 64);
    #pragma unroll
    for (int j = 0; j < 8; ++j) {
        acc[j] += __shfl_xor(acc[j], 16, 64);
        acc[j] += __shfl_xor(acc[j], 32, 64);
    }

    if (quarter == 0) {
        float r = 1.f / den;
        const float4* bp = reinterpret_cast<const float4*>(bias) + q * 2;
        float4 ba = bp[0], bb = bp[1];
        __half hv[8];
        hv[0] = __float2half(fmaxf(acc[0]*r+ba.x, 0.f));
        hv[1] = __float2half(fmaxf(acc[1]*r+ba.y, 0.f));
        hv[2] = __float2half(fmaxf(acc[2]*r+ba.z, 0.f));
        hv[3] = __float2half(fmaxf(acc[3]*r+ba.w, 0.f));
        hv[4] = __float2half(fmaxf(acc[4]*r+bb.x, 0.f));
        hv[5] = __float2half(fmaxf(acc[5]*r+bb.y, 0.f));
        hv[6] = __float2half(fmaxf(acc[6]*r+bb.z, 0.f));
        hv[7] = __float2half(fmaxf(acc[7]*r+bb.w, 0.f));
        *reinterpret_cast<uint4*>(&h16[(size_t)d * 128 + q * 8]) =
            *reinterpret_cast<uint4*>(hv);
    }
}

// ---------------------------------------------------------------------------
// Layer-2 gather, packed fp16, depth-2 pipelined. interleaved [mu|lv].
// One wave per node. lane = oct*8 + r. 16 edges/iter.
// ---------------------------------------------------------------------------
__global__ __launch_bounds__(256) void gat_gather2(
    const __half* __restrict__ xi16, const __half* __restrict__ xrI16,
    const float* __restrict__ atmu, const float* __restrict__ atlv,
    const float* __restrict__ bmu,  const float* __restrict__ blv,
    const int* __restrict__ offs, const unsigned short* __restrict__ csr,
    float* __restrict__ out)
{
    int d = (blockIdx.x * 256 + threadIdx.x) >> 6;
    if (d >= NNODES) return;
    int lane = threadIdx.x & 63;
    int oct = lane >> 3;
    int r   = lane & 7;
    bool lv = r >= 4;
    int cq  = lv ? r - 4 : r;
    int off0 = oct * 2, off1 = off0 + 1;

    v2h xrh[4], ath[4];
    {
        union { uint4 u; v2h v[4]; } R;
        R.u = reinterpret_cast<const uint4*>(xrI16)[(size_t)d * 8 + r];
        #pragma unroll
        for (int j = 0; j < 4; ++j) xrh[j] = R.v[j];
        const float4* t4 = reinterpret_cast<const float4*>(lv ? atlv : atmu) + cq * 2;
        float4 a = t4[0], b = t4[1];
        ath[0] = (v2h){(_Float16)a.x, (_Float16)a.y};
        ath[1] = (v2h){(_Float16)a.z, (_Float16)a.w};
        ath[2] = (v2h){(_Float16)b.x, (_Float16)b.y};
        ath[3] = (v2h){(_Float16)b.z, (_Float16)b.w};
    }
    const v2h neg2 = (v2h){(_Float16)NEG, (_Float16)NEG};

    int beg = offs[d], end = offs[d + 1];
    int nI = (end - beg + 15) >> 4;
    const uint4* xiu = reinterpret_cast<const uint4*>(xi16);

    float den = 0.f;
    float acc[8] = {0.f,0.f,0.f,0.f,0.f,0.f,0.f,0.f};

    auto compute = [&](uint4 U, bool val) {
        union { uint4 u; v2h v[4]; } X; X.u = U;
        float t = 0.f;
        #pragma unroll
        for (int j = 0; j < 4; ++j) {
            v2h s = X.v[j] + xrh[j];
            v2h l = __builtin_elementwise_max(s, s * neg2);
            t = hdot2v(l, ath[j], t);
        }
        t += __shfl_xor(t, 1, 64);
        t += __shfl_xor(t, 2, 64);
        float p = val ? __expf(t) : 0.f;
        den += p;
        #pragma unroll
        for (int j = 0; j < 4; ++j) {
            acc[2*j]   += p * (float)X.v[j].x;
            acc[2*j+1] += p * (float)X.v[j].y;
        }
    };

    int sA0 = beg + off0, sA1 = beg + off1;
    bool vA0 = sA0 < end, vA1 = sA1 < end;
    int iA0 = csr[vA0 ? sA0 : end - 1];
    int iA1 = csr[vA1 ? sA1 : end - 1];
    uint4 rA0 = xiu[(size_t)iA0 * 8 + r];
    uint4 rA1 = xiu[(size_t)iA1 * 8 + r];

    int sB0 = beg + 16 + off0, sB1 = beg + 16 + off1;
    bool vB0 = sB0 < end, vB1 = sB1 < end;
    int iB0 = csr[vB0 ? sB0 : end - 1];
    int iB1 = csr[vB1 ? sB1 : end - 1];

    for (int it = 0; it < nI; ++it) {
        int b2 = beg + (it + 2) * 16;
        int sC0 = b2 + off0, sC1 = b2 + off1;
        bool vC0 = sC0 < end, vC1 = sC1 < end;
        int iC0 = csr[vC0 ? sC0 : end - 1];
        int iC1 = csr[vC1 ? sC1 : end - 1];
        uint4 rB0 = xiu[(size_t)iB0 * 8 + r];
        uint4 rB1 = xiu[(size_t)iB1 * 8 + r];
        compute(rA0, vA0);
        compute(rA1, vA1);
        rA0 = rB0; rA1 = rB1; vA0 = vB0; vA1 = vB1;
        iB0 = iC0; iB1 = iC1; vB0 = vC0; vB1 = vC1;
    }

    den += __shfl_xor(den, 8, 64);
    den += __shfl_xor(den, 16, 64);
    den += __shfl_xor(den, 32, 64);
    #pragma unroll
    for (int j = 0; j < 8; ++j) {
        acc[j] += __shfl_xor(acc[j], 8, 64);
        acc[j] += __shfl_xor(acc[j], 16, 64);
        acc[j] += __shfl_xor(acc[j], 32, 64);
    }

    if (oct == 0) {
        float rr = 1.f / den;
        const float4* bp = reinterpret_cast<const float4*>(lv ? blv : bmu) + cq * 2;
        float4 ba = bp[0], bb = bp[1];
        float4 o1 = make_float4(acc[0]*rr+ba.x, acc[1]*rr+ba.y,
                                acc[2]*rr+ba.z, acc[3]*rr+ba.w);
        float4 o2 = make_float4(acc[4]*rr+bb.x, acc[5]*rr+bb.y,
                                acc[6]*rr+bb.z, acc[7]*rr+bb.w);
        float* base_out = out + (lv ? 1600000 : 0);
        float4* op = reinterpret_cast<float4*>(base_out) + (size_t)d * 8 + cq * 2;
        op[0] = o1; op[1] = o2;
    }
}

extern "C" void kernel_launch(void* const* d_in, const int* in_sizes, int n_in,
                              void* d_out, int out_size, void* d_ws, size_t ws_size,
                              hipStream_t stream) {
    const float* x    = (const float*)d_in[0];
    const int*   ei   = (const int*)d_in[1];
    const float* Wl1  = (const float*)d_in[2];
    const float* bl1  = (const float*)d_in[3];
    const float* Wr1  = (const float*)d_in[4];
    const float* br1  = (const float*)d_in[5];
    const float* att1 = (const float*)d_in[6];
    const float* b1   = (const float*)d_in[7];
    const float* Wlmu = (const float*)d_in[8];
    const float* blmu = (const float*)d_in[9];
    const float* Wrmu = (const float*)d_in[10];
    const float* brmu = (const float*)d_in[11];
    const float* atmu = (const float*)d_in[12];
    const float* bmu  = (const float*)d_in[13];
    const float* Wllv = (const float*)d_in[14];
    const float* bllv = (const float*)d_in[15];
    const float* Wrlv = (const float*)d_in[16];
    const float* brlv = (const float*)d_in[17];
    const float* atlv = (const float*)d_in[18];
    const float* blv  = (const float*)d_in[19];

    float* out = (float*)d_out;
    float* ws  = (float*)d_ws;

    __half* xl16 = (__half*)ws;                      // [0, 3.2M f32)
    __half* xr16 = (__half*)(ws + 3200000);          // [3.2M, 6.4M)
    __half* h16  = (__half*)(ws + 6400000);          // [6.4M, 9.6M)
    __half* WT   = (__half*)(ws + 9600000);          // 32768 halves
    __half* WT2  = (__half*)(ws + 9620000);          // 16384 halves

    __half* xi16  = (__half*)ws;                     // aliases (dead xl16)
    __half* xrI16 = (__half*)(ws + 1600000);

    int* ip = (int*)(ws + 10000000);
    unsigned int*   pairs = (unsigned int*)ip;       // 1,650,000
    int*            btot  = ip + 1650000;            // 391
    int*            bbase = ip + 1650400;            // 392
    int*            bcur  = ip + 1650800;            // 391
    int*            offs  = ip + 1651200;            // 50,001
    unsigned short* csr   = (unsigned short*)(ip + 1701204);  // 1,650,000 u16

    const int* srcp = ei;
    const int* dstp = ei + EORIG;

    const int NBE = (ETOT + EPB - 1) / EPB;          // 404

    // ---- weight pack + btot init ----
    wcvt_kernel<<<192, 256, 0, stream>>>(Wl1, Wr1, Wlmu, Wllv, Wrmu, Wrlv, WT, WT2, btot);

    // ---- CSR build ----
    bhist_kernel<<<NBE, 256, 0, stream>>>(dstp, btot);
    bscan_kernel<<<1, 512, 0, stream>>>(btot, bbase, bcur);
    part_kernel<<<NBE, 256, 0, stream>>>(srcp, dstp, bcur, pairs);
    csrfill_kernel<<<NBUCK, 256, 0, stream>>>(pairs, bbase, offs, csr);

    // ---- layer 1 ----
    lin1_kernel<<<(NRT + 3) / 4, 256, 0, stream>>>(x, WT, bl1, br1, xl16, xr16);

    gat_gather1<<<(NNODES * 64 + 255) / 256, 256, 0, stream>>>(
        xl16, xr16, att1, b1, offs, csr, h16);

    // ---- layer 2 ----
    lin2_kernel<<<(NRT + 3) / 4, 256, 0, stream>>>(
        h16, WT2, blmu, bllv, brmu, brlv, xi16, xrI16);

    gat_gather2<<<(NNODES * 64 + 255) / 256, 256, 0, stream>>>(
        xi16, xrI16, atmu, atlv, bmu, blv, offs, csr, out);
}

// Round 11
// 198.540 us; speedup vs baseline: 24.5250x; 1.0591x over previous
//
#include <hip/hip_runtime.h>
#include <hip/hip_fp16.h>

#define NNODES 50000
#define EORIG  1600000
#define ETOT   (EORIG + NNODES)
#define NEG 0.2f
#define BSH 7
#define NBUCK ((NNODES + 127) >> BSH)   // 391
#define BCAP 5120                        // padded bucket capacity (mean 4224, sd 65)
#define NRT (NNODES / 16)               // 3125 row-tiles
#define EPB 4096
#define LOG2E 1.44269504f

typedef _Float16 v2h __attribute__((ext_vector_type(2)));
typedef _Float16 v8h __attribute__((ext_vector_type(8)));
typedef float    v4f __attribute__((ext_vector_type(4)));

__device__ __forceinline__ float hdot2v(v2h a, v2h b, float c) {
#if __has_builtin(__builtin_amdgcn_fdot2)
    return __builtin_amdgcn_fdot2(a, b, c, false);
#else
    return c + (float)a.x * (float)b.x + (float)a.y * (float)b.y;
#endif
}

__device__ __forceinline__ float fexp2(float t) {
#if __has_builtin(__builtin_amdgcn_exp2f)
    return __builtin_amdgcn_exp2f(t);
#else
    return exp2f(t);
#endif
}

// ---------------------------------------------------------------------------
// Weight pack + bcur zero-init.
// ---------------------------------------------------------------------------
__global__ __launch_bounds__(256) void wcvt_kernel(
    const float* __restrict__ Wl, const float* __restrict__ Wr,
    const float* __restrict__ Wlmu, const float* __restrict__ Wllv,
    const float* __restrict__ Wrmu, const float* __restrict__ Wrlv,
    __half* __restrict__ WT, __half* __restrict__ WT2, int* __restrict__ bcur)
{
    int id = blockIdx.x * 256 + threadIdx.x;
    if (id < NBUCK) bcur[id] = 0;
    if (id < 32768) {
        int k = id >> 8, c = id & 255;
        float v = (c < 128) ? Wl[k * 128 + c] : Wr[k * 128 + (c - 128)];
        WT[c * 128 + k] = __float2half(v);
    } else if (id < 49152) {
        int loc = id - 32768;
        int k = loc >> 7, c = loc & 127;
        int sel = c >> 5, cc = c & 31;
        const float* W = sel == 0 ? Wlmu : sel == 1 ? Wllv : sel == 2 ? Wrmu : Wrlv;
        WT2[c * 128 + k] = __float2half(W[k * 32 + cc]);
    }
}

// ---------------------------------------------------------------------------
// Layer-1 dual linear via MFMA (16x16x32 f16).
// ---------------------------------------------------------------------------
__global__ __launch_bounds__(256) void lin1_kernel(
    const float* __restrict__ x, const __half* __restrict__ WT,
    const float* __restrict__ bl, const float* __restrict__ br,
    __half* __restrict__ xl16, __half* __restrict__ xr16)
{
    int rt = (blockIdx.x * 256 + threadIdx.x) >> 6;
    if (rt >= NRT) return;
    int l  = threadIdx.x & 63;
    int lr = l & 15, lg = l >> 4;
    int row = rt * 16 + lr;

    v8h a[4];
    const float4* xrow = reinterpret_cast<const float4*>(x + (size_t)row * 128);
    #pragma unroll
    for (int ks = 0; ks < 4; ++ks) {
        float4 f0 = xrow[ks * 8 + lg * 2];
        float4 f1 = xrow[ks * 8 + lg * 2 + 1];
        v8h t;
        t[0]=(_Float16)f0.x; t[1]=(_Float16)f0.y; t[2]=(_Float16)f0.z; t[3]=(_Float16)f0.w;
        t[4]=(_Float16)f1.x; t[5]=(_Float16)f1.y; t[6]=(_Float16)f1.z; t[7]=(_Float16)f1.w;
        a[ks] = t;
    }

    const uint4* wt4 = reinterpret_cast<const uint4*>(WT);
    #pragma unroll 4
    for (int ct = 0; ct < 16; ++ct) {
        int c = ct * 16 + lr;
        v4f acc = {0.f, 0.f, 0.f, 0.f};
        #pragma unroll
        for (int ks = 0; ks < 4; ++ks) {
            union { uint4 u; v8h h; } B;
            B.u = wt4[(size_t)c * 16 + ks * 4 + lg];
            acc = __builtin_amdgcn_mfma_f32_16x16x32_f16(a[ks], B.h, acc, 0, 0, 0);
        }
        float bb = (c < 128) ? bl[c] : br[c - 128];
        #pragma unroll
        for (int j = 0; j < 4; ++j) {
            int orow = rt * 16 + lg * 4 + j;
            __half hv = __float2half(acc[j] + bb);
            if (c < 128) xl16[(size_t)orow * 128 + c] = hv;
            else         xr16[(size_t)orow * 128 + (c - 128)] = hv;
        }
    }
}

// ---------------------------------------------------------------------------
// Layer-2 quad linear via MFMA.
// ---------------------------------------------------------------------------
__global__ __launch_bounds__(256) void lin2_kernel(
    const __half* __restrict__ h16, const __half* __restrict__ WT2,
    const float* __restrict__ blmu, const float* __restrict__ bllv,
    const float* __restrict__ brmu, const float* __restrict__ brlv,
    __half* __restrict__ xi16, __half* __restrict__ xrI16)
{
    int rt = (blockIdx.x * 256 + threadIdx.x) >> 6;
    if (rt >= NRT) return;
    int l  = threadIdx.x & 63;
    int lr = l & 15, lg = l >> 4;
    int row = rt * 16 + lr;

    v8h a[4];
    const uint4* hrow = reinterpret_cast<const uint4*>(h16 + (size_t)row * 128);
    #pragma unroll
    for (int ks = 0; ks < 4; ++ks) {
        union { uint4 u; v8h h; } A;
        A.u = hrow[ks * 4 + lg];
        a[ks] = A.h;
    }

    const uint4* wt4 = reinterpret_cast<const uint4*>(WT2);
    #pragma unroll 4
    for (int ct = 0; ct < 8; ++ct) {
        int c = ct * 16 + lr;
        v4f acc = {0.f, 0.f, 0.f, 0.f};
        #pragma unroll
        for (int ks = 0; ks < 4; ++ks) {
            union { uint4 u; v8h h; } B;
            B.u = wt4[(size_t)c * 16 + ks * 4 + lg];
            acc = __builtin_amdgcn_mfma_f32_16x16x32_f16(a[ks], B.h, acc, 0, 0, 0);
        }
        int sel = c >> 5, cc = c & 31;
        const float* bp = sel == 0 ? blmu : sel == 1 ? bllv : sel == 2 ? brmu : brlv;
        float bb = bp[cc];
        #pragma unroll
        for (int j = 0; j < 4; ++j) {
            int orow = rt * 16 + lg * 4 + j;
            __half hv = __float2half(acc[j] + bb);
            if (c < 64) xi16 [(size_t)orow * 64 + c]      = hv;
            else        xrI16[(size_t)orow * 64 + (c-64)] = hv;
        }
    }
}

// ---------------------------------------------------------------------------
// CSR build, padded-bucket layout (no global scan needed).
// part: per-block LDS count -> claim per-bucket chunk -> write packed pairs.
// csrfill: per-bucket local hist+scan -> begend int2 + ushort csr.
// ---------------------------------------------------------------------------
__global__ __launch_bounds__(256) void part_kernel(
    const int* __restrict__ src, const int* __restrict__ dst,
    int* __restrict__ bcur, unsigned int* __restrict__ pairs)
{
    __shared__ int cnt[NBUCK];
    __shared__ int gbase[NBUCK];
    const int e0 = blockIdx.x * EPB;

    for (int i = threadIdx.x; i < NBUCK; i += 256) cnt[i] = 0;
    __syncthreads();

    for (int i = threadIdx.x; i < EPB; i += 256) {
        int e = e0 + i;
        if (e >= ETOT) break;
        int d = (e < EORIG) ? dst[e] : e - EORIG;
        atomicAdd(&cnt[d >> BSH], 1);
    }
    __syncthreads();

    for (int b = threadIdx.x; b < NBUCK; b += 256) {
        int c = cnt[b];
        gbase[b] = c ? (b * BCAP + atomicAdd(&bcur[b], c)) : 0;
        cnt[b] = 0;
    }
    __syncthreads();

    for (int i = threadIdx.x; i < EPB; i += 256) {
        int e = e0 + i;
        if (e >= ETOT) break;
        int s, d;
        if (e < EORIG) { s = src[e]; d = dst[e]; }
        else           { s = d = e - EORIG; }
        int b = d >> BSH;
        int slot = atomicAdd(&cnt[b], 1);
        pairs[gbase[b] + slot] = (unsigned)s | ((unsigned)(d & 127) << 16);
    }
}

__global__ __launch_bounds__(256) void csrfill_kernel(
    const unsigned int* __restrict__ pairs, const int* __restrict__ bcur,
    int2* __restrict__ begend, unsigned short* __restrict__ csr)
{
    __shared__ int cnt[128];
    __shared__ int lofs[128];
    __shared__ int scnt[128];
    const int b = blockIdx.x, n0 = b << BSH;
    const int nn = min(128, NNODES - n0);
    const int pbase = b * BCAP;
    const int pend = pbase + bcur[b];
    const int t = threadIdx.x;

    if (t < 128) { cnt[t] = 0; scnt[t] = 0; }
    __syncthreads();
    for (int i = pbase + t; i < pend; i += 256)
        atomicAdd(&cnt[pairs[i] >> 16], 1);
    __syncthreads();

    if (t < 128) lofs[t] = cnt[t];
    __syncthreads();
    for (int off = 1; off < 128; off <<= 1) {
        int v = (t < 128 && t >= off) ? lofs[t - off] : 0;
        __syncthreads();
        if (t < 128) lofs[t] += v;
        __syncthreads();
    }
    if (t < 128) lofs[t] = pbase + lofs[t] - cnt[t];   // exclusive + bucket base
    __syncthreads();

    if (t < nn) begend[n0 + t] = make_int2(lofs[t], lofs[t] + cnt[t]);

    for (int i = pbase + t; i < pend; i += 256) {
        unsigned pr = pairs[i];
        int l = pr >> 16;
        int slot = atomicAdd(&scnt[l], 1);
        csr[lofs[l] + slot] = (unsigned short)(pr & 0xFFFFu);
    }
}

// ---------------------------------------------------------------------------
// Layer-1 gather: 16 edges/iter (4 per quarter), depth-2 pipeline.
// lane = quarter*16 + q. att pre-scaled by log2(e); p = exp2.
// ---------------------------------------------------------------------------
__global__ __launch_bounds__(256) void gat_gather1(
    const __half* __restrict__ xl16, const __half* __restrict__ xr16,
    const float* __restrict__ att, const float* __restrict__ bias,
    const int2* __restrict__ begend, const unsigned short* __restrict__ csr,
    __half* __restrict__ h16)
{
    int d = (blockIdx.x * 256 + threadIdx.x) >> 6;
    if (d >= NNODES) return;
    int lane = threadIdx.x & 63;
    int quarter = lane >> 4;
    int q = lane & 15;
    int qo = quarter * 4;

    v2h xrh[4], ath[4];
    {
        union { uint4 u; v2h v[4]; } R;
        R.u = reinterpret_cast<const uint4*>(xr16)[(size_t)d * 16 + q];
        #pragma unroll
        for (int j = 0; j < 4; ++j) xrh[j] = R.v[j];
        const float4* t4 = reinterpret_cast<const float4*>(att) + q * 2;
        float4 a = t4[0], b = t4[1];
        ath[0] = (v2h){(_Float16)(a.x*LOG2E), (_Float16)(a.y*LOG2E)};
        ath[1] = (v2h){(_Float16)(a.z*LOG2E), (_Float16)(a.w*LOG2E)};
        ath[2] = (v2h){(_Float16)(b.x*LOG2E), (_Float16)(b.y*LOG2E)};
        ath[3] = (v2h){(_Float16)(b.z*LOG2E), (_Float16)(b.w*LOG2E)};
    }
    const v2h neg2 = (v2h){(_Float16)NEG, (_Float16)NEG};

    int2 be = begend[d];
    int beg = be.x, end = be.y;          // deg >= 1 (self-loop)
    int nI = (end - beg + 15) >> 4;
    const uint4* xlu = reinterpret_cast<const uint4*>(xl16);

    float den = 0.f;
    float acc[8] = {0.f,0.f,0.f,0.f,0.f,0.f,0.f,0.f};

    auto compute = [&](uint4 U, bool val) {
        union { uint4 u; v2h v[4]; } X; X.u = U;
        float t = 0.f;
        #pragma unroll
        for (int j = 0; j < 4; ++j) {
            v2h s = X.v[j] + xrh[j];
            v2h l = __builtin_elementwise_max(s, s * neg2);
            t = hdot2v(l, ath[j], t);
        }
        t += __shfl_xor(t, 1, 64);
        t += __shfl_xor(t, 2, 64);
        float p = val ? fexp2(t) : 0.f;
        den += p;
        #pragma unroll
        for (int j = 0; j < 4; ++j) {
            acc[2*j]   += p * (float)X.v[j].x;
            acc[2*j+1] += p * (float)X.v[j].y;
        }
    };

    int  iA[4], iB[4];
    bool vA[4], vB[4];
    uint4 rA[4];

    #pragma unroll
    for (int k = 0; k < 4; ++k) {
        int s = beg + qo + k;
        vA[k] = s < end;
        iA[k] = csr[vA[k] ? s : end - 1];
    }
    #pragma unroll
    for (int k = 0; k < 4; ++k) rA[k] = xlu[(size_t)iA[k] * 16 + q];
    #pragma unroll
    for (int k = 0; k < 4; ++k) {
        int s = beg + 16 + qo + k;
        vB[k] = s < end;
        iB[k] = csr[vB[k] ? s : end - 1];
    }

    for (int it = 0; it < nI; ++it) {
        int b2 = beg + (it + 2) * 16;
        int  iC[4]; bool vC[4];
        #pragma unroll
        for (int k = 0; k < 4; ++k) {
            int s = b2 + qo + k;
            vC[k] = s < end;
            iC[k] = csr[vC[k] ? s : end - 1];
        }
        uint4 rB[4];
        #pragma unroll
        for (int k = 0; k < 4; ++k) rB[k] = xlu[(size_t)iB[k] * 16 + q];
        #pragma unroll
        for (int k = 0; k < 4; ++k) compute(rA[k], vA[k]);
        #pragma unroll
        for (int k = 0; k < 4; ++k) {
            rA[k] = rB[k]; vA[k] = vB[k];
            iB[k] = iC[k]; vB[k] = vC[k];
        }
    }

    den += __shfl_xor(den, 16, 64);
    den += __shfl_xor(den, 32, 64);
    #pragma unroll
    for (int j = 0; j < 8; ++j) {
        acc[j] += __shfl_xor(acc[j], 16, 64);
        acc[j] += __shfl_xor(acc[j], 32, 64);
    }

    if (quarter == 0) {
        float r = 1.f / den;
        const float4* bp = reinterpret_cast<const float4*>(bias) + q * 2;
        float4 ba = bp[0], bb = bp[1];
        __half hv[8];
        hv[0] = __float2half(fmaxf(acc[0]*r+ba.x, 0.f));
        hv[1] = __float2half(fmaxf(acc[1]*r+ba.y, 0.f));
        hv[2] = __float2half(fmaxf(acc[2]*r+ba.z, 0.f));
        hv[3] = __float2half(fmaxf(acc[3]*r+ba.w, 0.f));
        hv[4] = __float2half(fmaxf(acc[4]*r+bb.x, 0.f));
        hv[5] = __float2half(fmaxf(acc[5]*r+bb.y, 0.f));
        hv[6] = __float2half(fmaxf(acc[6]*r+bb.z, 0.f));
        hv[7] = __float2half(fmaxf(acc[7]*r+bb.w, 0.f));
        *reinterpret_cast<uint4*>(&h16[(size_t)d * 128 + q * 8]) =
            *reinterpret_cast<uint4*>(hv);
    }
}

// ---------------------------------------------------------------------------
// Layer-2 gather: 16 edges/iter (2 per oct), depth-2 pipeline, [mu|lv] rows.
// ---------------------------------------------------------------------------
__global__ __launch_bounds__(256) void gat_gather2(
    const __half* __restrict__ xi16, const __half* __restrict__ xrI16,
    const float* __restrict__ atmu, const float* __restrict__ atlv,
    const float* __restrict__ bmu,  const float* __restrict__ blv,
    const int2* __restrict__ begend, const unsigned short* __restrict__ csr,
    float* __restrict__ out)
{
    int d = (blockIdx.x * 256 + threadIdx.x) >> 6;
    if (d >= NNODES) return;
    int lane = threadIdx.x & 63;
    int oct = lane >> 3;
    int r   = lane & 7;
    bool lv = r >= 4;
    int cq  = lv ? r - 4 : r;
    int oo = oct * 2;

    v2h xrh[4], ath[4];
    {
        union { uint4 u; v2h v[4]; } R;
        R.u = reinterpret_cast<const uint4*>(xrI16)[(size_t)d * 8 + r];
        #pragma unroll
        for (int j = 0; j < 4; ++j) xrh[j] = R.v[j];
        const float4* t4 = reinterpret_cast<const float4*>(lv ? atlv : atmu) + cq * 2;
        float4 a = t4[0], b = t4[1];
        ath[0] = (v2h){(_Float16)(a.x*LOG2E), (_Float16)(a.y*LOG2E)};
        ath[1] = (v2h){(_Float16)(a.z*LOG2E), (_Float16)(a.w*LOG2E)};
        ath[2] = (v2h){(_Float16)(b.x*LOG2E), (_Float16)(b.y*LOG2E)};
        ath[3] = (v2h){(_Float16)(b.z*LOG2E), (_Float16)(b.w*LOG2E)};
    }
    const v2h neg2 = (v2h){(_Float16)NEG, (_Float16)NEG};

    int2 be = begend[d];
    int beg = be.x, end = be.y;
    int nI = (end - beg + 15) >> 4;
    const uint4* xiu = reinterpret_cast<const uint4*>(xi16);

    float den = 0.f;
    float acc[8] = {0.f,0.f,0.f,0.f,0.f,0.f,0.f,0.f};

    auto compute = [&](uint4 U, bool val) {
        union { uint4 u; v2h v[4]; } X; X.u = U;
        float t = 0.f;
        #pragma unroll
        for (int j = 0; j < 4; ++j) {
            v2h s = X.v[j] + xrh[j];
            v2h l = __builtin_elementwise_max(s, s * neg2);
            t = hdot2v(l, ath[j], t);
        }
        t += __shfl_xor(t, 1, 64);
        t += __shfl_xor(t, 2, 64);
        float p = val ? fexp2(t) : 0.f;
        den += p;
        #pragma unroll
        for (int j = 0; j < 4; ++j) {
            acc[2*j]   += p * (float)X.v[j].x;
            acc[2*j+1] += p * (float)X.v[j].y;
        }
    };

    int  iA[2], iB[2];
    bool vA[2], vB[2];
    uint4 rA[2];

    #pragma unroll
    for (int k = 0; k < 2; ++k) {
        int s = beg + oo + k;
        vA[k] = s < end;
        iA[k] = csr[vA[k] ? s : end - 1];
    }
    #pragma unroll
    for (int k = 0; k < 2; ++k) rA[k] = xiu[(size_t)iA[k] * 8 + r];
    #pragma unroll
    for (int k = 0; k < 2; ++k) {
        int s = beg + 16 + oo + k;
        vB[k] = s < end;
        iB[k] = csr[vB[k] ? s : end - 1];
    }

    for (int it = 0; it < nI; ++it) {
        int b2 = beg + (it + 2) * 16;
        int  iC[2]; bool vC[2];
        #pragma unroll
        for (int k = 0; k < 2; ++k) {
            int s = b2 + oo + k;
            vC[k] = s < end;
            iC[k] = csr[vC[k] ? s : end - 1];
        }
        uint4 rB[2];
        #pragma unroll
        for (int k = 0; k < 2; ++k) rB[k] = xiu[(size_t)iB[k] * 8 + r];
        #pragma unroll
        for (int k = 0; k < 2; ++k) compute(rA[k], vA[k]);
        #pragma unroll
        for (int k = 0; k < 2; ++k) {
            rA[k] = rB[k]; vA[k] = vB[k];
            iB[k] = iC[k]; vB[k] = vC[k];
        }
    }

    den += __shfl_xor(den, 8, 64);
    den += __shfl_xor(den, 16, 64);
    den += __shfl_xor(den, 32, 64);
    #pragma unroll
    for (int j = 0; j < 8; ++j) {
        acc[j] += __shfl_xor(acc[j], 8, 64);
        acc[j] += __shfl_xor(acc[j], 16, 64);
        acc[j] += __shfl_xor(acc[j], 32, 64);
    }

    if (oct == 0) {
        float rr = 1.f / den;
        const float4* bp = reinterpret_cast<const float4*>(lv ? blv : bmu) + cq * 2;
        float4 ba = bp[0], bb = bp[1];
        float4 o1 = make_float4(acc[0]*rr+ba.x, acc[1]*rr+ba.y,
                                acc[2]*rr+ba.z, acc[3]*rr+ba.w);
        float4 o2 = make_float4(acc[4]*rr+bb.x, acc[5]*rr+bb.y,
                                acc[6]*rr+bb.z, acc[7]*rr+bb.w);
        float* base_out = out + (lv ? 1600000 : 0);
        float4* op = reinterpret_cast<float4*>(base_out) + (size_t)d * 8 + cq * 2;
        op[0] = o1; op[1] = o2;
    }
}

extern "C" void kernel_launch(void* const* d_in, const int* in_sizes, int n_in,
                              void* d_out, int out_size, void* d_ws, size_t ws_size,
                              hipStream_t stream) {
    const float* x    = (const float*)d_in[0];
    const int*   ei   = (const int*)d_in[1];
    const float* Wl1  = (const float*)d_in[2];
    const float* bl1  = (const float*)d_in[3];
    const float* Wr1  = (const float*)d_in[4];
    const float* br1  = (const float*)d_in[5];
    const float* att1 = (const float*)d_in[6];
    const float* b1   = (const float*)d_in[7];
    const float* Wlmu = (const float*)d_in[8];
    const float* blmu = (const float*)d_in[9];
    const float* Wrmu = (const float*)d_in[10];
    const float* brmu = (const float*)d_in[11];
    const float* atmu = (const float*)d_in[12];
    const float* bmu  = (const float*)d_in[13];
    const float* Wllv = (const float*)d_in[14];
    const float* bllv = (const float*)d_in[15];
    const float* Wrlv = (const float*)d_in[16];
    const float* brlv = (const float*)d_in[17];
    const float* atlv = (const float*)d_in[18];
    const float* blv  = (const float*)d_in[19];

    float* out = (float*)d_out;
    float* ws  = (float*)d_ws;

    __half* xl16 = (__half*)ws;                      // 6.4M halves
    __half* xr16 = (__half*)(ws + 3200000);          // 6.4M halves
    __half* h16  = (__half*)(ws + 6400000);          // 6.4M halves
    __half* WT   = (__half*)(ws + 9600000);          // 32768 halves
    __half* WT2  = (__half*)(ws + 9620000);          // 16384 halves

    __half* xi16  = (__half*)ws;                     // aliases (dead xl16)
    __half* xrI16 = (__half*)(ws + 1600000);

    int* ip = (int*)(ws + 10000000);
    unsigned int*   pairs  = (unsigned int*)ip;               // 391*5120 = 2,001,920
    int*            bcur   = ip + 2001920;                    // 392 (padded even)
    int2*           begend = (int2*)(ip + 2002312);           // 50,000 int2
    unsigned short* csr    = (unsigned short*)(ip + 2102312); // 2,001,920 u16

    const int* srcp = ei;
    const int* dstp = ei + EORIG;

    const int NBE = (ETOT + EPB - 1) / EPB;          // 404

    // ---- weight pack + bcur init ----
    wcvt_kernel<<<192, 256, 0, stream>>>(Wl1, Wr1, Wlmu, Wllv, Wrmu, Wrlv, WT, WT2, bcur);

    // ---- CSR build (padded buckets, no global scan) ----
    part_kernel<<<NBE, 256, 0, stream>>>(srcp, dstp, bcur, pairs);
    csrfill_kernel<<<NBUCK, 256, 0, stream>>>(pairs, bcur, begend, csr);

    // ---- layer 1 ----
    lin1_kernel<<<(NRT + 3) / 4, 256, 0, stream>>>(x, WT, bl1, br1, xl16, xr16);

    gat_gather1<<<(NNODES * 64 + 255) / 256, 256, 0, stream>>>(
        xl16, xr16, att1, b1, begend, csr, h16);

    // ---- layer 2 ----
    lin2_kernel<<<(NRT + 3) / 4, 256, 0, stream>>>(
        h16, WT2, blmu, bllv, brmu, brlv, xi16, xrI16);

    gat_gather2<<<(NNODES * 64 + 255) / 256, 256, 0, stream>>>(
        xi16, xrI16, atmu, atlv, bmu, blv, begend, csr, out);
}

// Round 12
// 196.806 us; speedup vs baseline: 24.7411x; 1.0088x over previous
//
#include <hip/hip_runtime.h>
#include <hip/hip_fp16.h>

#define NNODES 50000
#define EORIG  1600000
#define ETOT   (EORIG + NNODES)
#define NEG 0.2f
#define BSH 7
#define NBUCK ((NNODES + 127) >> BSH)   // 391
#define BCAP 5120                        // padded bucket capacity (mean 4224, sd 65)
#define NRT (NNODES / 16)               // 3125 row-tiles
#define EPB 4096
#define LOG2E 1.44269504f

typedef _Float16 v2h __attribute__((ext_vector_type(2)));
typedef _Float16 v8h __attribute__((ext_vector_type(8)));
typedef float    v4f __attribute__((ext_vector_type(4)));

__device__ __forceinline__ float hdot2v(v2h a, v2h b, float c) {
#if __has_builtin(__builtin_amdgcn_fdot2)
    return __builtin_amdgcn_fdot2(a, b, c, false);
#else
    return c + (float)a.x * (float)b.x + (float)a.y * (float)b.y;
#endif
}

__device__ __forceinline__ float fexp2(float t) {
#if __has_builtin(__builtin_amdgcn_exp2f)
    return __builtin_amdgcn_exp2f(t);
#else
    return exp2f(t);
#endif
}

// ---------------------------------------------------------------------------
// Weight pack + bcur zero-init.
// ---------------------------------------------------------------------------
__global__ __launch_bounds__(256) void wcvt_kernel(
    const float* __restrict__ Wl, const float* __restrict__ Wr,
    const float* __restrict__ Wlmu, const float* __restrict__ Wllv,
    const float* __restrict__ Wrmu, const float* __restrict__ Wrlv,
    __half* __restrict__ WT, __half* __restrict__ WT2, int* __restrict__ bcur)
{
    int id = blockIdx.x * 256 + threadIdx.x;
    if (id < NBUCK) bcur[id] = 0;
    if (id < 32768) {
        int k = id >> 8, c = id & 255;
        float v = (c < 128) ? Wl[k * 128 + c] : Wr[k * 128 + (c - 128)];
        WT[c * 128 + k] = __float2half(v);
    } else if (id < 49152) {
        int loc = id - 32768;
        int k = loc >> 7, c = loc & 127;
        int sel = c >> 5, cc = c & 31;
        const float* W = sel == 0 ? Wlmu : sel == 1 ? Wllv : sel == 2 ? Wrmu : Wrlv;
        WT2[c * 128 + k] = __float2half(W[k * 32 + cc]);
    }
}

// ---------------------------------------------------------------------------
// Layer-1 dual linear via MFMA (16x16x32 f16).
// ---------------------------------------------------------------------------
__global__ __launch_bounds__(256) void lin1_kernel(
    const float* __restrict__ x, const __half* __restrict__ WT,
    const float* __restrict__ bl, const float* __restrict__ br,
    __half* __restrict__ xl16, __half* __restrict__ xr16)
{
    int rt = (blockIdx.x * 256 + threadIdx.x) >> 6;
    if (rt >= NRT) return;
    int l  = threadIdx.x & 63;
    int lr = l & 15, lg = l >> 4;
    int row = rt * 16 + lr;

    v8h a[4];
    const float4* xrow = reinterpret_cast<const float4*>(x + (size_t)row * 128);
    #pragma unroll
    for (int ks = 0; ks < 4; ++ks) {
        float4 f0 = xrow[ks * 8 + lg * 2];
        float4 f1 = xrow[ks * 8 + lg * 2 + 1];
        v8h t;
        t[0]=(_Float16)f0.x; t[1]=(_Float16)f0.y; t[2]=(_Float16)f0.z; t[3]=(_Float16)f0.w;
        t[4]=(_Float16)f1.x; t[5]=(_Float16)f1.y; t[6]=(_Float16)f1.z; t[7]=(_Float16)f1.w;
        a[ks] = t;
    }

    const uint4* wt4 = reinterpret_cast<const uint4*>(WT);
    #pragma unroll 4
    for (int ct = 0; ct < 16; ++ct) {
        int c = ct * 16 + lr;
        v4f acc = {0.f, 0.f, 0.f, 0.f};
        #pragma unroll
        for (int ks = 0; ks < 4; ++ks) {
            union { uint4 u; v8h h; } B;
            B.u = wt4[(size_t)c * 16 + ks * 4 + lg];
            acc = __builtin_amdgcn_mfma_f32_16x16x32_f16(a[ks], B.h, acc, 0, 0, 0);
        }
        float bb = (c < 128) ? bl[c] : br[c - 128];
        #pragma unroll
        for (int j = 0; j < 4; ++j) {
            int orow = rt * 16 + lg * 4 + j;
            __half hv = __float2half(acc[j] + bb);
            if (c < 128) xl16[(size_t)orow * 128 + c] = hv;
            else         xr16[(size_t)orow * 128 + (c - 128)] = hv;
        }
    }
}

// ---------------------------------------------------------------------------
// Layer-2 quad linear via MFMA.
// ---------------------------------------------------------------------------
__global__ __launch_bounds__(256) void lin2_kernel(
    const __half* __restrict__ h16, const __half* __restrict__ WT2,
    const float* __restrict__ blmu, const float* __restrict__ bllv,
    const float* __restrict__ brmu, const float* __restrict__ brlv,
    __half* __restrict__ xi16, __half* __restrict__ xrI16)
{
    int rt = (blockIdx.x * 256 + threadIdx.x) >> 6;
    if (rt >= NRT) return;
    int l  = threadIdx.x & 63;
    int lr = l & 15, lg = l >> 4;
    int row = rt * 16 + lr;

    v8h a[4];
    const uint4* hrow = reinterpret_cast<const uint4*>(h16 + (size_t)row * 128);
    #pragma unroll
    for (int ks = 0; ks < 4; ++ks) {
        union { uint4 u; v8h h; } A;
        A.u = hrow[ks * 4 + lg];
        a[ks] = A.h;
    }

    const uint4* wt4 = reinterpret_cast<const uint4*>(WT2);
    #pragma unroll 4
    for (int ct = 0; ct < 8; ++ct) {
        int c = ct * 16 + lr;
        v4f acc = {0.f, 0.f, 0.f, 0.f};
        #pragma unroll
        for (int ks = 0; ks < 4; ++ks) {
            union { uint4 u; v8h h; } B;
            B.u = wt4[(size_t)c * 16 + ks * 4 + lg];
            acc = __builtin_amdgcn_mfma_f32_16x16x32_f16(a[ks], B.h, acc, 0, 0, 0);
        }
        int sel = c >> 5, cc = c & 31;
        const float* bp = sel == 0 ? blmu : sel == 1 ? bllv : sel == 2 ? brmu : brlv;
        float bb = bp[cc];
        #pragma unroll
        for (int j = 0; j < 4; ++j) {
            int orow = rt * 16 + lg * 4 + j;
            __half hv = __float2half(acc[j] + bb);
            if (c < 64) xi16 [(size_t)orow * 64 + c]      = hv;
            else        xrI16[(size_t)orow * 64 + (c-64)] = hv;
        }
    }
}

// ---------------------------------------------------------------------------
// CSR build, padded-bucket layout (no global scan needed).
// ---------------------------------------------------------------------------
__global__ __launch_bounds__(256) void part_kernel(
    const int* __restrict__ src, const int* __restrict__ dst,
    int* __restrict__ bcur, unsigned int* __restrict__ pairs)
{
    __shared__ int cnt[NBUCK];
    __shared__ int gbase[NBUCK];
    const int e0 = blockIdx.x * EPB;

    for (int i = threadIdx.x; i < NBUCK; i += 256) cnt[i] = 0;
    __syncthreads();

    for (int i = threadIdx.x; i < EPB; i += 256) {
        int e = e0 + i;
        if (e >= ETOT) break;
        int d = (e < EORIG) ? dst[e] : e - EORIG;
        atomicAdd(&cnt[d >> BSH], 1);
    }
    __syncthreads();

    for (int b = threadIdx.x; b < NBUCK; b += 256) {
        int c = cnt[b];
        gbase[b] = c ? (b * BCAP + atomicAdd(&bcur[b], c)) : 0;
        cnt[b] = 0;
    }
    __syncthreads();

    for (int i = threadIdx.x; i < EPB; i += 256) {
        int e = e0 + i;
        if (e >= ETOT) break;
        int s, d;
        if (e < EORIG) { s = src[e]; d = dst[e]; }
        else           { s = d = e - EORIG; }
        int b = d >> BSH;
        int slot = atomicAdd(&cnt[b], 1);
        pairs[gbase[b] + slot] = (unsigned)s | ((unsigned)(d & 127) << 16);
    }
}

__global__ __launch_bounds__(256) void csrfill_kernel(
    const unsigned int* __restrict__ pairs, const int* __restrict__ bcur,
    int2* __restrict__ begend, unsigned short* __restrict__ csr)
{
    __shared__ int cnt[128];
    __shared__ int lofs[128];
    __shared__ int scnt[128];
    const int b = blockIdx.x, n0 = b << BSH;
    const int nn = min(128, NNODES - n0);
    const int pbase = b * BCAP;
    const int pend = pbase + bcur[b];
    const int t = threadIdx.x;

    if (t < 128) { cnt[t] = 0; scnt[t] = 0; }
    __syncthreads();
    for (int i = pbase + t; i < pend; i += 256)
        atomicAdd(&cnt[pairs[i] >> 16], 1);
    __syncthreads();

    if (t < 128) lofs[t] = cnt[t];
    __syncthreads();
    for (int off = 1; off < 128; off <<= 1) {
        int v = (t < 128 && t >= off) ? lofs[t - off] : 0;
        __syncthreads();
        if (t < 128) lofs[t] += v;
        __syncthreads();
    }
    if (t < 128) lofs[t] = pbase + lofs[t] - cnt[t];   // exclusive + bucket base
    __syncthreads();

    if (t < nn) begend[n0 + t] = make_int2(lofs[t], lofs[t] + cnt[t]);

    for (int i = pbase + t; i < pend; i += 256) {
        unsigned pr = pairs[i];
        int l = pr >> 16;
        int slot = atomicAdd(&scnt[l], 1);
        csr[lofs[l] + slot] = (unsigned short)(pr & 0xFFFFu);
    }
}

// ---------------------------------------------------------------------------
// Layer-1 gather: 8 edges/iter (2 per quarter), DEPTH-3 pipeline:
// compute(it) | rows(it+1), rows(it+2) in flight | idx(it+3) prefetch.
// ---------------------------------------------------------------------------
__global__ __launch_bounds__(256) void gat_gather1(
    const __half* __restrict__ xl16, const __half* __restrict__ xr16,
    const float* __restrict__ att, const float* __restrict__ bias,
    const int2* __restrict__ begend, const unsigned short* __restrict__ csr,
    __half* __restrict__ h16)
{
    int d = (blockIdx.x * 256 + threadIdx.x) >> 6;
    if (d >= NNODES) return;
    int lane = threadIdx.x & 63;
    int quarter = lane >> 4;
    int q = lane & 15;
    int qo = quarter * 2;

    v2h xrh[4], ath[4];
    {
        union { uint4 u; v2h v[4]; } R;
        R.u = reinterpret_cast<const uint4*>(xr16)[(size_t)d * 16 + q];
        #pragma unroll
        for (int j = 0; j < 4; ++j) xrh[j] = R.v[j];
        const float4* t4 = reinterpret_cast<const float4*>(att) + q * 2;
        float4 a = t4[0], b = t4[1];
        ath[0] = (v2h){(_Float16)(a.x*LOG2E), (_Float16)(a.y*LOG2E)};
        ath[1] = (v2h){(_Float16)(a.z*LOG2E), (_Float16)(a.w*LOG2E)};
        ath[2] = (v2h){(_Float16)(b.x*LOG2E), (_Float16)(b.y*LOG2E)};
        ath[3] = (v2h){(_Float16)(b.z*LOG2E), (_Float16)(b.w*LOG2E)};
    }
    const v2h neg2 = (v2h){(_Float16)NEG, (_Float16)NEG};

    int2 be = begend[d];
    int beg = be.x, end = be.y;          // deg >= 1 (self-loop)
    int nI = (end - beg + 7) >> 3;
    const uint4* xlu = reinterpret_cast<const uint4*>(xl16);

    float den = 0.f;
    float acc[8] = {0.f,0.f,0.f,0.f,0.f,0.f,0.f,0.f};

    auto compute = [&](uint4 U, bool val) {
        union { uint4 u; v2h v[4]; } X; X.u = U;
        float t = 0.f;
        #pragma unroll
        for (int j = 0; j < 4; ++j) {
            v2h s = X.v[j] + xrh[j];
            v2h l = __builtin_elementwise_max(s, s * neg2);
            t = hdot2v(l, ath[j], t);
        }
        t += __shfl_xor(t, 1, 64);
        t += __shfl_xor(t, 2, 64);
        float p = val ? fexp2(t) : 0.f;
        den += p;
        #pragma unroll
        for (int j = 0; j < 4; ++j) {
            acc[2*j]   += p * (float)X.v[j].x;
            acc[2*j+1] += p * (float)X.v[j].y;
        }
    };

    int  iA[2], iB[2], iC[2];
    bool vA[2], vB[2], vC[2];
    uint4 rA[2], rB[2];

    #pragma unroll
    for (int k = 0; k < 2; ++k) {
        int s = beg + qo + k;
        vA[k] = s < end;
        iA[k] = csr[vA[k] ? s : end - 1];
    }
    #pragma unroll
    for (int k = 0; k < 2; ++k) rA[k] = xlu[(size_t)iA[k] * 16 + q];
    #pragma unroll
    for (int k = 0; k < 2; ++k) {
        int s = beg + 8 + qo + k;
        vB[k] = s < end;
        iB[k] = csr[vB[k] ? s : end - 1];
    }
    #pragma unroll
    for (int k = 0; k < 2; ++k) rB[k] = xlu[(size_t)iB[k] * 16 + q];
    #pragma unroll
    for (int k = 0; k < 2; ++k) {
        int s = beg + 16 + qo + k;
        vC[k] = s < end;
        iC[k] = csr[vC[k] ? s : end - 1];
    }

    for (int it = 0; it < nI; ++it) {
        // rows for it+2 (indices loaded last iter)
        uint4 rC[2];
        #pragma unroll
        for (int k = 0; k < 2; ++k) rC[k] = xlu[(size_t)iC[k] * 16 + q];
        // indices for it+3
        int b3 = beg + (it + 3) * 8;
        int iD[2]; bool vD[2];
        #pragma unroll
        for (int k = 0; k < 2; ++k) {
            int s = b3 + qo + k;
            vD[k] = s < end;
            iD[k] = csr[vD[k] ? s : end - 1];
        }
        // compute it
        compute(rA[0], vA[0]);
        compute(rA[1], vA[1]);
        // rotate stages
        #pragma unroll
        for (int k = 0; k < 2; ++k) {
            rA[k] = rB[k]; vA[k] = vB[k];
            rB[k] = rC[k]; vB[k] = vC[k];
            iC[k] = iD[k]; vC[k] = vD[k];
        }
    }

    den += __shfl_xor(den, 16, 64);
    den += __shfl_xor(den, 32, 64);
    #pragma unroll
    for (int j = 0; j < 8; ++j) {
        acc[j] += __shfl_xor(acc[j], 16, 64);
        acc[j] += __shfl_xor(acc[j], 32, 64);
    }

    if (quarter == 0) {
        float r = 1.f / den;
        const float4* bp = reinterpret_cast<const float4*>(bias) + q * 2;
        float4 ba = bp[0], bb = bp[1];
        __half hv[8];
        hv[0] = __float2half(fmaxf(acc[0]*r+ba.x, 0.f));
        hv[1] = __float2half(fmaxf(acc[1]*r+ba.y, 0.f));
        hv[2] = __float2half(fmaxf(acc[2]*r+ba.z, 0.f));
        hv[3] = __float2half(fmaxf(acc[3]*r+ba.w, 0.f));
        hv[4] = __float2half(fmaxf(acc[4]*r+bb.x, 0.f));
        hv[5] = __float2half(fmaxf(acc[5]*r+bb.y, 0.f));
        hv[6] = __float2half(fmaxf(acc[6]*r+bb.z, 0.f));
        hv[7] = __float2half(fmaxf(acc[7]*r+bb.w, 0.f));
        *reinterpret_cast<uint4*>(&h16[(size_t)d * 128 + q * 8]) =
            *reinterpret_cast<uint4*>(hv);
    }
}

// ---------------------------------------------------------------------------
// Layer-2 gather: 16 edges/iter (2 per oct), depth-2 pipeline, [mu|lv] rows.
// ---------------------------------------------------------------------------
__global__ __launch_bounds__(256) void gat_gather2(
    const __half* __restrict__ xi16, const __half* __restrict__ xrI16,
    const float* __restrict__ atmu, const float* __restrict__ atlv,
    const float* __restrict__ bmu,  const float* __restrict__ blv,
    const int2* __restrict__ begend, const unsigned short* __restrict__ csr,
    float* __restrict__ out)
{
    int d = (blockIdx.x * 256 + threadIdx.x) >> 6;
    if (d >= NNODES) return;
    int lane = threadIdx.x & 63;
    int oct = lane >> 3;
    int r   = lane & 7;
    bool lv = r >= 4;
    int cq  = lv ? r - 4 : r;
    int oo = oct * 2;

    v2h xrh[4], ath[4];
    {
        union { uint4 u; v2h v[4]; } R;
        R.u = reinterpret_cast<const uint4*>(xrI16)[(size_t)d * 8 + r];
        #pragma unroll
        for (int j = 0; j < 4; ++j) xrh[j] = R.v[j];
        const float4* t4 = reinterpret_cast<const float4*>(lv ? atlv : atmu) + cq * 2;
        float4 a = t4[0], b = t4[1];
        ath[0] = (v2h){(_Float16)(a.x*LOG2E), (_Float16)(a.y*LOG2E)};
        ath[1] = (v2h){(_Float16)(a.z*LOG2E), (_Float16)(a.w*LOG2E)};
        ath[2] = (v2h){(_Float16)(b.x*LOG2E), (_Float16)(b.y*LOG2E)};
        ath[3] = (v2h){(_Float16)(b.z*LOG2E), (_Float16)(b.w*LOG2E)};
    }
    const v2h neg2 = (v2h){(_Float16)NEG, (_Float16)NEG};

    int2 be = begend[d];
    int beg = be.x, end = be.y;
    int nI = (end - beg + 15) >> 4;
    const uint4* xiu = reinterpret_cast<const uint4*>(xi16);

    float den = 0.f;
    float acc[8] = {0.f,0.f,0.f,0.f,0.f,0.f,0.f,0.f};

    auto compute = [&](uint4 U, bool val) {
        union { uint4 u; v2h v[4]; } X; X.u = U;
        float t = 0.f;
        #pragma unroll
        for (int j = 0; j < 4; ++j) {
            v2h s = X.v[j] + xrh[j];
            v2h l = __builtin_elementwise_max(s, s * neg2);
            t = hdot2v(l, ath[j], t);
        }
        t += __shfl_xor(t, 1, 64);
        t += __shfl_xor(t, 2, 64);
        float p = val ? fexp2(t) : 0.f;
        den += p;
        #pragma unroll
        for (int j = 0; j < 4; ++j) {
            acc[2*j]   += p * (float)X.v[j].x;
            acc[2*j+1] += p * (float)X.v[j].y;
        }
    };

    int  iA[2], iB[2];
    bool vA[2], vB[2];
    uint4 rA[2];

    #pragma unroll
    for (int k = 0; k < 2; ++k) {
        int s = beg + oo + k;
        vA[k] = s < end;
        iA[k] = csr[vA[k] ? s : end - 1];
    }
    #pragma unroll
    for (int k = 0; k < 2; ++k) rA[k] = xiu[(size_t)iA[k] * 8 + r];
    #pragma unroll
    for (int k = 0; k < 2; ++k) {
        int s = beg + 16 + oo + k;
        vB[k] = s < end;
        iB[k] = csr[vB[k] ? s : end - 1];
    }

    for (int it = 0; it < nI; ++it) {
        int b2 = beg + (it + 2) * 16;
        int  iC[2]; bool vC[2];
        #pragma unroll
        for (int k = 0; k < 2; ++k) {
            int s = b2 + oo + k;
            vC[k] = s < end;
            iC[k] = csr[vC[k] ? s : end - 1];
        }
        uint4 rB[2];
        #pragma unroll
        for (int k = 0; k < 2; ++k) rB[k] = xiu[(size_t)iB[k] * 8 + r];
        #pragma unroll
        for (int k = 0; k < 2; ++k) compute(rA[k], vA[k]);
        #pragma unroll
        for (int k = 0; k < 2; ++k) {
            rA[k] = rB[k]; vA[k] = vB[k];
            iB[k] = iC[k]; vB[k] = vC[k];
        }
    }

    den += __shfl_xor(den, 8, 64);
    den += __shfl_xor(den, 16, 64);
    den += __shfl_xor(den, 32, 64);
    #pragma unroll
    for (int j = 0; j < 8; ++j) {
        acc[j] += __shfl_xor(acc[j], 8, 64);
        acc[j] += __shfl_xor(acc[j], 16, 64);
        acc[j] += __shfl_xor(acc[j], 32, 64);
    }

    if (oct == 0) {
        float rr = 1.f / den;
        const float4* bp = reinterpret_cast<const float4*>(lv ? blv : bmu) + cq * 2;
        float4 ba = bp[0], bb = bp[1];
        float4 o1 = make_float4(acc[0]*rr+ba.x, acc[1]*rr+ba.y,
                                acc[2]*rr+ba.z, acc[3]*rr+ba.w);
        float4 o2 = make_float4(acc[4]*rr+bb.x, acc[5]*rr+bb.y,
                                acc[6]*rr+bb.z, acc[7]*rr+bb.w);
        float* base_out = out + (lv ? 1600000 : 0);
        float4* op = reinterpret_cast<float4*>(base_out) + (size_t)d * 8 + cq * 2;
        op[0] = o1; op[1] = o2;
    }
}

extern "C" void kernel_launch(void* const* d_in, const int* in_sizes, int n_in,
                              void* d_out, int out_size, void* d_ws, size_t ws_size,
                              hipStream_t stream) {
    const float* x    = (const float*)d_in[0];
    const int*   ei   = (const int*)d_in[1];
    const float* Wl1  = (const float*)d_in[2];
    const float* bl1  = (const float*)d_in[3];
    const float* Wr1  = (const float*)d_in[4];
    const float* br1  = (const float*)d_in[5];
    const float* att1 = (const float*)d_in[6];
    const float* b1   = (const float*)d_in[7];
    const float* Wlmu = (const float*)d_in[8];
    const float* blmu = (const float*)d_in[9];
    const float* Wrmu = (const float*)d_in[10];
    const float* brmu = (const float*)d_in[11];
    const float* atmu = (const float*)d_in[12];
    const float* bmu  = (const float*)d_in[13];
    const float* Wllv = (const float*)d_in[14];
    const float* bllv = (const float*)d_in[15];
    const float* Wrlv = (const float*)d_in[16];
    const float* brlv = (const float*)d_in[17];
    const float* atlv = (const float*)d_in[18];
    const float* blv  = (const float*)d_in[19];

    float* out = (float*)d_out;
    float* ws  = (float*)d_ws;

    __half* xl16 = (__half*)ws;                      // 6.4M halves
    __half* xr16 = (__half*)(ws + 3200000);          // 6.4M halves
    __half* h16  = (__half*)(ws + 6400000);          // 6.4M halves
    __half* WT   = (__half*)(ws + 9600000);          // 32768 halves
    __half* WT2  = (__half*)(ws + 9620000);          // 16384 halves

    __half* xi16  = (__half*)ws;                     // aliases (dead xl16)
    __half* xrI16 = (__half*)(ws + 1600000);

    int* ip = (int*)(ws + 10000000);
    unsigned int*   pairs  = (unsigned int*)ip;               // 391*5120 = 2,001,920
    int*            bcur   = ip + 2001920;                    // 392 (padded even)
    int2*           begend = (int2*)(ip + 2002312);           // 50,000 int2
    unsigned short* csr    = (unsigned short*)(ip + 2102312); // 2,001,920 u16

    const int* srcp = ei;
    const int* dstp = ei + EORIG;

    const int NBE = (ETOT + EPB - 1) / EPB;          // 404

    // ---- weight pack + bcur init ----
    wcvt_kernel<<<192, 256, 0, stream>>>(Wl1, Wr1, Wlmu, Wllv, Wrmu, Wrlv, WT, WT2, bcur);

    // ---- CSR build (padded buckets, no global scan) ----
    part_kernel<<<NBE, 256, 0, stream>>>(srcp, dstp, bcur, pairs);
    csrfill_kernel<<<NBUCK, 256, 0, stream>>>(pairs, bcur, begend, csr);

    // ---- layer 1 ----
    lin1_kernel<<<(NRT + 3) / 4, 256, 0, stream>>>(x, WT, bl1, br1, xl16, xr16);

    gat_gather1<<<(NNODES * 64 + 255) / 256, 256, 0, stream>>>(
        xl16, xr16, att1, b1, begend, csr, h16);

    // ---- layer 2 ----
    lin2_kernel<<<(NRT + 3) / 4, 256, 0, stream>>>(
        h16, WT2, blmu, bllv, brmu, brlv, xi16, xrI16);

    gat_gather2<<<(NNODES * 64 + 255) / 256, 256, 0, stream>>>(
        xi16, xrI16, atmu, atlv, bmu, blv, begend, csr, out);
}

// Round 13
// 196.391 us; speedup vs baseline: 24.7933x; 1.0021x over previous
//
#include <hip/hip_runtime.h>
#include <hip/hip_fp16.h>

#define NNODES 50000
#define EORIG  1600000
#define ETOT   (EORIG + NNODES)
#define NEG 0.2f
#define BSH 7
#define NBUCK ((NNODES + 127) >> BSH)   // 391
#define BCAP 5120                        // padded bucket capacity
#define NRT (NNODES / 16)               // 3125 row-tiles
#define EPB 4096
#define LOG2E 1.44269504f

typedef _Float16 v2h __attribute__((ext_vector_type(2)));
typedef _Float16 v8h __attribute__((ext_vector_type(8)));
typedef float    v4f __attribute__((ext_vector_type(4)));

__device__ __forceinline__ float hdot2v(v2h a, v2h b, float c) {
#if __has_builtin(__builtin_amdgcn_fdot2)
    return __builtin_amdgcn_fdot2(a, b, c, false);
#else
    return c + (float)a.x * (float)b.x + (float)a.y * (float)b.y;
#endif
}

__device__ __forceinline__ float fexp2(float t) {
#if __has_builtin(__builtin_amdgcn_exp2f)
    return __builtin_amdgcn_exp2f(t);
#else
    return exp2f(t);
#endif
}

// ---------------------------------------------------------------------------
// Weight pack + bcur zero-init.
// ---------------------------------------------------------------------------
__global__ __launch_bounds__(256) void wcvt_kernel(
    const float* __restrict__ Wl, const float* __restrict__ Wr,
    const float* __restrict__ Wlmu, const float* __restrict__ Wllv,
    const float* __restrict__ Wrmu, const float* __restrict__ Wrlv,
    __half* __restrict__ WT, __half* __restrict__ WT2, int* __restrict__ bcur)
{
    int id = blockIdx.x * 256 + threadIdx.x;
    if (id < NBUCK) bcur[id] = 0;
    if (id < 32768) {
        int k = id >> 8, c = id & 255;
        float v = (c < 128) ? Wl[k * 128 + c] : Wr[k * 128 + (c - 128)];
        WT[c * 128 + k] = __float2half(v);
    } else if (id < 49152) {
        int loc = id - 32768;
        int k = loc >> 7, c = loc & 127;
        int sel = c >> 5, cc = c & 31;
        const float* W = sel == 0 ? Wlmu : sel == 1 ? Wllv : sel == 2 ? Wrmu : Wrlv;
        WT2[c * 128 + k] = __float2half(W[k * 32 + cc]);
    }
}

// ---------------------------------------------------------------------------
// Layer-1 dual linear via MFMA (16x16x32 f16).
// ---------------------------------------------------------------------------
__global__ __launch_bounds__(256) void lin1_kernel(
    const float* __restrict__ x, const __half* __restrict__ WT,
    const float* __restrict__ bl, const float* __restrict__ br,
    __half* __restrict__ xl16, __half* __restrict__ xr16)
{
    int rt = (blockIdx.x * 256 + threadIdx.x) >> 6;
    if (rt >= NRT) return;
    int l  = threadIdx.x & 63;
    int lr = l & 15, lg = l >> 4;
    int row = rt * 16 + lr;

    v8h a[4];
    const float4* xrow = reinterpret_cast<const float4*>(x + (size_t)row * 128);
    #pragma unroll
    for (int ks = 0; ks < 4; ++ks) {
        float4 f0 = xrow[ks * 8 + lg * 2];
        float4 f1 = xrow[ks * 8 + lg * 2 + 1];
        v8h t;
        t[0]=(_Float16)f0.x; t[1]=(_Float16)f0.y; t[2]=(_Float16)f0.z; t[3]=(_Float16)f0.w;
        t[4]=(_Float16)f1.x; t[5]=(_Float16)f1.y; t[6]=(_Float16)f1.z; t[7]=(_Float16)f1.w;
        a[ks] = t;
    }

    const uint4* wt4 = reinterpret_cast<const uint4*>(WT);
    #pragma unroll 4
    for (int ct = 0; ct < 16; ++ct) {
        int c = ct * 16 + lr;
        v4f acc = {0.f, 0.f, 0.f, 0.f};
        #pragma unroll
        for (int ks = 0; ks < 4; ++ks) {
            union { uint4 u; v8h h; } B;
            B.u = wt4[(size_t)c * 16 + ks * 4 + lg];
            acc = __builtin_amdgcn_mfma_f32_16x16x32_f16(a[ks], B.h, acc, 0, 0, 0);
        }
        float bb = (c < 128) ? bl[c] : br[c - 128];
        #pragma unroll
        for (int j = 0; j < 4; ++j) {
            int orow = rt * 16 + lg * 4 + j;
            __half hv = __float2half(acc[j] + bb);
            if (c < 128) xl16[(size_t)orow * 128 + c] = hv;
            else         xr16[(size_t)orow * 128 + (c - 128)] = hv;
        }
    }
}

// ---------------------------------------------------------------------------
// Layer-2 quad linear via MFMA.
// ---------------------------------------------------------------------------
__global__ __launch_bounds__(256) void lin2_kernel(
    const __half* __restrict__ h16, const __half* __restrict__ WT2,
    const float* __restrict__ blmu, const float* __restrict__ bllv,
    const float* __restrict__ brmu, const float* __restrict__ brlv,
    __half* __restrict__ xi16, __half* __restrict__ xrI16)
{
    int rt = (blockIdx.x * 256 + threadIdx.x) >> 6;
    if (rt >= NRT) return;
    int l  = threadIdx.x & 63;
    int lr = l & 15, lg = l >> 4;
    int row = rt * 16 + lr;

    v8h a[4];
    const uint4* hrow = reinterpret_cast<const uint4*>(h16 + (size_t)row * 128);
    #pragma unroll
    for (int ks = 0; ks < 4; ++ks) {
        union { uint4 u; v8h h; } A;
        A.u = hrow[ks * 4 + lg];
        a[ks] = A.h;
    }

    const uint4* wt4 = reinterpret_cast<const uint4*>(WT2);
    #pragma unroll 4
    for (int ct = 0; ct < 8; ++ct) {
        int c = ct * 16 + lr;
        v4f acc = {0.f, 0.f, 0.f, 0.f};
        #pragma unroll
        for (int ks = 0; ks < 4; ++ks) {
            union { uint4 u; v8h h; } B;
            B.u = wt4[(size_t)c * 16 + ks * 4 + lg];
            acc = __builtin_amdgcn_mfma_f32_16x16x32_f16(a[ks], B.h, acc, 0, 0, 0);
        }
        int sel = c >> 5, cc = c & 31;
        const float* bp = sel == 0 ? blmu : sel == 1 ? bllv : sel == 2 ? brmu : brlv;
        float bb = bp[cc];
        #pragma unroll
        for (int j = 0; j < 4; ++j) {
            int orow = rt * 16 + lg * 4 + j;
            __half hv = __float2half(acc[j] + bb);
            if (c < 64) xi16 [(size_t)orow * 64 + c]      = hv;
            else        xrI16[(size_t)orow * 64 + (c-64)] = hv;
        }
    }
}

// ---------------------------------------------------------------------------
// CSR build, padded buckets.  csrfill now SRC-BANDED: within each dst list,
// edges are grouped by src>>13 (7 x ~2MB row-bands) so concurrently-running
// waves touch the same band window -> L2-resident gathers.
// ---------------------------------------------------------------------------
__global__ __launch_bounds__(256) void part_kernel(
    const int* __restrict__ src, const int* __restrict__ dst,
    int* __restrict__ bcur, unsigned int* __restrict__ pairs)
{
    __shared__ int cnt[NBUCK];
    __shared__ int gbase[NBUCK];
    const int e0 = blockIdx.x * EPB;

    for (int i = threadIdx.x; i < NBUCK; i += 256) cnt[i] = 0;
    __syncthreads();

    for (int i = threadIdx.x; i < EPB; i += 256) {
        int e = e0 + i;
        if (e >= ETOT) break;
        int d = (e < EORIG) ? dst[e] : e - EORIG;
        atomicAdd(&cnt[d >> BSH], 1);
    }
    __syncthreads();

    for (int b = threadIdx.x; b < NBUCK; b += 256) {
        int c = cnt[b];
        gbase[b] = c ? (b * BCAP + atomicAdd(&bcur[b], c)) : 0;
        cnt[b] = 0;
    }
    __syncthreads();

    for (int i = threadIdx.x; i < EPB; i += 256) {
        int e = e0 + i;
        if (e >= ETOT) break;
        int s, d;
        if (e < EORIG) { s = src[e]; d = dst[e]; }
        else           { s = d = e - EORIG; }
        int b = d >> BSH;
        int slot = atomicAdd(&cnt[b], 1);
        pairs[gbase[b] + slot] = (unsigned)s | ((unsigned)(d & 127) << 16);
    }
}

__global__ __launch_bounds__(256) void csrfill_kernel(
    const unsigned int* __restrict__ pairs, const int* __restrict__ bcur,
    int2* __restrict__ begend, unsigned short* __restrict__ csr)
{
    __shared__ int cnt[1024];     // [dloc][band]  (band = src>>13, 0..7)
    __shared__ int pos[1024];     // exclusive prefix within bucket
    __shared__ int red[256];
    const int b = blockIdx.x, n0 = b << BSH;
    const int nn = min(128, NNODES - n0);
    const int pbase = b * BCAP;
    const int pend = pbase + bcur[b];
    const int t = threadIdx.x;

    for (int i = t; i < 1024; i += 256) cnt[i] = 0;
    __syncthreads();
    for (int i = pbase + t; i < pend; i += 256) {
        unsigned pr = pairs[i];
        atomicAdd(&cnt[((pr >> 16) << 3) | ((pr & 0xFFFFu) >> 13)], 1);
    }
    __syncthreads();

    // 1024-wide exclusive scan: thread t serially sums cnt[4t..4t+3],
    // block-scan of 256 partials, then write back.
    int s0 = cnt[4*t], s1 = cnt[4*t+1], s2 = cnt[4*t+2], s3 = cnt[4*t+3];
    int tot = s0 + s1 + s2 + s3;
    red[t] = tot;
    __syncthreads();
    for (int off = 1; off < 256; off <<= 1) {
        int v = (t >= off) ? red[t - off] : 0;
        __syncthreads();
        red[t] += v;
        __syncthreads();
    }
    int excl = red[t] - tot;
    pos[4*t]   = excl;
    pos[4*t+1] = excl + s0;
    pos[4*t+2] = excl + s0 + s1;
    pos[4*t+3] = excl + s0 + s1 + s2;
    __syncthreads();

    if (t < nn) {
        int bg = pbase + pos[t << 3];
        int en = (t == 127) ? pend : pbase + pos[(t + 1) << 3];
        begend[n0 + t] = make_int2(bg, en);
    }

    for (int i = t; i < 1024; i += 256) cnt[i] = 0;   // reuse as slot counters
    __syncthreads();
    for (int i = pbase + t; i < pend; i += 256) {
        unsigned pr = pairs[i];
        unsigned s = pr & 0xFFFFu;
        int idx = ((pr >> 16) << 3) | (s >> 13);
        int slot = atomicAdd(&cnt[idx], 1);
        csr[pbase + pos[idx] + slot] = (unsigned short)s;
    }
}

// ---------------------------------------------------------------------------
// Layer-1 gather: 8 edges/iter (2 per quarter), depth-2 pipeline (r10 best).
// att pre-scaled by log2(e); p = exp2.
// ---------------------------------------------------------------------------
__global__ __launch_bounds__(256) void gat_gather1(
    const __half* __restrict__ xl16, const __half* __restrict__ xr16,
    const float* __restrict__ att, const float* __restrict__ bias,
    const int2* __restrict__ begend, const unsigned short* __restrict__ csr,
    __half* __restrict__ h16)
{
    int d = (blockIdx.x * 256 + threadIdx.x) >> 6;
    if (d >= NNODES) return;
    int lane = threadIdx.x & 63;
    int quarter = lane >> 4;
    int q = lane & 15;
    int qo = quarter * 2;

    v2h xrh[4], ath[4];
    {
        union { uint4 u; v2h v[4]; } R;
        R.u = reinterpret_cast<const uint4*>(xr16)[(size_t)d * 16 + q];
        #pragma unroll
        for (int j = 0; j < 4; ++j) xrh[j] = R.v[j];
        const float4* t4 = reinterpret_cast<const float4*>(att) + q * 2;
        float4 a = t4[0], b = t4[1];
        ath[0] = (v2h){(_Float16)(a.x*LOG2E), (_Float16)(a.y*LOG2E)};
        ath[1] = (v2h){(_Float16)(a.z*LOG2E), (_Float16)(a.w*LOG2E)};
        ath[2] = (v2h){(_Float16)(b.x*LOG2E), (_Float16)(b.y*LOG2E)};
        ath[3] = (v2h){(_Float16)(b.z*LOG2E), (_Float16)(b.w*LOG2E)};
    }
    const v2h neg2 = (v2h){(_Float16)NEG, (_Float16)NEG};

    int2 be = begend[d];
    int beg = be.x, end = be.y;          // deg >= 1 (self-loop)
    int nI = (end - beg + 7) >> 3;
    const uint4* xlu = reinterpret_cast<const uint4*>(xl16);

    float den = 0.f;
    float acc[8] = {0.f,0.f,0.f,0.f,0.f,0.f,0.f,0.f};

    auto compute = [&](uint4 U, bool val) {
        union { uint4 u; v2h v[4]; } X; X.u = U;
        float t = 0.f;
        #pragma unroll
        for (int j = 0; j < 4; ++j) {
            v2h s = X.v[j] + xrh[j];
            v2h l = __builtin_elementwise_max(s, s * neg2);
            t = hdot2v(l, ath[j], t);
        }
        t += __shfl_xor(t, 1, 64);
        t += __shfl_xor(t, 2, 64);
        float p = val ? fexp2(t) : 0.f;
        den += p;
        #pragma unroll
        for (int j = 0; j < 4; ++j) {
            acc[2*j]   += p * (float)X.v[j].x;
            acc[2*j+1] += p * (float)X.v[j].y;
        }
    };

    int  iA[2], iB[2];
    bool vA[2], vB[2];
    uint4 rA[2];

    #pragma unroll
    for (int k = 0; k < 2; ++k) {
        int s = beg + qo + k;
        vA[k] = s < end;
        iA[k] = csr[vA[k] ? s : end - 1];
    }
    #pragma unroll
    for (int k = 0; k < 2; ++k) rA[k] = xlu[(size_t)iA[k] * 16 + q];
    #pragma unroll
    for (int k = 0; k < 2; ++k) {
        int s = beg + 8 + qo + k;
        vB[k] = s < end;
        iB[k] = csr[vB[k] ? s : end - 1];
    }

    for (int it = 0; it < nI; ++it) {
        int b2 = beg + (it + 2) * 8;
        int  iC[2]; bool vC[2];
        #pragma unroll
        for (int k = 0; k < 2; ++k) {
            int s = b2 + qo + k;
            vC[k] = s < end;
            iC[k] = csr[vC[k] ? s : end - 1];
        }
        uint4 rB[2];
        #pragma unroll
        for (int k = 0; k < 2; ++k) rB[k] = xlu[(size_t)iB[k] * 16 + q];
        compute(rA[0], vA[0]);
        compute(rA[1], vA[1]);
        #pragma unroll
        for (int k = 0; k < 2; ++k) {
            rA[k] = rB[k]; vA[k] = vB[k];
            iB[k] = iC[k]; vB[k] = vC[k];
        }
    }

    den += __shfl_xor(den, 16, 64);
    den += __shfl_xor(den, 32, 64);
    #pragma unroll
    for (int j = 0; j < 8; ++j) {
        acc[j] += __shfl_xor(acc[j], 16, 64);
        acc[j] += __shfl_xor(acc[j], 32, 64);
    }

    if (quarter == 0) {
        float r = 1.f / den;
        const float4* bp = reinterpret_cast<const float4*>(bias) + q * 2;
        float4 ba = bp[0], bb = bp[1];
        __half hv[8];
        hv[0] = __float2half(fmaxf(acc[0]*r+ba.x, 0.f));
        hv[1] = __float2half(fmaxf(acc[1]*r+ba.y, 0.f));
        hv[2] = __float2half(fmaxf(acc[2]*r+ba.z, 0.f));
        hv[3] = __float2half(fmaxf(acc[3]*r+ba.w, 0.f));
        hv[4] = __float2half(fmaxf(acc[4]*r+bb.x, 0.f));
        hv[5] = __float2half(fmaxf(acc[5]*r+bb.y, 0.f));
        hv[6] = __float2half(fmaxf(acc[6]*r+bb.z, 0.f));
        hv[7] = __float2half(fmaxf(acc[7]*r+bb.w, 0.f));
        *reinterpret_cast<uint4*>(&h16[(size_t)d * 128 + q * 8]) =
            *reinterpret_cast<uint4*>(hv);
    }
}

// ---------------------------------------------------------------------------
// Layer-2 gather: 16 edges/iter (2 per oct), depth-2 pipeline, [mu|lv] rows.
// ---------------------------------------------------------------------------
__global__ __launch_bounds__(256) void gat_gather2(
    const __half* __restrict__ xi16, const __half* __restrict__ xrI16,
    const float* __restrict__ atmu, const float* __restrict__ atlv,
    const float* __restrict__ bmu,  const float* __restrict__ blv,
    const int2* __restrict__ begend, const unsigned short* __restrict__ csr,
    float* __restrict__ out)
{
    int d = (blockIdx.x * 256 + threadIdx.x) >> 6;
    if (d >= NNODES) return;
    int lane = threadIdx.x & 63;
    int oct = lane >> 3;
    int r   = lane & 7;
    bool lv = r >= 4;
    int cq  = lv ? r - 4 : r;
    int oo = oct * 2;

    v2h xrh[4], ath[4];
    {
        union { uint4 u; v2h v[4]; } R;
        R.u = reinterpret_cast<const uint4*>(xrI16)[(size_t)d * 8 + r];
        #pragma unroll
        for (int j = 0; j < 4; ++j) xrh[j] = R.v[j];
        const float4* t4 = reinterpret_cast<const float4*>(lv ? atlv : atmu) + cq * 2;
        float4 a = t4[0], b = t4[1];
        ath[0] = (v2h){(_Float16)(a.x*LOG2E), (_Float16)(a.y*LOG2E)};
        ath[1] = (v2h){(_Float16)(a.z*LOG2E), (_Float16)(a.w*LOG2E)};
        ath[2] = (v2h){(_Float16)(b.x*LOG2E), (_Float16)(b.y*LOG2E)};
        ath[3] = (v2h){(_Float16)(b.z*LOG2E), (_Float16)(b.w*LOG2E)};
    }
    const v2h neg2 = (v2h){(_Float16)NEG, (_Float16)NEG};

    int2 be = begend[d];
    int beg = be.x, end = be.y;
    int nI = (end - beg + 15) >> 4;
    const uint4* xiu = reinterpret_cast<const uint4*>(xi16);

    float den = 0.f;
    float acc[8] = {0.f,0.f,0.f,0.f,0.f,0.f,0.f,0.f};

    auto compute = [&](uint4 U, bool val) {
        union { uint4 u; v2h v[4]; } X; X.u = U;
        float t = 0.f;
        #pragma unroll
        for (int j = 0; j < 4; ++j) {
            v2h s = X.v[j] + xrh[j];
            v2h l = __builtin_elementwise_max(s, s * neg2);
            t = hdot2v(l, ath[j], t);
        }
        t += __shfl_xor(t, 1, 64);
        t += __shfl_xor(t, 2, 64);
        float p = val ? fexp2(t) : 0.f;
        den += p;
        #pragma unroll
        for (int j = 0; j < 4; ++j) {
            acc[2*j]   += p * (float)X.v[j].x;
            acc[2*j+1] += p * (float)X.v[j].y;
        }
    };

    int  iA[2], iB[2];
    bool vA[2], vB[2];
    uint4 rA[2];

    #pragma unroll
    for (int k = 0; k < 2; ++k) {
        int s = beg + oo + k;
        vA[k] = s < end;
        iA[k] = csr[vA[k] ? s : end - 1];
    }
    #pragma unroll
    for (int k = 0; k < 2; ++k) rA[k] = xiu[(size_t)iA[k] * 8 + r];
    #pragma unroll
    for (int k = 0; k < 2; ++k) {
        int s = beg + 16 + oo + k;
        vB[k] = s < end;
        iB[k] = csr[vB[k] ? s : end - 1];
    }

    for (int it = 0; it < nI; ++it) {
        int b2 = beg + (it + 2) * 16;
        int  iC[2]; bool vC[2];
        #pragma unroll
        for (int k = 0; k < 2; ++k) {
            int s = b2 + oo + k;
            vC[k] = s < end;
            iC[k] = csr[vC[k] ? s : end - 1];
        }
        uint4 rB[2];
        #pragma unroll
        for (int k = 0; k < 2; ++k) rB[k] = xiu[(size_t)iB[k] * 8 + r];
        #pragma unroll
        for (int k = 0; k < 2; ++k) compute(rA[k], vA[k]);
        #pragma unroll
        for (int k = 0; k < 2; ++k) {
            rA[k] = rB[k]; vA[k] = vB[k];
            iB[k] = iC[k]; vB[k] = vC[k];
        }
    }

    den += __shfl_xor(den, 8, 64);
    den += __shfl_xor(den, 16, 64);
    den += __shfl_xor(den, 32, 64);
    #pragma unroll
    for (int j = 0; j < 8; ++j) {
        acc[j] += __shfl_xor(acc[j], 8, 64);
        acc[j] += __shfl_xor(acc[j], 16, 64);
        acc[j] += __shfl_xor(acc[j], 32, 64);
    }

    if (oct == 0) {
        float rr = 1.f / den;
        const float4* bp = reinterpret_cast<const float4*>(lv ? blv : bmu) + cq * 2;
        float4 ba = bp[0], bb = bp[1];
        float4 o1 = make_float4(acc[0]*rr+ba.x, acc[1]*rr+ba.y,
                                acc[2]*rr+ba.z, acc[3]*rr+ba.w);
        float4 o2 = make_float4(acc[4]*rr+bb.x, acc[5]*rr+bb.y,
                                acc[6]*rr+bb.z, acc[7]*rr+bb.w);
        float* base_out = out + (lv ? 1600000 : 0);
        float4* op = reinterpret_cast<float4*>(base_out) + (size_t)d * 8 + cq * 2;
        op[0] = o1; op[1] = o2;
    }
}

extern "C" void kernel_launch(void* const* d_in, const int* in_sizes, int n_in,
                              void* d_out, int out_size, void* d_ws, size_t ws_size,
                              hipStream_t stream) {
    const float* x    = (const float*)d_in[0];
    const int*   ei   = (const int*)d_in[1];
    const float* Wl1  = (const float*)d_in[2];
    const float* bl1  = (const float*)d_in[3];
    const float* Wr1  = (const float*)d_in[4];
    const float* br1  = (const float*)d_in[5];
    const float* att1 = (const float*)d_in[6];
    const float* b1   = (const float*)d_in[7];
    const float* Wlmu = (const float*)d_in[8];
    const float* blmu = (const float*)d_in[9];
    const float* Wrmu = (const float*)d_in[10];
    const float* brmu = (const float*)d_in[11];
    const float* atmu = (const float*)d_in[12];
    const float* bmu  = (const float*)d_in[13];
    const float* Wllv = (const float*)d_in[14];
    const float* bllv = (const float*)d_in[15];
    const float* Wrlv = (const float*)d_in[16];
    const float* brlv = (const float*)d_in[17];
    const float* atlv = (const float*)d_in[18];
    const float* blv  = (const float*)d_in[19];

    float* out = (float*)d_out;
    float* ws  = (float*)d_ws;

    __half* xl16 = (__half*)ws;                      // 6.4M halves
    __half* xr16 = (__half*)(ws + 3200000);          // 6.4M halves
    __half* h16  = (__half*)(ws + 6400000);          // 6.4M halves
    __half* WT   = (__half*)(ws + 9600000);          // 32768 halves
    __half* WT2  = (__half*)(ws + 9620000);          // 16384 halves

    __half* xi16  = (__half*)ws;                     // aliases (dead xl16)
    __half* xrI16 = (__half*)(ws + 1600000);

    int* ip = (int*)(ws + 10000000);
    unsigned int*   pairs  = (unsigned int*)ip;               // 391*5120 = 2,001,920
    int*            bcur   = ip + 2001920;                    // 392
    int2*           begend = (int2*)(ip + 2002312);           // 50,000 int2
    unsigned short* csr    = (unsigned short*)(ip + 2102312); // 2,001,920 u16

    const int* srcp = ei;
    const int* dstp = ei + EORIG;

    const int NBE = (ETOT + EPB - 1) / EPB;          // 404

    // ---- weight pack + bcur init ----
    wcvt_kernel<<<192, 256, 0, stream>>>(Wl1, Wr1, Wlmu, Wllv, Wrmu, Wrlv, WT, WT2, bcur);

    // ---- CSR build (padded buckets, src-banded lists) ----
    part_kernel<<<NBE, 256, 0, stream>>>(srcp, dstp, bcur, pairs);
    csrfill_kernel<<<NBUCK, 256, 0, stream>>>(pairs, bcur, begend, csr);

    // ---- layer 1 ----
    lin1_kernel<<<(NRT + 3) / 4, 256, 0, stream>>>(x, WT, bl1, br1, xl16, xr16);

    gat_gather1<<<(NNODES * 64 + 255) / 256, 256, 0, stream>>>(
        xl16, xr16, att1, b1, begend, csr, h16);

    // ---- layer 2 ----
    lin2_kernel<<<(NRT + 3) / 4, 256, 0, stream>>>(
        h16, WT2, blmu, bllv, brmu, brlv, xi16, xrI16);

    gat_gather2<<<(NNODES * 64 + 255) / 256, 256, 0, stream>>>(
        xi16, xrI16, atmu, atlv, bmu, blv, begend, csr, out);
}